// Round 8
// baseline (362.986 us; speedup 1.0000x reference)
//
#include <hip/hip_runtime.h>
#include <hip/hip_bf16.h>
#include <math.h>

typedef __bf16 bf16_t;
typedef __attribute__((ext_vector_type(8))) __bf16 bf16x8;
typedef __attribute__((ext_vector_type(4))) __bf16 bf16x4;
typedef __attribute__((ext_vector_type(4))) float f32x4;

#define LN_EPS 1e-5f
#define RADIUS_F 16.0f

__device__ inline bf16x8 zero8() {
    bf16x8 v;
#pragma unroll
    for (int i = 0; i < 8; ++i) v[i] = (__bf16)0.f;
    return v;
}

__device__ inline float wave_sum(float v) {
#pragma unroll
    for (int o = 1; o < 64; o <<= 1) v += __shfl_xor(v, o);
    return v;
}

__device__ inline void gload_lds16(const bf16_t* g, bf16_t* l) {
    __builtin_amdgcn_global_load_lds(
        (const __attribute__((address_space(1))) void*)g,
        (__attribute__((address_space(3))) void*)l, 16, 0, 0);
}

__device__ inline void drain_barrier() {
    asm volatile("s_waitcnt vmcnt(0)" ::: "memory");
    __builtin_amdgcn_s_barrier();
}

// ---------------- one cast kernel for all three weights ----------------
__global__ __launch_bounds__(256) void cast3_k(const float* __restrict__ qw,
                                               const float* __restrict__ vw,
                                               const float* __restrict__ ow,
                                               bf16_t* __restrict__ qwb,
                                               bf16_t* __restrict__ vwb,
                                               bf16_t* __restrict__ owb) {
    int i = blockIdx.x * 256 + threadIdx.x;  // float4 index, total 655360
    const float* src;
    bf16_t* dst;
    int j;
    if (i < 65536) { src = qw; dst = qwb; j = i; }
    else if (i < 131072) { src = vw; dst = vwb; j = i - 65536; }
    else { src = ow; dst = owb; j = i - 131072; }
    float4 v = reinterpret_cast<const float4*>(src)[j];
    bf16x4 o;
    o[0] = (__bf16)v.x; o[1] = (__bf16)v.y; o[2] = (__bf16)v.z; o[3] = (__bf16)v.w;
    reinterpret_cast<bf16x4*>(dst)[j] = o;
}

// normalize mem_key rows (896 x 64) -> bf16
__global__ __launch_bounds__(256) void keyn_k(const float* __restrict__ mk,
                                              bf16_t* __restrict__ kn) {
    int row = blockIdx.x * 4 + (threadIdx.x >> 6);
    int lane = threadIdx.x & 63;
    float x = mk[(size_t)row * 64 + lane];
    float ss = wave_sum(x * x);
    kn[(size_t)row * 64 + lane] = (__bf16)(x / fmaxf(sqrtf(ss), 1e-12f));
}

// mem_value: row inv-norms + bf16 copy (padded to 128) + transposed copy; zero loss
__global__ __launch_bounds__(256) void mv_prep_k(const float* __restrict__ mv,
                                                 bf16_t* __restrict__ mvb,
                                                 bf16_t* __restrict__ mvT,
                                                 float* __restrict__ invmv,
                                                 float* __restrict__ loss_slots) {
    const int s = blockIdx.x, tid = threadIdx.x;
    if (s >= 112) {
        mvb[(size_t)s * 512 + tid * 2] = (__bf16)0.f;
        mvb[(size_t)s * 512 + tid * 2 + 1] = (__bf16)0.f;
        mvT[(size_t)tid * 128 + s] = (__bf16)0.f;
        mvT[(size_t)(tid + 256) * 128 + s] = (__bf16)0.f;
        return;
    }
    float2 x = *reinterpret_cast<const float2*>(mv + (size_t)s * 512 + tid * 2);
    float ss = wave_sum(x.x * x.x + x.y * x.y);
    __shared__ float red[4];
    int wid = tid >> 6, lane = tid & 63;
    if (lane == 0) red[wid] = ss;
    __syncthreads();
    ss = red[0] + red[1] + red[2] + red[3];
    if (tid == 0) invmv[s] = 1.f / fmaxf(sqrtf(ss), 1e-12f);
    mvb[(size_t)s * 512 + tid * 2] = (__bf16)x.x;
    mvb[(size_t)s * 512 + tid * 2 + 1] = (__bf16)x.y;
    // transposed copy [512][128]
    mvT[(size_t)tid * 128 + s] = (__bf16)mv[(size_t)s * 512 + tid];
    mvT[(size_t)(tid + 256) * 128 + s] = (__bf16)mv[(size_t)s * 512 + tid + 256];
    if (s == 0 && tid < 2) loss_slots[tid] = 0.f;
}

// contrastive loss: sum |I - Gn Gn^T| * 0.01  (fp32)
__global__ __launch_bounds__(256) void contrastive_k(const float* __restrict__ mv,
                                                     const float* __restrict__ invmv,
                                                     float* __restrict__ out_slot) {
    const int a = blockIdx.x;
    const int tid = threadIdx.x, wid = tid >> 6, lane = tid & 63;
    __shared__ float rowa[512];
    __shared__ float wsum[4];
    for (int i = tid; i < 512; i += 256) rowa[i] = mv[(size_t)a * 512 + i];
    __syncthreads();
    float acc = 0.f;
    const float ia = invmv[a];
    for (int b = wid; b < 112; b += 4) {
        float d = 0.f;
#pragma unroll
        for (int i = 0; i < 8; ++i) d += rowa[lane + i * 64] * mv[(size_t)b * 512 + lane + i * 64];
        d = wave_sum(d);
        float gv = d * ia * invmv[b];
        acc += fabsf((a == b ? 1.f : 0.f) - gv);
    }
    if (lane == 0) wsum[wid] = acc;
    __syncthreads();
    if (tid == 0) atomicAdd(out_slot, (wsum[0] + wsum[1] + wsum[2] + wsum[3]) * 0.01f);
}

// ---------------- combined qp/v_proj GEMM (A fp32, reg-staged + cvt) ----------------
// blockIdx.z = 0: qp = query @ q_w^T + q_b ; z = 1: vp = value @ v_w^T + v_b
__global__ __launch_bounds__(256) void gemm_qv(
    const float* __restrict__ A0, const float* __restrict__ A1,
    const bf16_t* __restrict__ W0, const bf16_t* __restrict__ W1,
    const float* __restrict__ b0, const float* __restrict__ b1,
    bf16_t* __restrict__ C0, bf16_t* __restrict__ C1) {
    const float* A = blockIdx.z ? A1 : A0;
    const bf16_t* W = blockIdx.z ? W1 : W0;
    const float* bias = blockIdx.z ? b1 : b0;
    bf16_t* Cb = blockIdx.z ? C1 : C0;
    __shared__ __align__(16) bf16_t As[128 * 32];
    __shared__ __align__(16) bf16_t Bs[128 * 32];
    const int tid = threadIdx.x;
    const int wid = tid >> 6, lane = tid & 63;
    const int wr = wid >> 1, wc = wid & 1;
    const int lr = lane & 15;
    const int ko = (lane >> 4) * 8;
    const size_t rowBase = (size_t)blockIdx.x * 128;
    const size_t colBase = (size_t)blockIdx.y * 128;
    const int r0 = tid >> 2;
    const int c0 = (tid & 3) * 8;
    const float* a_src = A + (rowBase + r0) * 512 + c0;
    const bf16_t* w_src = W + (colBase + r0) * 512 + c0;
    f32x4 acc[4][4];
#pragma unroll
    for (int m = 0; m < 4; ++m)
#pragma unroll
        for (int n = 0; n < 4; ++n) {
            acc[m][n][0] = 0.f; acc[m][n][1] = 0.f;
            acc[m][n][2] = 0.f; acc[m][n][3] = 0.f;
        }
    for (int k0 = 0; k0 < 512; k0 += 32) {
        float4 a0 = *reinterpret_cast<const float4*>(a_src + k0);
        float4 a1 = *reinterpret_cast<const float4*>(a_src + k0 + 4);
        float4 a2 = *reinterpret_cast<const float4*>(a_src + (size_t)64 * 512 + k0);
        float4 a3 = *reinterpret_cast<const float4*>(a_src + (size_t)64 * 512 + k0 + 4);
        __syncthreads();
        gload_lds16(w_src + k0, Bs + tid * 8);
        gload_lds16(w_src + (size_t)64 * 512 + k0, Bs + 2048 + tid * 8);
        bf16x8 p0, p1;
        p0[0] = (__bf16)a0.x; p0[1] = (__bf16)a0.y; p0[2] = (__bf16)a0.z; p0[3] = (__bf16)a0.w;
        p0[4] = (__bf16)a1.x; p0[5] = (__bf16)a1.y; p0[6] = (__bf16)a1.z; p0[7] = (__bf16)a1.w;
        p1[0] = (__bf16)a2.x; p1[1] = (__bf16)a2.y; p1[2] = (__bf16)a2.z; p1[3] = (__bf16)a2.w;
        p1[4] = (__bf16)a3.x; p1[5] = (__bf16)a3.y; p1[6] = (__bf16)a3.z; p1[7] = (__bf16)a3.w;
        *reinterpret_cast<bf16x8*>(As + tid * 8) = p0;
        *reinterpret_cast<bf16x8*>(As + 2048 + tid * 8) = p1;
        __syncthreads();
        bf16x8 af[4], bfr[4];
#pragma unroll
        for (int m = 0; m < 4; ++m)
            af[m] = *reinterpret_cast<const bf16x8*>(As + (wr * 64 + m * 16 + lr) * 32 + ko);
#pragma unroll
        for (int n = 0; n < 4; ++n)
            bfr[n] = *reinterpret_cast<const bf16x8*>(Bs + (wc * 64 + n * 16 + lr) * 32 + ko);
#pragma unroll
        for (int m = 0; m < 4; ++m)
#pragma unroll
            for (int n = 0; n < 4; ++n)
                acc[m][n] = __builtin_amdgcn_mfma_f32_16x16x32_bf16(af[m], bfr[n], acc[m][n], 0, 0, 0);
    }
    const int rj = (lane >> 4) * 4;
#pragma unroll
    for (int n = 0; n < 4; ++n) {
        const int col = (int)colBase + wc * 64 + n * 16 + lr;
        const float bv = bias[col];
#pragma unroll
        for (int m = 0; m < 4; ++m) {
            const size_t r = rowBase + wr * 64 + m * 16 + rj;
#pragma unroll
            for (int j = 0; j < 4; ++j)
                Cb[(r + j) * 512 + col] = (__bf16)(acc[m][n][j] + bv);
        }
    }
}

// ---------------- 128x128 LDS-staged GEMM, bf16 A, bf16 out (+optional bias) ----------------
__global__ __launch_bounds__(256) void gemm128_bb(
    const bf16_t* __restrict__ A, int lda,
    const bf16_t* __restrict__ W, int ldw,
    const float* __restrict__ bias,
    bf16_t* __restrict__ Cb, int ldc, int K) {
    __shared__ __align__(16) bf16_t As[128 * 32];
    __shared__ __align__(16) bf16_t Bs[128 * 32];
    const int tid = threadIdx.x;
    const int wid = tid >> 6, lane = tid & 63;
    const int wr = wid >> 1, wc = wid & 1;
    const int lr = lane & 15;
    const int ko = (lane >> 4) * 8;
    const size_t rowBase = (size_t)blockIdx.x * 128;
    const size_t colBase = (size_t)blockIdx.y * 128;
    const int r0 = tid >> 2;
    const int c0 = (tid & 3) * 8;
    const bf16_t* a_src = A + (rowBase + r0) * lda + c0;
    const bf16_t* w_src = W + (colBase + r0) * ldw + c0;
    f32x4 acc[4][4];
#pragma unroll
    for (int m = 0; m < 4; ++m)
#pragma unroll
        for (int n = 0; n < 4; ++n) {
            acc[m][n][0] = 0.f; acc[m][n][1] = 0.f;
            acc[m][n][2] = 0.f; acc[m][n][3] = 0.f;
        }
    for (int k0 = 0; k0 < K; k0 += 32) {
        __syncthreads();
        gload_lds16(a_src + k0, As + tid * 8);
        gload_lds16(a_src + (size_t)64 * lda + k0, As + 2048 + tid * 8);
        gload_lds16(w_src + k0, Bs + tid * 8);
        gload_lds16(w_src + (size_t)64 * ldw + k0, Bs + 2048 + tid * 8);
        __syncthreads();
        bf16x8 af[4], bfr[4];
#pragma unroll
        for (int m = 0; m < 4; ++m)
            af[m] = *reinterpret_cast<const bf16x8*>(As + (wr * 64 + m * 16 + lr) * 32 + ko);
#pragma unroll
        for (int n = 0; n < 4; ++n)
            bfr[n] = *reinterpret_cast<const bf16x8*>(Bs + (wc * 64 + n * 16 + lr) * 32 + ko);
#pragma unroll
        for (int m = 0; m < 4; ++m)
#pragma unroll
            for (int n = 0; n < 4; ++n)
                acc[m][n] = __builtin_amdgcn_mfma_f32_16x16x32_bf16(af[m], bfr[n], acc[m][n], 0, 0, 0);
    }
    const int rj = (lane >> 4) * 4;
#pragma unroll
    for (int n = 0; n < 4; ++n) {
        const int col = (int)colBase + wc * 64 + n * 16 + lr;
        const float bv = bias ? bias[col] : 0.f;
#pragma unroll
        for (int m = 0; m < 4; ++m) {
            const size_t r = rowBase + wr * 64 + m * 16 + rj;
#pragma unroll
            for (int j = 0; j < 4; ++j)
                Cb[(r + j) * ldc + col] = (__bf16)(acc[m][n][j] + bv);
        }
    }
}

// ---------------- small direct GEMM (WcT fold only) ----------------
__global__ __launch_bounds__(256) void gemm_bt(
    const bf16_t* __restrict__ A, int lda, int aZ,
    const bf16_t* __restrict__ W, int ldw, int wZ,
    bf16_t* __restrict__ Cb, int ldc, int cZ,
    int M, int N, int K) {
    const int wid = threadIdx.x >> 6;
    const int lane = threadIdx.x & 63;
    const int lr = lane & 15;
    const int kk = (lane >> 4) * 8;
    const int row0 = blockIdx.x * 64 + wid * 16;
    const int col0 = blockIdx.y * 64;
    A += (size_t)blockIdx.z * aZ;
    W += (size_t)blockIdx.z * wZ;
    const bf16_t* a_ptr = A + (size_t)(row0 + lr) * lda + kk;
    const bf16_t* w_ptr = W + (size_t)(col0 + lr) * ldw + kk;
    f32x4 acc[4];
#pragma unroll
    for (int t = 0; t < 4; ++t) { acc[t][0] = 0.f; acc[t][1] = 0.f; acc[t][2] = 0.f; acc[t][3] = 0.f; }
    bool colv[4];
#pragma unroll
    for (int t = 0; t < 4; ++t) colv[t] = (col0 + t * 16 + lr) < N;
    for (int k0 = 0; k0 < K; k0 += 32) {
        bf16x8 a = *reinterpret_cast<const bf16x8*>(a_ptr + k0);
#pragma unroll
        for (int t = 0; t < 4; ++t) {
            bf16x8 b;
            if (colv[t]) b = *reinterpret_cast<const bf16x8*>(w_ptr + (size_t)t * 16 * ldw + k0);
            else b = zero8();
            acc[t] = __builtin_amdgcn_mfma_f32_16x16x32_bf16(a, b, acc[t], 0, 0, 0);
        }
    }
    const int rb = (lane >> 4) * 4;
    Cb += (size_t)blockIdx.z * cZ;
#pragma unroll
    for (int t = 0; t < 4; ++t) {
        int col = col0 + t * 16 + lr;
        if (col >= N) continue;
#pragma unroll
        for (int j = 0; j < 4; ++j) {
            int r = row0 + rb + j;
            Cb[(size_t)r * ldc + col] = (__bf16)acc[t][j];
        }
    }
}

// ---------------- predict addressing: sim -> softmax -> addr bf16 [N,896] ----------------
__global__ __launch_bounds__(256) void addr_predict(const bf16_t* __restrict__ qp,
                                                    const bf16_t* __restrict__ keyn,
                                                    bf16_t* __restrict__ addr) {
    const int wid = threadIdx.x >> 6, lane = threadIdx.x & 63;
    const int lr = lane & 15, kk = (lane >> 4) * 8;
    const int h = blockIdx.y;
    const int row0 = blockIdx.x * 64 + wid * 16;
    const bf16_t* a_ptr = qp + (size_t)(row0 + lr) * 512 + h * 64 + kk;
    bf16x8 a0 = *reinterpret_cast<const bf16x8*>(a_ptr);
    bf16x8 a1 = *reinterpret_cast<const bf16x8*>(a_ptr + 32);
    float ssq = 0.f;
#pragma unroll
    for (int j = 0; j < 8; ++j) {
        float x = (float)a0[j], y = (float)a1[j];
        ssq += x * x + y * y;
    }
    ssq += __shfl_xor(ssq, 16);
    ssq += __shfl_xor(ssq, 32);
    const float invq = 1.f / fmaxf(sqrtf(ssq), 1e-12f);
    f32x4 acc[7];
#pragma unroll
    for (int t = 0; t < 7; ++t) {
        const bf16_t* b_ptr = keyn + (size_t)(h * 112 + t * 16 + lr) * 64 + kk;
        bf16x8 b0 = *reinterpret_cast<const bf16x8*>(b_ptr);
        bf16x8 b1 = *reinterpret_cast<const bf16x8*>(b_ptr + 32);
        f32x4 c; c[0] = 0.f; c[1] = 0.f; c[2] = 0.f; c[3] = 0.f;
        c = __builtin_amdgcn_mfma_f32_16x16x32_bf16(a0, b0, c, 0, 0, 0);
        c = __builtin_amdgcn_mfma_f32_16x16x32_bf16(a1, b1, c, 0, 0, 0);
        acc[t] = c;
    }
    const int rb = (lane >> 4) * 4;
    float iq[4];
#pragma unroll
    for (int j = 0; j < 4; ++j) iq[j] = __shfl(invq, rb + j);
#pragma unroll
    for (int j = 0; j < 4; ++j) {
        float m = -1e30f;
#pragma unroll
        for (int t = 0; t < 7; ++t) { acc[t][j] *= iq[j] * RADIUS_F; m = fmaxf(m, acc[t][j]); }
#pragma unroll
        for (int o = 1; o < 16; o <<= 1) m = fmaxf(m, __shfl_xor(m, o));
        float s = 0.f;
#pragma unroll
        for (int t = 0; t < 7; ++t) { float e = __expf(acc[t][j] - m); acc[t][j] = e; s += e; }
#pragma unroll
        for (int o = 1; o < 16; o <<= 1) s += __shfl_xor(s, o);
        const float rs = 1.f / s;
#pragma unroll
        for (int t = 0; t < 7; ++t) acc[t][j] *= rs;
    }
#pragma unroll
    for (int t = 0; t < 7; ++t)
#pragma unroll
        for (int j = 0; j < 4; ++j)
            addr[(size_t)(row0 + rb + j) * 896 + h * 112 + t * 16 + lr] = (__bf16)acc[t][j];
}

// ---------------- fused recon sim GEMM + softmax -> addr2 [M][128] ----------------
__global__ __launch_bounds__(256, 2) void gemm_sim_softmax(
    const bf16_t* __restrict__ vp,   // [M][512]
    const bf16_t* __restrict__ mvb,  // [128][512] (rows 112..127 zero)
    const float* __restrict__ invmv, // [112]
    bf16_t* __restrict__ addr2) {    // [M][128]
    __shared__ __align__(16) bf16_t As[2][128 * 32];
    __shared__ __align__(16) bf16_t Bs[2][128 * 32];
    const int tid = threadIdx.x;
    const int wid = tid >> 6, lane = tid & 63;
    const int lr = lane & 15, hi = lane >> 4;
    const int ko = hi * 8;
    const size_t rowBase = (size_t)blockIdx.x * 128;
    const int r0 = tid >> 2, c0 = (tid & 3) * 8;
    const bf16_t* a_src = vp + (rowBase + r0) * 512 + c0;
    const bf16_t* b_src = mvb + (size_t)r0 * 512 + c0;
    f32x4 acc[2][8];
#pragma unroll
    for (int m = 0; m < 2; ++m)
#pragma unroll
        for (int n = 0; n < 8; ++n) {
            acc[m][n][0] = 0.f; acc[m][n][1] = 0.f;
            acc[m][n][2] = 0.f; acc[m][n][3] = 0.f;
        }
    float ssq[2] = {0.f, 0.f};
    auto stage = [&](int buf, int ks) {
        const int k0 = ks * 32;
        gload_lds16(a_src + k0, &As[buf][tid * 8]);
        gload_lds16(a_src + (size_t)64 * 512 + k0, &As[buf][2048 + tid * 8]);
        gload_lds16(b_src + k0, &Bs[buf][tid * 8]);
        gload_lds16(b_src + (size_t)64 * 512 + k0, &Bs[buf][2048 + tid * 8]);
    };
    stage(0, 0);
    drain_barrier();
    int cur = 0;
    for (int ks = 0; ks < 16; ++ks) {
        if (ks < 15) stage(cur ^ 1, ks + 1);
        bf16x8 af[2], bfr[8];
#pragma unroll
        for (int m = 0; m < 2; ++m)
            af[m] = *reinterpret_cast<const bf16x8*>(&As[cur][(wid * 32 + m * 16 + lr) * 32 + ko]);
#pragma unroll
        for (int n = 0; n < 8; ++n)
            bfr[n] = *reinterpret_cast<const bf16x8*>(&Bs[cur][(n * 16 + lr) * 32 + ko]);
#pragma unroll
        for (int m = 0; m < 2; ++m) {
#pragma unroll
            for (int j = 0; j < 8; ++j) { float x = (float)af[m][j]; ssq[m] += x * x; }
#pragma unroll
            for (int n = 0; n < 8; ++n)
                acc[m][n] = __builtin_amdgcn_mfma_f32_16x16x32_bf16(af[m], bfr[n], acc[m][n], 0, 0, 0);
        }
        drain_barrier();
        cur ^= 1;
    }
#pragma unroll
    for (int m = 0; m < 2; ++m) {
        ssq[m] += __shfl_xor(ssq[m], 16);
        ssq[m] += __shfl_xor(ssq[m], 32);
        ssq[m] = 1.f / fmaxf(sqrtf(ssq[m]), 1e-12f);
    }
    const int rb = hi * 4;
    float imv[7];
#pragma unroll
    for (int n = 0; n < 7; ++n) imv[n] = invmv[n * 16 + lr];
#pragma unroll
    for (int m = 0; m < 2; ++m)
#pragma unroll
        for (int j = 0; j < 4; ++j) {
            const float iq = __shfl(ssq[m], (lane & 48) | (rb + j));
            float x[7];
            float mx = -1e30f;
#pragma unroll
            for (int n = 0; n < 7; ++n) {
                x[n] = acc[m][n][j] * iq * imv[n] * RADIUS_F;
                mx = fmaxf(mx, x[n]);
            }
#pragma unroll
            for (int o = 1; o < 16; o <<= 1) mx = fmaxf(mx, __shfl_xor(mx, o));
            float s = 0.f;
#pragma unroll
            for (int n = 0; n < 7; ++n) { x[n] = __expf(x[n] - mx); s += x[n]; }
#pragma unroll
            for (int o = 1; o < 16; o <<= 1) s += __shfl_xor(s, o);
            const float rs = 1.f / s;
            const size_t row = rowBase + wid * 32 + m * 16 + rb + j;
#pragma unroll
            for (int n = 0; n < 7; ++n)
                addr2[row * 128 + n * 16 + lr] = (__bf16)(x[n] * rs);
            addr2[row * 128 + 112 + lr] = (__bf16)0.f;
        }
}

// ---------------- streaming LN (predict): 4 rows/wave, bf16 stage input ----------------
// out = LN1(query + stage); grid = 2048; lane handles cols [lane*8, lane*8+8)
__global__ __launch_bounds__(256) void ln_stream(
    const bf16_t* __restrict__ stage, const float* __restrict__ query,
    const float* __restrict__ g, const float* __restrict__ b,
    float* __restrict__ outp) {
    const int wid = threadIdx.x >> 6, lane = threadIdx.x & 63;
    const size_t row0 = (size_t)blockIdx.x * 16 + wid * 4;
    const int c1 = lane * 8, c2 = lane * 8 + 4;
    float4 x1[4], x2[4];
    float s1[4], s2[4];
#pragma unroll
    for (int r = 0; r < 4; ++r) {
        const size_t base = (row0 + r) * 512;
        bf16x8 a = *reinterpret_cast<const bf16x8*>(stage + base + c1);
        float4 q1 = *reinterpret_cast<const float4*>(query + base + c1);
        float4 q2 = *reinterpret_cast<const float4*>(query + base + c2);
        x1[r] = make_float4(q1.x + (float)a[0], q1.y + (float)a[1],
                            q1.z + (float)a[2], q1.w + (float)a[3]);
        x2[r] = make_float4(q2.x + (float)a[4], q2.y + (float)a[5],
                            q2.z + (float)a[6], q2.w + (float)a[7]);
        s1[r] = x1[r].x + x1[r].y + x1[r].z + x1[r].w + x2[r].x + x2[r].y + x2[r].z + x2[r].w;
        s2[r] = x1[r].x * x1[r].x + x1[r].y * x1[r].y + x1[r].z * x1[r].z + x1[r].w * x1[r].w +
                x2[r].x * x2[r].x + x2[r].y * x2[r].y + x2[r].z * x2[r].z + x2[r].w * x2[r].w;
    }
#pragma unroll
    for (int o = 1; o < 64; o <<= 1)
#pragma unroll
        for (int r = 0; r < 4; ++r) {
            s1[r] += __shfl_xor(s1[r], o);
            s2[r] += __shfl_xor(s2[r], o);
        }
    const float4 g1v = *reinterpret_cast<const float4*>(g + c1);
    const float4 g2v = *reinterpret_cast<const float4*>(g + c2);
    const float4 b1v = *reinterpret_cast<const float4*>(b + c1);
    const float4 b2v = *reinterpret_cast<const float4*>(b + c2);
#pragma unroll
    for (int r = 0; r < 4; ++r) {
        const size_t base = (row0 + r) * 512;
        const float mu = s1[r] * (1.f / 512.f);
        const float rs = rsqrtf(s2[r] * (1.f / 512.f) - mu * mu + LN_EPS);
        float4 o1 = make_float4((x1[r].x - mu) * rs * g1v.x + b1v.x,
                                (x1[r].y - mu) * rs * g1v.y + b1v.y,
                                (x1[r].z - mu) * rs * g1v.z + b1v.z,
                                (x1[r].w - mu) * rs * g1v.w + b1v.w);
        float4 o2 = make_float4((x2[r].x - mu) * rs * g2v.x + b2v.x,
                                (x2[r].y - mu) * rs * g2v.y + b2v.y,
                                (x2[r].z - mu) * rs * g2v.z + b2v.z,
                                (x2[r].w - mu) * rs * g2v.w + b2v.w);
        *reinterpret_cast<float4*>(outp + base + c1) = o1;
        *reinterpret_cast<float4*>(outp + base + c2) = o2;
    }
}

// ---------------- streaming recon epilogue: bf16 stage, no global atomics ----------------
// out = LN1(query + LN3(stage)); rrpart[blockIdx.x] = sum |1-cos(stage,value)|
__global__ __launch_bounds__(256) void recon_ep_stream(
    const bf16_t* __restrict__ stage,
    const float* __restrict__ query, const float* __restrict__ value,
    const float* __restrict__ g3, const float* __restrict__ b3,
    const float* __restrict__ g1, const float* __restrict__ b1,
    float* __restrict__ outp, float* __restrict__ rrpart) {
    const int wid = threadIdx.x >> 6, lane = threadIdx.x & 63;
    const size_t row0 = (size_t)blockIdx.x * 16 + wid * 4;
    const int c1 = lane * 8, c2 = lane * 8 + 4;
    float4 a1[4], a2[4];
    float sa[4], sa2[4], sav[4], sv2[4];
#pragma unroll
    for (int r = 0; r < 4; ++r) {
        const size_t base = (row0 + r) * 512;
        bf16x8 a = *reinterpret_cast<const bf16x8*>(stage + base + c1);
        a1[r] = make_float4((float)a[0], (float)a[1], (float)a[2], (float)a[3]);
        a2[r] = make_float4((float)a[4], (float)a[5], (float)a[6], (float)a[7]);
        float4 v1 = *reinterpret_cast<const float4*>(value + base + c1);
        float4 v2 = *reinterpret_cast<const float4*>(value + base + c2);
        sa[r] = a1[r].x + a1[r].y + a1[r].z + a1[r].w + a2[r].x + a2[r].y + a2[r].z + a2[r].w;
        sa2[r] = a1[r].x * a1[r].x + a1[r].y * a1[r].y + a1[r].z * a1[r].z + a1[r].w * a1[r].w +
                 a2[r].x * a2[r].x + a2[r].y * a2[r].y + a2[r].z * a2[r].z + a2[r].w * a2[r].w;
        sav[r] = a1[r].x * v1.x + a1[r].y * v1.y + a1[r].z * v1.z + a1[r].w * v1.w +
                 a2[r].x * v2.x + a2[r].y * v2.y + a2[r].z * v2.z + a2[r].w * v2.w;
        sv2[r] = v1.x * v1.x + v1.y * v1.y + v1.z * v1.z + v1.w * v1.w +
                 v2.x * v2.x + v2.y * v2.y + v2.z * v2.z + v2.w * v2.w;
    }
#pragma unroll
    for (int o = 1; o < 64; o <<= 1)
#pragma unroll
        for (int r = 0; r < 4; ++r) {
            sa[r] += __shfl_xor(sa[r], o);
            sa2[r] += __shfl_xor(sa2[r], o);
            sav[r] += __shfl_xor(sav[r], o);
            sv2[r] += __shfl_xor(sv2[r], o);
        }
    float rrw = 0.f;
#pragma unroll
    for (int r = 0; r < 4; ++r) {
        const float na = fmaxf(sqrtf(sa2[r]), 1e-12f);
        const float nv = fmaxf(sqrtf(sv2[r]), 1e-12f);
        rrw += fabsf(1.f - sav[r] / (na * nv));
    }
    const float4 g3a = *reinterpret_cast<const float4*>(g3 + c1);
    const float4 g3b = *reinterpret_cast<const float4*>(g3 + c2);
    const float4 b3a = *reinterpret_cast<const float4*>(b3 + c1);
    const float4 b3b = *reinterpret_cast<const float4*>(b3 + c2);
    float s1[4], s2[4];
#pragma unroll
    for (int r = 0; r < 4; ++r) {
        const size_t base = (row0 + r) * 512;
        const float mu3 = sa[r] * (1.f / 512.f);
        const float r3 = rsqrtf(sa2[r] * (1.f / 512.f) - mu3 * mu3 + LN_EPS);
        float4 q1 = *reinterpret_cast<const float4*>(query + base + c1);
        float4 q2 = *reinterpret_cast<const float4*>(query + base + c2);
        a1[r] = make_float4(q1.x + (a1[r].x - mu3) * r3 * g3a.x + b3a.x,
                            q1.y + (a1[r].y - mu3) * r3 * g3a.y + b3a.y,
                            q1.z + (a1[r].z - mu3) * r3 * g3a.z + b3a.z,
                            q1.w + (a1[r].w - mu3) * r3 * g3a.w + b3a.w);
        a2[r] = make_float4(q2.x + (a2[r].x - mu3) * r3 * g3b.x + b3b.x,
                            q2.y + (a2[r].y - mu3) * r3 * g3b.y + b3b.y,
                            q2.z + (a2[r].z - mu3) * r3 * g3b.z + b3b.z,
                            q2.w + (a2[r].w - mu3) * r3 * g3b.w + b3b.w);
        s1[r] = a1[r].x + a1[r].y + a1[r].z + a1[r].w + a2[r].x + a2[r].y + a2[r].z + a2[r].w;
        s2[r] = a1[r].x * a1[r].x + a1[r].y * a1[r].y + a1[r].z * a1[r].z + a1[r].w * a1[r].w +
                a2[r].x * a2[r].x + a2[r].y * a2[r].y + a2[r].z * a2[r].z + a2[r].w * a2[r].w;
    }
#pragma unroll
    for (int o = 1; o < 64; o <<= 1)
#pragma unroll
        for (int r = 0; r < 4; ++r) {
            s1[r] += __shfl_xor(s1[r], o);
            s2[r] += __shfl_xor(s2[r], o);
        }
    const float4 g1a = *reinterpret_cast<const float4*>(g1 + c1);
    const float4 g1b = *reinterpret_cast<const float4*>(g1 + c2);
    const float4 b1a = *reinterpret_cast<const float4*>(b1 + c1);
    const float4 b1b = *reinterpret_cast<const float4*>(b1 + c2);
#pragma unroll
    for (int r = 0; r < 4; ++r) {
        const size_t base = (row0 + r) * 512;
        const float mu = s1[r] * (1.f / 512.f);
        const float rs = rsqrtf(s2[r] * (1.f / 512.f) - mu * mu + LN_EPS);
        float4 o1 = make_float4((a1[r].x - mu) * rs * g1a.x + b1a.x,
                                (a1[r].y - mu) * rs * g1a.y + b1a.y,
                                (a1[r].z - mu) * rs * g1a.z + b1a.z,
                                (a1[r].w - mu) * rs * g1a.w + b1a.w);
        float4 o2 = make_float4((a2[r].x - mu) * rs * g1b.x + b1b.x,
                                (a2[r].y - mu) * rs * g1b.y + b1b.y,
                                (a2[r].z - mu) * rs * g1b.z + b1b.z,
                                (a2[r].w - mu) * rs * g1b.w + b1b.w);
        *reinterpret_cast<float4*>(outp + base + c1) = o1;
        *reinterpret_cast<float4*>(outp + base + c2) = o2;
    }
    __shared__ float rred[4];
    if (lane == 0) rred[wid] = rrw;
    __syncthreads();
    if (threadIdx.x == 0)
        rrpart[blockIdx.x] = rred[0] + rred[1] + rred[2] + rred[3];
}

// sum 2048 block partials -> loss_slots[0]
__global__ __launch_bounds__(256) void reduce_part_k(const float* __restrict__ part,
                                                     float* __restrict__ out) {
    float s = 0.f;
    for (int i = threadIdx.x; i < 2048; i += 256) s += part[i];
    s = wave_sum(s);
    __shared__ float red[4];
    const int wid = threadIdx.x >> 6, lane = threadIdx.x & 63;
    if (lane == 0) red[wid] = s;
    __syncthreads();
    if (threadIdx.x == 0)
        out[0] = (red[0] + red[1] + red[2] + red[3]) * (1.f / 32768.f);
}

extern "C" void kernel_launch(void* const* d_in, const int* in_sizes, int n_in,
                              void* d_out, int out_size, void* d_ws, size_t ws_size,
                              hipStream_t stream) {
    const float* query = (const float*)d_in[0];
    const float* value = (const float*)d_in[1];
    const float* mem_key = (const float*)d_in[2];
    const float* mem_value = (const float*)d_in[3];
    const float* q_w = (const float*)d_in[4];
    const float* q_b = (const float*)d_in[5];
    const float* v_w = (const float*)d_in[6];
    const float* v_b = (const float*)d_in[7];
    const float* out_w = (const float*)d_in[8];
    const float* out_b = (const float*)d_in[9];
    const float* ln1_g = (const float*)d_in[10];
    const float* ln1_b = (const float*)d_in[11];
    const float* ln3_g = (const float*)d_in[12];
    const float* ln3_b = (const float*)d_in[13];
    float* out = (float*)d_out;

    char* ws = (char*)d_ws;
    size_t off = 0;
    auto alloc = [&](size_t bytes) {
        void* p = ws + off;
        off += (bytes + 255) & ~(size_t)255;
        return p;
    };
    bf16_t* qpb = (bf16_t*)alloc(16777216ull * 2);     // qp bf16
    bf16_t* vpb = (bf16_t*)alloc(16777216ull * 2);     // v_proj bf16
    bf16_t* addr = (bf16_t*)alloc(32768ull * 896 * 2); // addr; addr2 aliases
    bf16_t* stageP = (bf16_t*)alloc(16777216ull * 2);  // attn_out bf16; attn_recon aliases
    bf16_t* qwb = (bf16_t*)alloc(262144ull * 2);
    bf16_t* vwb = (bf16_t*)alloc(262144ull * 2);
    bf16_t* owb = (bf16_t*)alloc(2097152ull * 2);
    bf16_t* wct = (bf16_t*)alloc(896ull * 512 * 2);    // WcT[512][896]
    bf16_t* keyn = (bf16_t*)alloc(896ull * 64 * 2);
    bf16_t* mvb = (bf16_t*)alloc(128ull * 512 * 2);    // padded to 128 rows
    bf16_t* mvT = (bf16_t*)alloc(512ull * 128 * 2);
    float* invmv = (float*)alloc(112 * 4);
    float* rrpart = (float*)alloc(2048 * 4);
    bf16_t* addr2 = addr;
    bf16_t* stageR = stageP;

    float* f_predict = out;
    float* f_recon = out + 16777216;
    float* loss_slots = out + 33554432;  // [recon_loss, contrastive_loss]

    // prep
    cast3_k<<<2560, 256, 0, stream>>>(q_w, v_w, out_w, qwb, vwb, owb);
    keyn_k<<<224, 256, 0, stream>>>(mem_key, keyn);
    mv_prep_k<<<128, 256, 0, stream>>>(mem_value, mvb, mvT, invmv, loss_slots);
    contrastive_k<<<112, 256, 0, stream>>>(mem_value, invmv, loss_slots + 1);
    // WcT[d][h*112+s] = sum_j out_w[d][h*512+j] * mem_value[s][j]
    gemm_bt<<<dim3(8, 2, 8), 256, 0, stream>>>(owb, 4096, 512, mvb, 512, 0,
                                               wct, 896, 112, 512, 112, 512);
    // both projections in one dispatch
    gemm_qv<<<dim3(256, 4, 2), 256, 0, stream>>>(query, value, qwb, vwb,
                                                 q_b, v_b, qpb, vpb);
    // predict branch
    addr_predict<<<dim3(512, 8), 256, 0, stream>>>(qpb, keyn, addr);
    gemm128_bb<<<dim3(256, 4), 256, 0, stream>>>(addr, 896, wct, 896, out_b,
                                                 stageP, 512, 896);
    ln_stream<<<2048, 256, 0, stream>>>(stageP, query, ln1_g, ln1_b, f_predict);
    // recon branch
    gemm_sim_softmax<<<256, 256, 0, stream>>>(vpb, mvb, invmv, addr2);
    gemm128_bb<<<dim3(256, 4), 256, 0, stream>>>(addr2, 128, mvT, 128,
                                                 (const float*)nullptr,
                                                 stageR, 512, 128);
    recon_ep_stream<<<2048, 256, 0, stream>>>(stageR, query, value,
                                              ln3_g, ln3_b, ln1_g, ln1_b,
                                              f_recon, rrpart);
    reduce_part_k<<<1, 256, 0, stream>>>(rrpart, loss_slots);
}

// Round 9
// 356.279 us; speedup vs baseline: 1.0188x; 1.0188x over previous
//
#include <hip/hip_runtime.h>
#include <hip/hip_bf16.h>
#include <math.h>

typedef __bf16 bf16_t;
typedef __attribute__((ext_vector_type(8))) __bf16 bf16x8;
typedef __attribute__((ext_vector_type(4))) __bf16 bf16x4;
typedef __attribute__((ext_vector_type(4))) float f32x4;

#define LN_EPS 1e-5f
#define RADIUS_F 16.0f

__device__ inline bf16x8 zero8() {
    bf16x8 v;
#pragma unroll
    for (int i = 0; i < 8; ++i) v[i] = (__bf16)0.f;
    return v;
}

__device__ inline float wave_sum(float v) {
#pragma unroll
    for (int o = 1; o < 64; o <<= 1) v += __shfl_xor(v, o);
    return v;
}

__device__ inline void gload_lds16(const bf16_t* g, bf16_t* l) {
    __builtin_amdgcn_global_load_lds(
        (const __attribute__((address_space(1))) void*)g,
        (__attribute__((address_space(3))) void*)l, 16, 0, 0);
}

__device__ inline void drain_barrier() {
    asm volatile("s_waitcnt vmcnt(0)" ::: "memory");
    __builtin_amdgcn_s_barrier();
}

// ---------------- one cast kernel for all three weights ----------------
__global__ __launch_bounds__(256) void cast3_k(const float* __restrict__ qw,
                                               const float* __restrict__ vw,
                                               const float* __restrict__ ow,
                                               bf16_t* __restrict__ qwb,
                                               bf16_t* __restrict__ vwb,
                                               bf16_t* __restrict__ owb) {
    int i = blockIdx.x * 256 + threadIdx.x;  // float4 index, total 655360
    const float* src;
    bf16_t* dst;
    int j;
    if (i < 65536) { src = qw; dst = qwb; j = i; }
    else if (i < 131072) { src = vw; dst = vwb; j = i - 65536; }
    else { src = ow; dst = owb; j = i - 131072; }
    float4 v = reinterpret_cast<const float4*>(src)[j];
    bf16x4 o;
    o[0] = (__bf16)v.x; o[1] = (__bf16)v.y; o[2] = (__bf16)v.z; o[3] = (__bf16)v.w;
    reinterpret_cast<bf16x4*>(dst)[j] = o;
}

// normalize mem_key rows (896 x 64) -> bf16
__global__ __launch_bounds__(256) void keyn_k(const float* __restrict__ mk,
                                              bf16_t* __restrict__ kn) {
    int row = blockIdx.x * 4 + (threadIdx.x >> 6);
    int lane = threadIdx.x & 63;
    float x = mk[(size_t)row * 64 + lane];
    float ss = wave_sum(x * x);
    kn[(size_t)row * 64 + lane] = (__bf16)(x / fmaxf(sqrtf(ss), 1e-12f));
}

// mem_value: row inv-norms + bf16 copy (padded to 128) + transposed copy; zero loss
__global__ __launch_bounds__(256) void mv_prep_k(const float* __restrict__ mv,
                                                 bf16_t* __restrict__ mvb,
                                                 bf16_t* __restrict__ mvT,
                                                 float* __restrict__ invmv,
                                                 float* __restrict__ loss_slots) {
    const int s = blockIdx.x, tid = threadIdx.x;
    if (s >= 112) {
        mvb[(size_t)s * 512 + tid * 2] = (__bf16)0.f;
        mvb[(size_t)s * 512 + tid * 2 + 1] = (__bf16)0.f;
        mvT[(size_t)tid * 128 + s] = (__bf16)0.f;
        mvT[(size_t)(tid + 256) * 128 + s] = (__bf16)0.f;
        return;
    }
    float2 x = *reinterpret_cast<const float2*>(mv + (size_t)s * 512 + tid * 2);
    float ss = wave_sum(x.x * x.x + x.y * x.y);
    __shared__ float red[4];
    int wid = tid >> 6, lane = tid & 63;
    if (lane == 0) red[wid] = ss;
    __syncthreads();
    ss = red[0] + red[1] + red[2] + red[3];
    if (tid == 0) invmv[s] = 1.f / fmaxf(sqrtf(ss), 1e-12f);
    mvb[(size_t)s * 512 + tid * 2] = (__bf16)x.x;
    mvb[(size_t)s * 512 + tid * 2 + 1] = (__bf16)x.y;
    mvT[(size_t)tid * 128 + s] = (__bf16)mv[(size_t)s * 512 + tid];
    mvT[(size_t)(tid + 256) * 128 + s] = (__bf16)mv[(size_t)s * 512 + tid + 256];
    if (s == 0 && tid < 2) loss_slots[tid] = 0.f;
}

// contrastive loss: sum |I - Gn Gn^T| * 0.01  (fp32)
__global__ __launch_bounds__(256) void contrastive_k(const float* __restrict__ mv,
                                                     const float* __restrict__ invmv,
                                                     float* __restrict__ out_slot) {
    const int a = blockIdx.x;
    const int tid = threadIdx.x, wid = tid >> 6, lane = tid & 63;
    __shared__ float rowa[512];
    __shared__ float wsum[4];
    for (int i = tid; i < 512; i += 256) rowa[i] = mv[(size_t)a * 512 + i];
    __syncthreads();
    float acc = 0.f;
    const float ia = invmv[a];
    for (int b = wid; b < 112; b += 4) {
        float d = 0.f;
#pragma unroll
        for (int i = 0; i < 8; ++i) d += rowa[lane + i * 64] * mv[(size_t)b * 512 + lane + i * 64];
        d = wave_sum(d);
        float gv = d * ia * invmv[b];
        acc += fabsf((a == b ? 1.f : 0.f) - gv);
    }
    if (lane == 0) wsum[wid] = acc;
    __syncthreads();
    if (tid == 0) atomicAdd(out_slot, (wsum[0] + wsum[1] + wsum[2] + wsum[3]) * 0.01f);
}

// ---------------- combined qp/v_proj GEMM: T3-minimum 2-phase pipeline ----------------
// dbuf LDS; STAGE(k+1) issued before MFMA(k); ONE barrier per K-step.
// blockIdx.z = 0: qp = query @ q_w^T + q_b ; z = 1: vp = value @ v_w^T + v_b
__global__ __launch_bounds__(256) void gemm_qv(
    const float* __restrict__ A0, const float* __restrict__ A1,
    const bf16_t* __restrict__ W0, const bf16_t* __restrict__ W1,
    const float* __restrict__ b0, const float* __restrict__ b1,
    bf16_t* __restrict__ C0, bf16_t* __restrict__ C1) {
    const float* A = blockIdx.z ? A1 : A0;
    const bf16_t* W = blockIdx.z ? W1 : W0;
    const float* bias = blockIdx.z ? b1 : b0;
    bf16_t* Cb = blockIdx.z ? C1 : C0;
    __shared__ __align__(16) bf16_t As[2][128 * 32];
    __shared__ __align__(16) bf16_t Bs[2][128 * 32];
    const int tid = threadIdx.x;
    const int wid = tid >> 6, lane = tid & 63;
    const int wr = wid >> 1, wc = wid & 1;
    const int lr = lane & 15;
    const int ko = (lane >> 4) * 8;
    const size_t rowBase = (size_t)blockIdx.x * 128;
    const size_t colBase = (size_t)blockIdx.y * 128;
    const int r0 = tid >> 2;
    const int c0 = (tid & 3) * 8;
    const float* a_src = A + (rowBase + r0) * 512 + c0;
    const bf16_t* w_src = W + (colBase + r0) * 512 + c0;
    f32x4 acc[4][4];
#pragma unroll
    for (int m = 0; m < 4; ++m)
#pragma unroll
        for (int n = 0; n < 4; ++n) {
            acc[m][n][0] = 0.f; acc[m][n][1] = 0.f;
            acc[m][n][2] = 0.f; acc[m][n][3] = 0.f;
        }
    // prologue: stage tile 0 into buf 0
    {
        gload_lds16(w_src, &Bs[0][tid * 8]);
        gload_lds16(w_src + (size_t)64 * 512, &Bs[0][2048 + tid * 8]);
        float4 a0 = *reinterpret_cast<const float4*>(a_src);
        float4 a1 = *reinterpret_cast<const float4*>(a_src + 4);
        float4 a2 = *reinterpret_cast<const float4*>(a_src + (size_t)64 * 512);
        float4 a3 = *reinterpret_cast<const float4*>(a_src + (size_t)64 * 512 + 4);
        bf16x8 p0, p1;
        p0[0] = (__bf16)a0.x; p0[1] = (__bf16)a0.y; p0[2] = (__bf16)a0.z; p0[3] = (__bf16)a0.w;
        p0[4] = (__bf16)a1.x; p0[5] = (__bf16)a1.y; p0[6] = (__bf16)a1.z; p0[7] = (__bf16)a1.w;
        p1[0] = (__bf16)a2.x; p1[1] = (__bf16)a2.y; p1[2] = (__bf16)a2.z; p1[3] = (__bf16)a2.w;
        p1[4] = (__bf16)a3.x; p1[5] = (__bf16)a3.y; p1[6] = (__bf16)a3.z; p1[7] = (__bf16)a3.w;
        *reinterpret_cast<bf16x8*>(&As[0][tid * 8]) = p0;
        *reinterpret_cast<bf16x8*>(&As[0][2048 + tid * 8]) = p1;
    }
    __syncthreads();
    int cur = 0;
    for (int ks = 0; ks < 16; ++ks) {
        const int nb = cur ^ 1;
        float4 a0, a1, a2, a3;
        if (ks < 15) {
            const int k1 = (ks + 1) * 32;
            // issue next-tile staging BEFORE compute (latency covered by MFMA)
            gload_lds16(w_src + k1, &Bs[nb][tid * 8]);
            gload_lds16(w_src + (size_t)64 * 512 + k1, &Bs[nb][2048 + tid * 8]);
            a0 = *reinterpret_cast<const float4*>(a_src + k1);
            a1 = *reinterpret_cast<const float4*>(a_src + k1 + 4);
            a2 = *reinterpret_cast<const float4*>(a_src + (size_t)64 * 512 + k1);
            a3 = *reinterpret_cast<const float4*>(a_src + (size_t)64 * 512 + k1 + 4);
        }
        bf16x8 af[4], bfr[4];
#pragma unroll
        for (int m = 0; m < 4; ++m)
            af[m] = *reinterpret_cast<const bf16x8*>(&As[cur][(wr * 64 + m * 16 + lr) * 32 + ko]);
#pragma unroll
        for (int n = 0; n < 4; ++n)
            bfr[n] = *reinterpret_cast<const bf16x8*>(&Bs[cur][(wc * 64 + n * 16 + lr) * 32 + ko]);
#pragma unroll
        for (int m = 0; m < 4; ++m)
#pragma unroll
            for (int n = 0; n < 4; ++n)
                acc[m][n] = __builtin_amdgcn_mfma_f32_16x16x32_bf16(af[m], bfr[n], acc[m][n], 0, 0, 0);
        if (ks < 15) {
            bf16x8 p0, p1;
            p0[0] = (__bf16)a0.x; p0[1] = (__bf16)a0.y; p0[2] = (__bf16)a0.z; p0[3] = (__bf16)a0.w;
            p0[4] = (__bf16)a1.x; p0[5] = (__bf16)a1.y; p0[6] = (__bf16)a1.z; p0[7] = (__bf16)a1.w;
            p1[0] = (__bf16)a2.x; p1[1] = (__bf16)a2.y; p1[2] = (__bf16)a2.z; p1[3] = (__bf16)a2.w;
            p1[4] = (__bf16)a3.x; p1[5] = (__bf16)a3.y; p1[6] = (__bf16)a3.z; p1[7] = (__bf16)a3.w;
            *reinterpret_cast<bf16x8*>(&As[nb][tid * 8]) = p0;
            *reinterpret_cast<bf16x8*>(&As[nb][2048 + tid * 8]) = p1;
        }
        __syncthreads();
        cur = nb;
    }
    const int rj = (lane >> 4) * 4;
#pragma unroll
    for (int n = 0; n < 4; ++n) {
        const int col = (int)colBase + wc * 64 + n * 16 + lr;
        const float bv = bias[col];
#pragma unroll
        for (int m = 0; m < 4; ++m) {
            const size_t r = rowBase + wr * 64 + m * 16 + rj;
#pragma unroll
            for (int j = 0; j < 4; ++j)
                Cb[(r + j) * 512 + col] = (__bf16)(acc[m][n][j] + bv);
        }
    }
}

// ---------------- 128x128 GEMM, bf16 A, bf16 out: T3-minimum 2-phase pipeline ----------------
__global__ __launch_bounds__(256) void gemm128_bb(
    const bf16_t* __restrict__ A, int lda,
    const bf16_t* __restrict__ W, int ldw,
    const float* __restrict__ bias,
    bf16_t* __restrict__ Cb, int ldc, int K) {
    __shared__ __align__(16) bf16_t As[2][128 * 32];
    __shared__ __align__(16) bf16_t Bs[2][128 * 32];
    const int tid = threadIdx.x;
    const int wid = tid >> 6, lane = tid & 63;
    const int wr = wid >> 1, wc = wid & 1;
    const int lr = lane & 15;
    const int ko = (lane >> 4) * 8;
    const size_t rowBase = (size_t)blockIdx.x * 128;
    const size_t colBase = (size_t)blockIdx.y * 128;
    const int r0 = tid >> 2;
    const int c0 = (tid & 3) * 8;
    const bf16_t* a_src = A + (rowBase + r0) * lda + c0;
    const bf16_t* w_src = W + (colBase + r0) * ldw + c0;
    f32x4 acc[4][4];
#pragma unroll
    for (int m = 0; m < 4; ++m)
#pragma unroll
        for (int n = 0; n < 4; ++n) {
            acc[m][n][0] = 0.f; acc[m][n][1] = 0.f;
            acc[m][n][2] = 0.f; acc[m][n][3] = 0.f;
        }
    auto stage = [&](int buf, int ks) {
        const int k0 = ks * 32;
        gload_lds16(a_src + k0, &As[buf][tid * 8]);
        gload_lds16(a_src + (size_t)64 * lda + k0, &As[buf][2048 + tid * 8]);
        gload_lds16(w_src + k0, &Bs[buf][tid * 8]);
        gload_lds16(w_src + (size_t)64 * ldw + k0, &Bs[buf][2048 + tid * 8]);
    };
    stage(0, 0);
    __syncthreads();
    const int nt = K >> 5;
    int cur = 0;
    for (int ks = 0; ks < nt; ++ks) {
        const int nb = cur ^ 1;
        if (ks + 1 < nt) stage(nb, ks + 1);  // issued BEFORE compute; drained at barrier
        bf16x8 af[4], bfr[4];
#pragma unroll
        for (int m = 0; m < 4; ++m)
            af[m] = *reinterpret_cast<const bf16x8*>(&As[cur][(wr * 64 + m * 16 + lr) * 32 + ko]);
#pragma unroll
        for (int n = 0; n < 4; ++n)
            bfr[n] = *reinterpret_cast<const bf16x8*>(&Bs[cur][(wc * 64 + n * 16 + lr) * 32 + ko]);
#pragma unroll
        for (int m = 0; m < 4; ++m)
#pragma unroll
            for (int n = 0; n < 4; ++n)
                acc[m][n] = __builtin_amdgcn_mfma_f32_16x16x32_bf16(af[m], bfr[n], acc[m][n], 0, 0, 0);
        __syncthreads();
        cur = nb;
    }
    const int rj = (lane >> 4) * 4;
#pragma unroll
    for (int n = 0; n < 4; ++n) {
        const int col = (int)colBase + wc * 64 + n * 16 + lr;
        const float bv = bias ? bias[col] : 0.f;
#pragma unroll
        for (int m = 0; m < 4; ++m) {
            const size_t r = rowBase + wr * 64 + m * 16 + rj;
#pragma unroll
            for (int j = 0; j < 4; ++j)
                Cb[(r + j) * ldc + col] = (__bf16)(acc[m][n][j] + bv);
        }
    }
}

// ---------------- small direct GEMM (WcT fold only) ----------------
__global__ __launch_bounds__(256) void gemm_bt(
    const bf16_t* __restrict__ A, int lda, int aZ,
    const bf16_t* __restrict__ W, int ldw, int wZ,
    bf16_t* __restrict__ Cb, int ldc, int cZ,
    int M, int N, int K) {
    const int wid = threadIdx.x >> 6;
    const int lane = threadIdx.x & 63;
    const int lr = lane & 15;
    const int kk = (lane >> 4) * 8;
    const int row0 = blockIdx.x * 64 + wid * 16;
    const int col0 = blockIdx.y * 64;
    A += (size_t)blockIdx.z * aZ;
    W += (size_t)blockIdx.z * wZ;
    const bf16_t* a_ptr = A + (size_t)(row0 + lr) * lda + kk;
    const bf16_t* w_ptr = W + (size_t)(col0 + lr) * ldw + kk;
    f32x4 acc[4];
#pragma unroll
    for (int t = 0; t < 4; ++t) { acc[t][0] = 0.f; acc[t][1] = 0.f; acc[t][2] = 0.f; acc[t][3] = 0.f; }
    bool colv[4];
#pragma unroll
    for (int t = 0; t < 4; ++t) colv[t] = (col0 + t * 16 + lr) < N;
    for (int k0 = 0; k0 < K; k0 += 32) {
        bf16x8 a = *reinterpret_cast<const bf16x8*>(a_ptr + k0);
#pragma unroll
        for (int t = 0; t < 4; ++t) {
            bf16x8 b;
            if (colv[t]) b = *reinterpret_cast<const bf16x8*>(w_ptr + (size_t)t * 16 * ldw + k0);
            else b = zero8();
            acc[t] = __builtin_amdgcn_mfma_f32_16x16x32_bf16(a, b, acc[t], 0, 0, 0);
        }
    }
    const int rb = (lane >> 4) * 4;
    Cb += (size_t)blockIdx.z * cZ;
#pragma unroll
    for (int t = 0; t < 4; ++t) {
        int col = col0 + t * 16 + lr;
        if (col >= N) continue;
#pragma unroll
        for (int j = 0; j < 4; ++j) {
            int r = row0 + rb + j;
            Cb[(size_t)r * ldc + col] = (__bf16)acc[t][j];
        }
    }
}

// ---------------- predict addressing: sim -> softmax -> addr bf16 [N,896] ----------------
__global__ __launch_bounds__(256) void addr_predict(const bf16_t* __restrict__ qp,
                                                    const bf16_t* __restrict__ keyn,
                                                    bf16_t* __restrict__ addr) {
    const int wid = threadIdx.x >> 6, lane = threadIdx.x & 63;
    const int lr = lane & 15, kk = (lane >> 4) * 8;
    const int h = blockIdx.y;
    const int row0 = blockIdx.x * 64 + wid * 16;
    const bf16_t* a_ptr = qp + (size_t)(row0 + lr) * 512 + h * 64 + kk;
    bf16x8 a0 = *reinterpret_cast<const bf16x8*>(a_ptr);
    bf16x8 a1 = *reinterpret_cast<const bf16x8*>(a_ptr + 32);
    float ssq = 0.f;
#pragma unroll
    for (int j = 0; j < 8; ++j) {
        float x = (float)a0[j], y = (float)a1[j];
        ssq += x * x + y * y;
    }
    ssq += __shfl_xor(ssq, 16);
    ssq += __shfl_xor(ssq, 32);
    const float invq = 1.f / fmaxf(sqrtf(ssq), 1e-12f);
    f32x4 acc[7];
#pragma unroll
    for (int t = 0; t < 7; ++t) {
        const bf16_t* b_ptr = keyn + (size_t)(h * 112 + t * 16 + lr) * 64 + kk;
        bf16x8 b0 = *reinterpret_cast<const bf16x8*>(b_ptr);
        bf16x8 b1 = *reinterpret_cast<const bf16x8*>(b_ptr + 32);
        f32x4 c; c[0] = 0.f; c[1] = 0.f; c[2] = 0.f; c[3] = 0.f;
        c = __builtin_amdgcn_mfma_f32_16x16x32_bf16(a0, b0, c, 0, 0, 0);
        c = __builtin_amdgcn_mfma_f32_16x16x32_bf16(a1, b1, c, 0, 0, 0);
        acc[t] = c;
    }
    const int rb = (lane >> 4) * 4;
    float iq[4];
#pragma unroll
    for (int j = 0; j < 4; ++j) iq[j] = __shfl(invq, rb + j);
#pragma unroll
    for (int j = 0; j < 4; ++j) {
        float m = -1e30f;
#pragma unroll
        for (int t = 0; t < 7; ++t) { acc[t][j] *= iq[j] * RADIUS_F; m = fmaxf(m, acc[t][j]); }
#pragma unroll
        for (int o = 1; o < 16; o <<= 1) m = fmaxf(m, __shfl_xor(m, o));
        float s = 0.f;
#pragma unroll
        for (int t = 0; t < 7; ++t) { float e = __expf(acc[t][j] - m); acc[t][j] = e; s += e; }
#pragma unroll
        for (int o = 1; o < 16; o <<= 1) s += __shfl_xor(s, o);
        const float rs = 1.f / s;
#pragma unroll
        for (int t = 0; t < 7; ++t) acc[t][j] *= rs;
    }
#pragma unroll
    for (int t = 0; t < 7; ++t)
#pragma unroll
        for (int j = 0; j < 4; ++j)
            addr[(size_t)(row0 + rb + j) * 896 + h * 112 + t * 16 + lr] = (__bf16)acc[t][j];
}

// ---------------- fused recon sim GEMM + softmax -> addr2 [M][128] ----------------
__global__ __launch_bounds__(256, 2) void gemm_sim_softmax(
    const bf16_t* __restrict__ vp,   // [M][512]
    const bf16_t* __restrict__ mvb,  // [128][512] (rows 112..127 zero)
    const float* __restrict__ invmv, // [112]
    bf16_t* __restrict__ addr2) {    // [M][128]
    __shared__ __align__(16) bf16_t As[2][128 * 32];
    __shared__ __align__(16) bf16_t Bs[2][128 * 32];
    const int tid = threadIdx.x;
    const int wid = tid >> 6, lane = tid & 63;
    const int lr = lane & 15, hi = lane >> 4;
    const int ko = hi * 8;
    const size_t rowBase = (size_t)blockIdx.x * 128;
    const int r0 = tid >> 2, c0 = (tid & 3) * 8;
    const bf16_t* a_src = vp + (rowBase + r0) * 512 + c0;
    const bf16_t* b_src = mvb + (size_t)r0 * 512 + c0;
    f32x4 acc[2][8];
#pragma unroll
    for (int m = 0; m < 2; ++m)
#pragma unroll
        for (int n = 0; n < 8; ++n) {
            acc[m][n][0] = 0.f; acc[m][n][1] = 0.f;
            acc[m][n][2] = 0.f; acc[m][n][3] = 0.f;
        }
    float ssq[2] = {0.f, 0.f};
    auto stage = [&](int buf, int ks) {
        const int k0 = ks * 32;
        gload_lds16(a_src + k0, &As[buf][tid * 8]);
        gload_lds16(a_src + (size_t)64 * 512 + k0, &As[buf][2048 + tid * 8]);
        gload_lds16(b_src + k0, &Bs[buf][tid * 8]);
        gload_lds16(b_src + (size_t)64 * 512 + k0, &Bs[buf][2048 + tid * 8]);
    };
    stage(0, 0);
    drain_barrier();
    int cur = 0;
    for (int ks = 0; ks < 16; ++ks) {
        if (ks < 15) stage(cur ^ 1, ks + 1);
        bf16x8 af[2], bfr[8];
#pragma unroll
        for (int m = 0; m < 2; ++m)
            af[m] = *reinterpret_cast<const bf16x8*>(&As[cur][(wid * 32 + m * 16 + lr) * 32 + ko]);
#pragma unroll
        for (int n = 0; n < 8; ++n)
            bfr[n] = *reinterpret_cast<const bf16x8*>(&Bs[cur][(n * 16 + lr) * 32 + ko]);
#pragma unroll
        for (int m = 0; m < 2; ++m) {
#pragma unroll
            for (int j = 0; j < 8; ++j) { float x = (float)af[m][j]; ssq[m] += x * x; }
#pragma unroll
            for (int n = 0; n < 8; ++n)
                acc[m][n] = __builtin_amdgcn_mfma_f32_16x16x32_bf16(af[m], bfr[n], acc[m][n], 0, 0, 0);
        }
        drain_barrier();
        cur ^= 1;
    }
#pragma unroll
    for (int m = 0; m < 2; ++m) {
        ssq[m] += __shfl_xor(ssq[m], 16);
        ssq[m] += __shfl_xor(ssq[m], 32);
        ssq[m] = 1.f / fmaxf(sqrtf(ssq[m]), 1e-12f);
    }
    const int rb = hi * 4;
    float imv[7];
#pragma unroll
    for (int n = 0; n < 7; ++n) imv[n] = invmv[n * 16 + lr];
#pragma unroll
    for (int m = 0; m < 2; ++m)
#pragma unroll
        for (int j = 0; j < 4; ++j) {
            const float iq = __shfl(ssq[m], (lane & 48) | (rb + j));
            float x[7];
            float mx = -1e30f;
#pragma unroll
            for (int n = 0; n < 7; ++n) {
                x[n] = acc[m][n][j] * iq * imv[n] * RADIUS_F;
                mx = fmaxf(mx, x[n]);
            }
#pragma unroll
            for (int o = 1; o < 16; o <<= 1) mx = fmaxf(mx, __shfl_xor(mx, o));
            float s = 0.f;
#pragma unroll
            for (int n = 0; n < 7; ++n) { x[n] = __expf(x[n] - mx); s += x[n]; }
#pragma unroll
            for (int o = 1; o < 16; o <<= 1) s += __shfl_xor(s, o);
            const float rs = 1.f / s;
            const size_t row = rowBase + wid * 32 + m * 16 + rb + j;
#pragma unroll
            for (int n = 0; n < 7; ++n)
                addr2[row * 128 + n * 16 + lr] = (__bf16)(x[n] * rs);
            addr2[row * 128 + 112 + lr] = (__bf16)0.f;
        }
}

// ---------------- streaming LN (predict): 4 rows/wave, bf16 stage input ----------------
__global__ __launch_bounds__(256) void ln_stream(
    const bf16_t* __restrict__ stage, const float* __restrict__ query,
    const float* __restrict__ g, const float* __restrict__ b,
    float* __restrict__ outp) {
    const int wid = threadIdx.x >> 6, lane = threadIdx.x & 63;
    const size_t row0 = (size_t)blockIdx.x * 16 + wid * 4;
    const int c1 = lane * 8, c2 = lane * 8 + 4;
    float4 x1[4], x2[4];
    float s1[4], s2[4];
#pragma unroll
    for (int r = 0; r < 4; ++r) {
        const size_t base = (row0 + r) * 512;
        bf16x8 a = *reinterpret_cast<const bf16x8*>(stage + base + c1);
        float4 q1 = *reinterpret_cast<const float4*>(query + base + c1);
        float4 q2 = *reinterpret_cast<const float4*>(query + base + c2);
        x1[r] = make_float4(q1.x + (float)a[0], q1.y + (float)a[1],
                            q1.z + (float)a[2], q1.w + (float)a[3]);
        x2[r] = make_float4(q2.x + (float)a[4], q2.y + (float)a[5],
                            q2.z + (float)a[6], q2.w + (float)a[7]);
        s1[r] = x1[r].x + x1[r].y + x1[r].z + x1[r].w + x2[r].x + x2[r].y + x2[r].z + x2[r].w;
        s2[r] = x1[r].x * x1[r].x + x1[r].y * x1[r].y + x1[r].z * x1[r].z + x1[r].w * x1[r].w +
                x2[r].x * x2[r].x + x2[r].y * x2[r].y + x2[r].z * x2[r].z + x2[r].w * x2[r].w;
    }
#pragma unroll
    for (int o = 1; o < 64; o <<= 1)
#pragma unroll
        for (int r = 0; r < 4; ++r) {
            s1[r] += __shfl_xor(s1[r], o);
            s2[r] += __shfl_xor(s2[r], o);
        }
    const float4 g1v = *reinterpret_cast<const float4*>(g + c1);
    const float4 g2v = *reinterpret_cast<const float4*>(g + c2);
    const float4 b1v = *reinterpret_cast<const float4*>(b + c1);
    const float4 b2v = *reinterpret_cast<const float4*>(b + c2);
#pragma unroll
    for (int r = 0; r < 4; ++r) {
        const size_t base = (row0 + r) * 512;
        const float mu = s1[r] * (1.f / 512.f);
        const float rs = rsqrtf(s2[r] * (1.f / 512.f) - mu * mu + LN_EPS);
        float4 o1 = make_float4((x1[r].x - mu) * rs * g1v.x + b1v.x,
                                (x1[r].y - mu) * rs * g1v.y + b1v.y,
                                (x1[r].z - mu) * rs * g1v.z + b1v.z,
                                (x1[r].w - mu) * rs * g1v.w + b1v.w);
        float4 o2 = make_float4((x2[r].x - mu) * rs * g2v.x + b2v.x,
                                (x2[r].y - mu) * rs * g2v.y + b2v.y,
                                (x2[r].z - mu) * rs * g2v.z + b2v.z,
                                (x2[r].w - mu) * rs * g2v.w + b2v.w);
        *reinterpret_cast<float4*>(outp + base + c1) = o1;
        *reinterpret_cast<float4*>(outp + base + c2) = o2;
    }
}

// ---------------- streaming recon epilogue: bf16 stage, no global atomics ----------------
__global__ __launch_bounds__(256) void recon_ep_stream(
    const bf16_t* __restrict__ stage,
    const float* __restrict__ query, const float* __restrict__ value,
    const float* __restrict__ g3, const float* __restrict__ b3,
    const float* __restrict__ g1, const float* __restrict__ b1,
    float* __restrict__ outp, float* __restrict__ rrpart) {
    const int wid = threadIdx.x >> 6, lane = threadIdx.x & 63;
    const size_t row0 = (size_t)blockIdx.x * 16 + wid * 4;
    const int c1 = lane * 8, c2 = lane * 8 + 4;
    float4 a1[4], a2[4];
    float sa[4], sa2[4], sav[4], sv2[4];
#pragma unroll
    for (int r = 0; r < 4; ++r) {
        const size_t base = (row0 + r) * 512;
        bf16x8 a = *reinterpret_cast<const bf16x8*>(stage + base + c1);
        a1[r] = make_float4((float)a[0], (float)a[1], (float)a[2], (float)a[3]);
        a2[r] = make_float4((float)a[4], (float)a[5], (float)a[6], (float)a[7]);
        float4 v1 = *reinterpret_cast<const float4*>(value + base + c1);
        float4 v2 = *reinterpret_cast<const float4*>(value + base + c2);
        sa[r] = a1[r].x + a1[r].y + a1[r].z + a1[r].w + a2[r].x + a2[r].y + a2[r].z + a2[r].w;
        sa2[r] = a1[r].x * a1[r].x + a1[r].y * a1[r].y + a1[r].z * a1[r].z + a1[r].w * a1[r].w +
                 a2[r].x * a2[r].x + a2[r].y * a2[r].y + a2[r].z * a2[r].z + a2[r].w * a2[r].w;
        sav[r] = a1[r].x * v1.x + a1[r].y * v1.y + a1[r].z * v1.z + a1[r].w * v1.w +
                 a2[r].x * v2.x + a2[r].y * v2.y + a2[r].z * v2.z + a2[r].w * v2.w;
        sv2[r] = v1.x * v1.x + v1.y * v1.y + v1.z * v1.z + v1.w * v1.w +
                 v2.x * v2.x + v2.y * v2.y + v2.z * v2.z + v2.w * v2.w;
    }
#pragma unroll
    for (int o = 1; o < 64; o <<= 1)
#pragma unroll
        for (int r = 0; r < 4; ++r) {
            sa[r] += __shfl_xor(sa[r], o);
            sa2[r] += __shfl_xor(sa2[r], o);
            sav[r] += __shfl_xor(sav[r], o);
            sv2[r] += __shfl_xor(sv2[r], o);
        }
    float rrw = 0.f;
#pragma unroll
    for (int r = 0; r < 4; ++r) {
        const float na = fmaxf(sqrtf(sa2[r]), 1e-12f);
        const float nv = fmaxf(sqrtf(sv2[r]), 1e-12f);
        rrw += fabsf(1.f - sav[r] / (na * nv));
    }
    const float4 g3a = *reinterpret_cast<const float4*>(g3 + c1);
    const float4 g3b = *reinterpret_cast<const float4*>(g3 + c2);
    const float4 b3a = *reinterpret_cast<const float4*>(b3 + c1);
    const float4 b3b = *reinterpret_cast<const float4*>(b3 + c2);
    float s1[4], s2[4];
#pragma unroll
    for (int r = 0; r < 4; ++r) {
        const size_t base = (row0 + r) * 512;
        const float mu3 = sa[r] * (1.f / 512.f);
        const float r3 = rsqrtf(sa2[r] * (1.f / 512.f) - mu3 * mu3 + LN_EPS);
        float4 q1 = *reinterpret_cast<const float4*>(query + base + c1);
        float4 q2 = *reinterpret_cast<const float4*>(query + base + c2);
        a1[r] = make_float4(q1.x + (a1[r].x - mu3) * r3 * g3a.x + b3a.x,
                            q1.y + (a1[r].y - mu3) * r3 * g3a.y + b3a.y,
                            q1.z + (a1[r].z - mu3) * r3 * g3a.z + b3a.z,
                            q1.w + (a1[r].w - mu3) * r3 * g3a.w + b3a.w);
        a2[r] = make_float4(q2.x + (a2[r].x - mu3) * r3 * g3b.x + b3b.x,
                            q2.y + (a2[r].y - mu3) * r3 * g3b.y + b3b.y,
                            q2.z + (a2[r].z - mu3) * r3 * g3b.z + b3b.z,
                            q2.w + (a2[r].w - mu3) * r3 * g3b.w + b3b.w);
        s1[r] = a1[r].x + a1[r].y + a1[r].z + a1[r].w + a2[r].x + a2[r].y + a2[r].z + a2[r].w;
        s2[r] = a1[r].x * a1[r].x + a1[r].y * a1[r].y + a1[r].z * a1[r].z + a1[r].w * a1[r].w +
                a2[r].x * a2[r].x + a2[r].y * a2[r].y + a2[r].z * a2[r].z + a2[r].w * a2[r].w;
    }
#pragma unroll
    for (int o = 1; o < 64; o <<= 1)
#pragma unroll
        for (int r = 0; r < 4; ++r) {
            s1[r] += __shfl_xor(s1[r], o);
            s2[r] += __shfl_xor(s2[r], o);
        }
    const float4 g1a = *reinterpret_cast<const float4*>(g1 + c1);
    const float4 g1b = *reinterpret_cast<const float4*>(g1 + c2);
    const float4 b1a = *reinterpret_cast<const float4*>(b1 + c1);
    const float4 b1b = *reinterpret_cast<const float4*>(b1 + c2);
#pragma unroll
    for (int r = 0; r < 4; ++r) {
        const size_t base = (row0 + r) * 512;
        const float mu = s1[r] * (1.f / 512.f);
        const float rs = rsqrtf(s2[r] * (1.f / 512.f) - mu * mu + LN_EPS);
        float4 o1 = make_float4((a1[r].x - mu) * rs * g1a.x + b1a.x,
                                (a1[r].y - mu) * rs * g1a.y + b1a.y,
                                (a1[r].z - mu) * rs * g1a.z + b1a.z,
                                (a1[r].w - mu) * rs * g1a.w + b1a.w);
        float4 o2 = make_float4((a2[r].x - mu) * rs * g1b.x + b1b.x,
                                (a2[r].y - mu) * rs * g1b.y + b1b.y,
                                (a2[r].z - mu) * rs * g1b.z + b1b.z,
                                (a2[r].w - mu) * rs * g1b.w + b1b.w);
        *reinterpret_cast<float4*>(outp + base + c1) = o1;
        *reinterpret_cast<float4*>(outp + base + c2) = o2;
    }
    __shared__ float rred[4];
    if (lane == 0) rred[wid] = rrw;
    __syncthreads();
    if (threadIdx.x == 0)
        rrpart[blockIdx.x] = rred[0] + rred[1] + rred[2] + rred[3];
}

// sum 2048 block partials -> loss_slots[0]
__global__ __launch_bounds__(256) void reduce_part_k(const float* __restrict__ part,
                                                     float* __restrict__ out) {
    float s = 0.f;
    for (int i = threadIdx.x; i < 2048; i += 256) s += part[i];
    s = wave_sum(s);
    __shared__ float red[4];
    const int wid = threadIdx.x >> 6, lane = threadIdx.x & 63;
    if (lane == 0) red[wid] = s;
    __syncthreads();
    if (threadIdx.x == 0)
        out[0] = (red[0] + red[1] + red[2] + red[3]) * (1.f / 32768.f);
}

extern "C" void kernel_launch(void* const* d_in, const int* in_sizes, int n_in,
                              void* d_out, int out_size, void* d_ws, size_t ws_size,
                              hipStream_t stream) {
    const float* query = (const float*)d_in[0];
    const float* value = (const float*)d_in[1];
    const float* mem_key = (const float*)d_in[2];
    const float* mem_value = (const float*)d_in[3];
    const float* q_w = (const float*)d_in[4];
    const float* q_b = (const float*)d_in[5];
    const float* v_w = (const float*)d_in[6];
    const float* v_b = (const float*)d_in[7];
    const float* out_w = (const float*)d_in[8];
    const float* out_b = (const float*)d_in[9];
    const float* ln1_g = (const float*)d_in[10];
    const float* ln1_b = (const float*)d_in[11];
    const float* ln3_g = (const float*)d_in[12];
    const float* ln3_b = (const float*)d_in[13];
    float* out = (float*)d_out;

    char* ws = (char*)d_ws;
    size_t off = 0;
    auto alloc = [&](size_t bytes) {
        void* p = ws + off;
        off += (bytes + 255) & ~(size_t)255;
        return p;
    };
    bf16_t* qpb = (bf16_t*)alloc(16777216ull * 2);     // qp bf16
    bf16_t* vpb = (bf16_t*)alloc(16777216ull * 2);     // v_proj bf16
    bf16_t* addr = (bf16_t*)alloc(32768ull * 896 * 2); // addr; addr2 aliases
    bf16_t* stageP = (bf16_t*)alloc(16777216ull * 2);  // attn_out bf16; attn_recon aliases
    bf16_t* qwb = (bf16_t*)alloc(262144ull * 2);
    bf16_t* vwb = (bf16_t*)alloc(262144ull * 2);
    bf16_t* owb = (bf16_t*)alloc(2097152ull * 2);
    bf16_t* wct = (bf16_t*)alloc(896ull * 512 * 2);    // WcT[512][896]
    bf16_t* keyn = (bf16_t*)alloc(896ull * 64 * 2);
    bf16_t* mvb = (bf16_t*)alloc(128ull * 512 * 2);    // padded to 128 rows
    bf16_t* mvT = (bf16_t*)alloc(512ull * 128 * 2);
    float* invmv = (float*)alloc(112 * 4);
    float* rrpart = (float*)alloc(2048 * 4);
    bf16_t* addr2 = addr;
    bf16_t* stageR = stageP;

    float* f_predict = out;
    float* f_recon = out + 16777216;
    float* loss_slots = out + 33554432;  // [recon_loss, contrastive_loss]

    // prep
    cast3_k<<<2560, 256, 0, stream>>>(q_w, v_w, out_w, qwb, vwb, owb);
    keyn_k<<<224, 256, 0, stream>>>(mem_key, keyn);
    mv_prep_k<<<128, 256, 0, stream>>>(mem_value, mvb, mvT, invmv, loss_slots);
    contrastive_k<<<112, 256, 0, stream>>>(mem_value, invmv, loss_slots + 1);
    // WcT[d][h*112+s] = sum_j out_w[d][h*512+j] * mem_value[s][j]
    gemm_bt<<<dim3(8, 2, 8), 256, 0, stream>>>(owb, 4096, 512, mvb, 512, 0,
                                               wct, 896, 112, 512, 112, 512);
    // both projections in one dispatch (pipelined)
    gemm_qv<<<dim3(256, 4, 2), 256, 0, stream>>>(query, value, qwb, vwb,
                                                 q_b, v_b, qpb, vpb);
    // predict branch
    addr_predict<<<dim3(512, 8), 256, 0, stream>>>(qpb, keyn, addr);
    gemm128_bb<<<dim3(256, 4), 256, 0, stream>>>(addr, 896, wct, 896, out_b,
                                                 stageP, 512, 896);
    ln_stream<<<2048, 256, 0, stream>>>(stageP, query, ln1_g, ln1_b, f_predict);
    // recon branch
    gemm_sim_softmax<<<256, 256, 0, stream>>>(vpb, mvb, invmv, addr2);
    gemm128_bb<<<dim3(256, 4), 256, 0, stream>>>(addr2, 128, mvT, 128,
                                                 (const float*)nullptr,
                                                 stageR, 512, 128);
    recon_ep_stream<<<2048, 256, 0, stream>>>(stageR, query, value,
                                              ln3_g, ln3_b, ln1_g, ln1_b,
                                              f_recon, rrpart);
    reduce_part_k<<<1, 256, 0, stream>>>(rrpart, loss_slots);
}

// Round 10
// 325.012 us; speedup vs baseline: 1.1168x; 1.0962x over previous
//
#include <hip/hip_runtime.h>
#include <hip/hip_bf16.h>
#include <math.h>

typedef __bf16 bf16_t;
typedef __attribute__((ext_vector_type(8))) __bf16 bf16x8;
typedef __attribute__((ext_vector_type(4))) __bf16 bf16x4;
typedef __attribute__((ext_vector_type(4))) float f32x4;

#define LN_EPS 1e-5f
#define RADIUS_F 16.0f

__device__ inline bf16x8 zero8() {
    bf16x8 v;
#pragma unroll
    for (int i = 0; i < 8; ++i) v[i] = (__bf16)0.f;
    return v;
}

__device__ inline float wave_sum(float v) {
#pragma unroll
    for (int o = 1; o < 64; o <<= 1) v += __shfl_xor(v, o);
    return v;
}

__device__ inline void gload_lds16(const bf16_t* g, bf16_t* l) {
    __builtin_amdgcn_global_load_lds(
        (const __attribute__((address_space(1))) void*)g,
        (__attribute__((address_space(3))) void*)l, 16, 0, 0);
}

__device__ inline void drain_barrier() {
    asm volatile("s_waitcnt vmcnt(0)" ::: "memory");
    __builtin_amdgcn_s_barrier();
}

// ---------------- one grid-stride cast for q, v, and all three weights ----------------
__global__ __launch_bounds__(256) void cast_all(
    const float* __restrict__ q, const float* __restrict__ v,
    const float* __restrict__ qw, const float* __restrict__ vw,
    const float* __restrict__ ow,
    bf16_t* __restrict__ qb, bf16_t* __restrict__ vb,
    bf16_t* __restrict__ qwb, bf16_t* __restrict__ vwb,
    bf16_t* __restrict__ owb) {
    const int total = 9043968;  // float4 count: 4194304+4194304+65536+65536+524288
    for (int i = blockIdx.x * 256 + threadIdx.x; i < total; i += gridDim.x * 256) {
        const float* src;
        bf16_t* dst;
        int j;
        if (i < 4194304) { src = q; dst = qb; j = i; }
        else if (i < 8388608) { src = v; dst = vb; j = i - 4194304; }
        else if (i < 8454144) { src = qw; dst = qwb; j = i - 8388608; }
        else if (i < 8519680) { src = vw; dst = vwb; j = i - 8454144; }
        else { src = ow; dst = owb; j = i - 8519680; }
        float4 x = reinterpret_cast<const float4*>(src)[j];
        bf16x4 o;
        o[0] = (__bf16)x.x; o[1] = (__bf16)x.y; o[2] = (__bf16)x.z; o[3] = (__bf16)x.w;
        reinterpret_cast<bf16x4*>(dst)[j] = o;
    }
}

// normalize mem_key rows (896 x 64) -> bf16
__global__ __launch_bounds__(256) void keyn_k(const float* __restrict__ mk,
                                              bf16_t* __restrict__ kn) {
    int row = blockIdx.x * 4 + (threadIdx.x >> 6);
    int lane = threadIdx.x & 63;
    float x = mk[(size_t)row * 64 + lane];
    float ss = wave_sum(x * x);
    kn[(size_t)row * 64 + lane] = (__bf16)(x / fmaxf(sqrtf(ss), 1e-12f));
}

// mem_value: row inv-norms + bf16 copy (padded to 128) + transposed copy; zero loss
__global__ __launch_bounds__(256) void mv_prep_k(const float* __restrict__ mv,
                                                 bf16_t* __restrict__ mvb,
                                                 bf16_t* __restrict__ mvT,
                                                 float* __restrict__ invmv,
                                                 float* __restrict__ loss_slots) {
    const int s = blockIdx.x, tid = threadIdx.x;
    if (s >= 112) {
        mvb[(size_t)s * 512 + tid * 2] = (__bf16)0.f;
        mvb[(size_t)s * 512 + tid * 2 + 1] = (__bf16)0.f;
        mvT[(size_t)tid * 128 + s] = (__bf16)0.f;
        mvT[(size_t)(tid + 256) * 128 + s] = (__bf16)0.f;
        return;
    }
    float2 x = *reinterpret_cast<const float2*>(mv + (size_t)s * 512 + tid * 2);
    float ss = wave_sum(x.x * x.x + x.y * x.y);
    __shared__ float red[4];
    int wid = tid >> 6, lane = tid & 63;
    if (lane == 0) red[wid] = ss;
    __syncthreads();
    ss = red[0] + red[1] + red[2] + red[3];
    if (tid == 0) invmv[s] = 1.f / fmaxf(sqrtf(ss), 1e-12f);
    mvb[(size_t)s * 512 + tid * 2] = (__bf16)x.x;
    mvb[(size_t)s * 512 + tid * 2 + 1] = (__bf16)x.y;
    mvT[(size_t)tid * 128 + s] = (__bf16)mv[(size_t)s * 512 + tid];
    mvT[(size_t)(tid + 256) * 128 + s] = (__bf16)mv[(size_t)s * 512 + tid + 256];
    if (s == 0 && tid < 2) loss_slots[tid] = 0.f;
}

// contrastive loss: sum |I - Gn Gn^T| * 0.01  (fp32)
__global__ __launch_bounds__(256) void contrastive_k(const float* __restrict__ mv,
                                                     const float* __restrict__ invmv,
                                                     float* __restrict__ out_slot) {
    const int a = blockIdx.x;
    const int tid = threadIdx.x, wid = tid >> 6, lane = tid & 63;
    __shared__ float rowa[512];
    __shared__ float wsum[4];
    for (int i = tid; i < 512; i += 256) rowa[i] = mv[(size_t)a * 512 + i];
    __syncthreads();
    float acc = 0.f;
    const float ia = invmv[a];
    for (int b = wid; b < 112; b += 4) {
        float d = 0.f;
#pragma unroll
        for (int i = 0; i < 8; ++i) d += rowa[lane + i * 64] * mv[(size_t)b * 512 + lane + i * 64];
        d = wave_sum(d);
        float gv = d * ia * invmv[b];
        acc += fabsf((a == b ? 1.f : 0.f) - gv);
    }
    if (lane == 0) wsum[wid] = acc;
    __syncthreads();
    if (tid == 0) atomicAdd(out_slot, (wsum[0] + wsum[1] + wsum[2] + wsum[3]) * 0.01f);
}

// ---------------- 128x128 GEMM, bf16 A, bf16 out: 2-phase dbuf pipeline ----------------
__global__ __launch_bounds__(256) void gemm128_bb(
    const bf16_t* __restrict__ A, int lda,
    const bf16_t* __restrict__ W, int ldw,
    const float* __restrict__ bias,
    bf16_t* __restrict__ Cb, int ldc, int K) {
    __shared__ __align__(16) bf16_t As[2][128 * 32];
    __shared__ __align__(16) bf16_t Bs[2][128 * 32];
    const int tid = threadIdx.x;
    const int wid = tid >> 6, lane = tid & 63;
    const int wr = wid >> 1, wc = wid & 1;
    const int lr = lane & 15;
    const int ko = (lane >> 4) * 8;
    const size_t rowBase = (size_t)blockIdx.x * 128;
    const size_t colBase = (size_t)blockIdx.y * 128;
    const int r0 = tid >> 2;
    const int c0 = (tid & 3) * 8;
    const bf16_t* a_src = A + (rowBase + r0) * lda + c0;
    const bf16_t* w_src = W + (colBase + r0) * ldw + c0;
    f32x4 acc[4][4];
#pragma unroll
    for (int m = 0; m < 4; ++m)
#pragma unroll
        for (int n = 0; n < 4; ++n) {
            acc[m][n][0] = 0.f; acc[m][n][1] = 0.f;
            acc[m][n][2] = 0.f; acc[m][n][3] = 0.f;
        }
    auto stage = [&](int buf, int ks) {
        const int k0 = ks * 32;
        gload_lds16(a_src + k0, &As[buf][tid * 8]);
        gload_lds16(a_src + (size_t)64 * lda + k0, &As[buf][2048 + tid * 8]);
        gload_lds16(w_src + k0, &Bs[buf][tid * 8]);
        gload_lds16(w_src + (size_t)64 * ldw + k0, &Bs[buf][2048 + tid * 8]);
    };
    stage(0, 0);
    __syncthreads();
    const int nt = K >> 5;
    int cur = 0;
    for (int ks = 0; ks < nt; ++ks) {
        const int nb = cur ^ 1;
        if (ks + 1 < nt) stage(nb, ks + 1);
        bf16x8 af[4], bfr[4];
#pragma unroll
        for (int m = 0; m < 4; ++m)
            af[m] = *reinterpret_cast<const bf16x8*>(&As[cur][(wr * 64 + m * 16 + lr) * 32 + ko]);
#pragma unroll
        for (int n = 0; n < 4; ++n)
            bfr[n] = *reinterpret_cast<const bf16x8*>(&Bs[cur][(wc * 64 + n * 16 + lr) * 32 + ko]);
#pragma unroll
        for (int m = 0; m < 4; ++m)
#pragma unroll
            for (int n = 0; n < 4; ++n)
                acc[m][n] = __builtin_amdgcn_mfma_f32_16x16x32_bf16(af[m], bfr[n], acc[m][n], 0, 0, 0);
        __syncthreads();
        cur = nb;
    }
    const int rj = (lane >> 4) * 4;
#pragma unroll
    for (int n = 0; n < 4; ++n) {
        const int col = (int)colBase + wc * 64 + n * 16 + lr;
        const float bv = bias ? bias[col] : 0.f;
#pragma unroll
        for (int m = 0; m < 4; ++m) {
            const size_t r = rowBase + wr * 64 + m * 16 + rj;
#pragma unroll
            for (int j = 0; j < 4; ++j)
                Cb[(r + j) * ldc + col] = (__bf16)(acc[m][n][j] + bv);
        }
    }
}

// ---------------- small direct GEMM (WcT fold only) ----------------
__global__ __launch_bounds__(256) void gemm_bt(
    const bf16_t* __restrict__ A, int lda, int aZ,
    const bf16_t* __restrict__ W, int ldw, int wZ,
    bf16_t* __restrict__ Cb, int ldc, int cZ,
    int M, int N, int K) {
    const int wid = threadIdx.x >> 6;
    const int lane = threadIdx.x & 63;
    const int lr = lane & 15;
    const int kk = (lane >> 4) * 8;
    const int row0 = blockIdx.x * 64 + wid * 16;
    const int col0 = blockIdx.y * 64;
    A += (size_t)blockIdx.z * aZ;
    W += (size_t)blockIdx.z * wZ;
    const bf16_t* a_ptr = A + (size_t)(row0 + lr) * lda + kk;
    const bf16_t* w_ptr = W + (size_t)(col0 + lr) * ldw + kk;
    f32x4 acc[4];
#pragma unroll
    for (int t = 0; t < 4; ++t) { acc[t][0] = 0.f; acc[t][1] = 0.f; acc[t][2] = 0.f; acc[t][3] = 0.f; }
    bool colv[4];
#pragma unroll
    for (int t = 0; t < 4; ++t) colv[t] = (col0 + t * 16 + lr) < N;
    for (int k0 = 0; k0 < K; k0 += 32) {
        bf16x8 a = *reinterpret_cast<const bf16x8*>(a_ptr + k0);
#pragma unroll
        for (int t = 0; t < 4; ++t) {
            bf16x8 b;
            if (colv[t]) b = *reinterpret_cast<const bf16x8*>(w_ptr + (size_t)t * 16 * ldw + k0);
            else b = zero8();
            acc[t] = __builtin_amdgcn_mfma_f32_16x16x32_bf16(a, b, acc[t], 0, 0, 0);
        }
    }
    const int rb = (lane >> 4) * 4;
    Cb += (size_t)blockIdx.z * cZ;
#pragma unroll
    for (int t = 0; t < 4; ++t) {
        int col = col0 + t * 16 + lr;
        if (col >= N) continue;
#pragma unroll
        for (int j = 0; j < 4; ++j) {
            int r = row0 + rb + j;
            Cb[(size_t)r * ldc + col] = (__bf16)acc[t][j];
        }
    }
}

// ---------------- predict addressing: sim -> softmax -> addr bf16 [N,896] ----------------
__global__ __launch_bounds__(256) void addr_predict(const bf16_t* __restrict__ qp,
                                                    const bf16_t* __restrict__ keyn,
                                                    bf16_t* __restrict__ addr) {
    const int wid = threadIdx.x >> 6, lane = threadIdx.x & 63;
    const int lr = lane & 15, kk = (lane >> 4) * 8;
    const int h = blockIdx.y;
    const int row0 = blockIdx.x * 64 + wid * 16;
    const bf16_t* a_ptr = qp + (size_t)(row0 + lr) * 512 + h * 64 + kk;
    bf16x8 a0 = *reinterpret_cast<const bf16x8*>(a_ptr);
    bf16x8 a1 = *reinterpret_cast<const bf16x8*>(a_ptr + 32);
    float ssq = 0.f;
#pragma unroll
    for (int j = 0; j < 8; ++j) {
        float x = (float)a0[j], y = (float)a1[j];
        ssq += x * x + y * y;
    }
    ssq += __shfl_xor(ssq, 16);
    ssq += __shfl_xor(ssq, 32);
    const float invq = 1.f / fmaxf(sqrtf(ssq), 1e-12f);
    f32x4 acc[7];
#pragma unroll
    for (int t = 0; t < 7; ++t) {
        const bf16_t* b_ptr = keyn + (size_t)(h * 112 + t * 16 + lr) * 64 + kk;
        bf16x8 b0 = *reinterpret_cast<const bf16x8*>(b_ptr);
        bf16x8 b1 = *reinterpret_cast<const bf16x8*>(b_ptr + 32);
        f32x4 c; c[0] = 0.f; c[1] = 0.f; c[2] = 0.f; c[3] = 0.f;
        c = __builtin_amdgcn_mfma_f32_16x16x32_bf16(a0, b0, c, 0, 0, 0);
        c = __builtin_amdgcn_mfma_f32_16x16x32_bf16(a1, b1, c, 0, 0, 0);
        acc[t] = c;
    }
    const int rb = (lane >> 4) * 4;
    float iq[4];
#pragma unroll
    for (int j = 0; j < 4; ++j) iq[j] = __shfl(invq, rb + j);
#pragma unroll
    for (int j = 0; j < 4; ++j) {
        float m = -1e30f;
#pragma unroll
        for (int t = 0; t < 7; ++t) { acc[t][j] *= iq[j] * RADIUS_F; m = fmaxf(m, acc[t][j]); }
#pragma unroll
        for (int o = 1; o < 16; o <<= 1) m = fmaxf(m, __shfl_xor(m, o));
        float s = 0.f;
#pragma unroll
        for (int t = 0; t < 7; ++t) { float e = __expf(acc[t][j] - m); acc[t][j] = e; s += e; }
#pragma unroll
        for (int o = 1; o < 16; o <<= 1) s += __shfl_xor(s, o);
        const float rs = 1.f / s;
#pragma unroll
        for (int t = 0; t < 7; ++t) acc[t][j] *= rs;
    }
#pragma unroll
    for (int t = 0; t < 7; ++t)
#pragma unroll
        for (int j = 0; j < 4; ++j)
            addr[(size_t)(row0 + rb + j) * 896 + h * 112 + t * 16 + lr] = (__bf16)acc[t][j];
}

// ---------------- fused recon sim GEMM + softmax -> addr2 [M][128] ----------------
__global__ __launch_bounds__(256, 2) void gemm_sim_softmax(
    const bf16_t* __restrict__ vp,   // [M][512]
    const bf16_t* __restrict__ mvb,  // [128][512] (rows 112..127 zero)
    const float* __restrict__ invmv, // [112]
    bf16_t* __restrict__ addr2) {    // [M][128]
    __shared__ __align__(16) bf16_t As[2][128 * 32];
    __shared__ __align__(16) bf16_t Bs[2][128 * 32];
    const int tid = threadIdx.x;
    const int wid = tid >> 6, lane = tid & 63;
    const int lr = lane & 15, hi = lane >> 4;
    const int ko = hi * 8;
    const size_t rowBase = (size_t)blockIdx.x * 128;
    const int r0 = tid >> 2, c0 = (tid & 3) * 8;
    const bf16_t* a_src = vp + (rowBase + r0) * 512 + c0;
    const bf16_t* b_src = mvb + (size_t)r0 * 512 + c0;
    f32x4 acc[2][8];
#pragma unroll
    for (int m = 0; m < 2; ++m)
#pragma unroll
        for (int n = 0; n < 8; ++n) {
            acc[m][n][0] = 0.f; acc[m][n][1] = 0.f;
            acc[m][n][2] = 0.f; acc[m][n][3] = 0.f;
        }
    float ssq[2] = {0.f, 0.f};
    auto stage = [&](int buf, int ks) {
        const int k0 = ks * 32;
        gload_lds16(a_src + k0, &As[buf][tid * 8]);
        gload_lds16(a_src + (size_t)64 * 512 + k0, &As[buf][2048 + tid * 8]);
        gload_lds16(b_src + k0, &Bs[buf][tid * 8]);
        gload_lds16(b_src + (size_t)64 * 512 + k0, &Bs[buf][2048 + tid * 8]);
    };
    stage(0, 0);
    drain_barrier();
    int cur = 0;
    for (int ks = 0; ks < 16; ++ks) {
        if (ks < 15) stage(cur ^ 1, ks + 1);
        bf16x8 af[2], bfr[8];
#pragma unroll
        for (int m = 0; m < 2; ++m)
            af[m] = *reinterpret_cast<const bf16x8*>(&As[cur][(wid * 32 + m * 16 + lr) * 32 + ko]);
#pragma unroll
        for (int n = 0; n < 8; ++n)
            bfr[n] = *reinterpret_cast<const bf16x8*>(&Bs[cur][(n * 16 + lr) * 32 + ko]);
#pragma unroll
        for (int m = 0; m < 2; ++m) {
#pragma unroll
            for (int j = 0; j < 8; ++j) { float x = (float)af[m][j]; ssq[m] += x * x; }
#pragma unroll
            for (int n = 0; n < 8; ++n)
                acc[m][n] = __builtin_amdgcn_mfma_f32_16x16x32_bf16(af[m], bfr[n], acc[m][n], 0, 0, 0);
        }
        drain_barrier();
        cur ^= 1;
    }
#pragma unroll
    for (int m = 0; m < 2; ++m) {
        ssq[m] += __shfl_xor(ssq[m], 16);
        ssq[m] += __shfl_xor(ssq[m], 32);
        ssq[m] = 1.f / fmaxf(sqrtf(ssq[m]), 1e-12f);
    }
    const int rb = hi * 4;
    float imv[7];
#pragma unroll
    for (int n = 0; n < 7; ++n) imv[n] = invmv[n * 16 + lr];
#pragma unroll
    for (int m = 0; m < 2; ++m)
#pragma unroll
        for (int j = 0; j < 4; ++j) {
            const float iq = __shfl(ssq[m], (lane & 48) | (rb + j));
            float x[7];
            float mx = -1e30f;
#pragma unroll
            for (int n = 0; n < 7; ++n) {
                x[n] = acc[m][n][j] * iq * imv[n] * RADIUS_F;
                mx = fmaxf(mx, x[n]);
            }
#pragma unroll
            for (int o = 1; o < 16; o <<= 1) mx = fmaxf(mx, __shfl_xor(mx, o));
            float s = 0.f;
#pragma unroll
            for (int n = 0; n < 7; ++n) { x[n] = __expf(x[n] - mx); s += x[n]; }
#pragma unroll
            for (int o = 1; o < 16; o <<= 1) s += __shfl_xor(s, o);
            const float rs = 1.f / s;
            const size_t row = rowBase + wid * 32 + m * 16 + rb + j;
#pragma unroll
            for (int n = 0; n < 7; ++n)
                addr2[row * 128 + n * 16 + lr] = (__bf16)(x[n] * rs);
            addr2[row * 128 + 112 + lr] = (__bf16)0.f;
        }
}

// ---------------- fused epilogue: BOTH branches, 2 rows/wave, all-bf16 inputs ----------------
// f_predict = LN1(q + sP); f_recon = LN1(q + LN3(sR)); rrpart += |1-cos(sR, v)|
__global__ __launch_bounds__(256) void fused_ep(
    const bf16_t* __restrict__ sP, const bf16_t* __restrict__ sR,
    const bf16_t* __restrict__ qb, const bf16_t* __restrict__ vb,
    const float* __restrict__ g1, const float* __restrict__ b1,
    const float* __restrict__ g3, const float* __restrict__ b3,
    float* __restrict__ fP, float* __restrict__ fR,
    float* __restrict__ rrpart) {
    const int wid = threadIdx.x >> 6, lane = threadIdx.x & 63;
    const size_t row0 = (size_t)blockIdx.x * 8 + wid * 2;
    const int c1 = lane * 8, c2 = lane * 8 + 4;
    float xP[2][8], aR[2][8], qv[2][8];
    float s1[2], s2[2], sa[2], sa2[2], sav[2], sv2[2];
#pragma unroll
    for (int r = 0; r < 2; ++r) {
        const size_t base = (row0 + r) * 512;
        bf16x8 p = *reinterpret_cast<const bf16x8*>(sP + base + c1);
        bf16x8 rr = *reinterpret_cast<const bf16x8*>(sR + base + c1);
        bf16x8 qq = *reinterpret_cast<const bf16x8*>(qb + base + c1);
        bf16x8 vv = *reinterpret_cast<const bf16x8*>(vb + base + c1);
        s1[r] = 0.f; s2[r] = 0.f;
        sa[r] = 0.f; sa2[r] = 0.f; sav[r] = 0.f; sv2[r] = 0.f;
#pragma unroll
        for (int j = 0; j < 8; ++j) {
            const float qf = (float)qq[j];
            const float pf = (float)p[j];
            const float af = (float)rr[j];
            const float vf = (float)vv[j];
            qv[r][j] = qf;
            const float x = qf + pf;
            xP[r][j] = x;
            s1[r] += x; s2[r] += x * x;
            aR[r][j] = af;
            sa[r] += af; sa2[r] += af * af;
            sav[r] += af * vf; sv2[r] += vf * vf;
        }
    }
    // 12 interleaved reduction chains
#pragma unroll
    for (int o = 1; o < 64; o <<= 1)
#pragma unroll
        for (int r = 0; r < 2; ++r) {
            s1[r] += __shfl_xor(s1[r], o);
            s2[r] += __shfl_xor(s2[r], o);
            sa[r] += __shfl_xor(sa[r], o);
            sa2[r] += __shfl_xor(sa2[r], o);
            sav[r] += __shfl_xor(sav[r], o);
            sv2[r] += __shfl_xor(sv2[r], o);
        }
    const float4 g1a = *reinterpret_cast<const float4*>(g1 + c1);
    const float4 g1b = *reinterpret_cast<const float4*>(g1 + c2);
    const float4 b1a = *reinterpret_cast<const float4*>(b1 + c1);
    const float4 b1b = *reinterpret_cast<const float4*>(b1 + c2);
    // predict branch write
#pragma unroll
    for (int r = 0; r < 2; ++r) {
        const size_t base = (row0 + r) * 512;
        const float mu = s1[r] * (1.f / 512.f);
        const float rs = rsqrtf(s2[r] * (1.f / 512.f) - mu * mu + LN_EPS);
        float4 o1 = make_float4((xP[r][0] - mu) * rs * g1a.x + b1a.x,
                                (xP[r][1] - mu) * rs * g1a.y + b1a.y,
                                (xP[r][2] - mu) * rs * g1a.z + b1a.z,
                                (xP[r][3] - mu) * rs * g1a.w + b1a.w);
        float4 o2 = make_float4((xP[r][4] - mu) * rs * g1b.x + b1b.x,
                                (xP[r][5] - mu) * rs * g1b.y + b1b.y,
                                (xP[r][6] - mu) * rs * g1b.z + b1b.z,
                                (xP[r][7] - mu) * rs * g1b.w + b1b.w);
        *reinterpret_cast<float4*>(fP + base + c1) = o1;
        *reinterpret_cast<float4*>(fP + base + c2) = o2;
    }
    // loss partial
    float rrw = 0.f;
    if (lane == 0) {
#pragma unroll
        for (int r = 0; r < 2; ++r) {
            const float na = fmaxf(sqrtf(sa2[r]), 1e-12f);
            const float nv = fmaxf(sqrtf(sv2[r]), 1e-12f);
            rrw += fabsf(1.f - sav[r] / (na * nv));
        }
    }
    // recon branch: x = q + LN3(aR), then LN1
    const float4 g3a = *reinterpret_cast<const float4*>(g3 + c1);
    const float4 g3b = *reinterpret_cast<const float4*>(g3 + c2);
    const float4 b3a = *reinterpret_cast<const float4*>(b3 + c1);
    const float4 b3b = *reinterpret_cast<const float4*>(b3 + c2);
#pragma unroll
    for (int r = 0; r < 2; ++r) {
        const float mu3 = sa[r] * (1.f / 512.f);
        const float r3 = rsqrtf(sa2[r] * (1.f / 512.f) - mu3 * mu3 + LN_EPS);
        float s1n = 0.f, s2n = 0.f;
        const float gg[8] = {g3a.x, g3a.y, g3a.z, g3a.w, g3b.x, g3b.y, g3b.z, g3b.w};
        const float bb[8] = {b3a.x, b3a.y, b3a.z, b3a.w, b3b.x, b3b.y, b3b.z, b3b.w};
#pragma unroll
        for (int j = 0; j < 8; ++j) {
            const float x = qv[r][j] + (aR[r][j] - mu3) * r3 * gg[j] + bb[j];
            aR[r][j] = x;
            s1n += x; s2n += x * x;
        }
        s1[r] = s1n; s2[r] = s2n;
    }
#pragma unroll
    for (int o = 1; o < 64; o <<= 1)
#pragma unroll
        for (int r = 0; r < 2; ++r) {
            s1[r] += __shfl_xor(s1[r], o);
            s2[r] += __shfl_xor(s2[r], o);
        }
#pragma unroll
    for (int r = 0; r < 2; ++r) {
        const size_t base = (row0 + r) * 512;
        const float mu = s1[r] * (1.f / 512.f);
        const float rs = rsqrtf(s2[r] * (1.f / 512.f) - mu * mu + LN_EPS);
        float4 o1 = make_float4((aR[r][0] - mu) * rs * g1a.x + b1a.x,
                                (aR[r][1] - mu) * rs * g1a.y + b1a.y,
                                (aR[r][2] - mu) * rs * g1a.z + b1a.z,
                                (aR[r][3] - mu) * rs * g1a.w + b1a.w);
        float4 o2 = make_float4((aR[r][4] - mu) * rs * g1b.x + b1b.x,
                                (aR[r][5] - mu) * rs * g1b.y + b1b.y,
                                (aR[r][6] - mu) * rs * g1b.z + b1b.z,
                                (aR[r][7] - mu) * rs * g1b.w + b1b.w);
        *reinterpret_cast<float4*>(fR + base + c1) = o1;
        *reinterpret_cast<float4*>(fR + base + c2) = o2;
    }
    __shared__ float rred[4];
    if (lane == 0) rred[wid] = rrw;
    __syncthreads();
    if (threadIdx.x == 0)
        rrpart[blockIdx.x] = rred[0] + rred[1] + rred[2] + rred[3];
}

// sum block partials -> loss_slots[0]
__global__ __launch_bounds__(256) void reduce_part_k(const float* __restrict__ part,
                                                     int n, float* __restrict__ out) {
    float s = 0.f;
    for (int i = threadIdx.x; i < n; i += 256) s += part[i];
    s = wave_sum(s);
    __shared__ float red[4];
    const int wid = threadIdx.x >> 6, lane = threadIdx.x & 63;
    if (lane == 0) red[wid] = s;
    __syncthreads();
    if (threadIdx.x == 0)
        out[0] = (red[0] + red[1] + red[2] + red[3]) * (1.f / 32768.f);
}

extern "C" void kernel_launch(void* const* d_in, const int* in_sizes, int n_in,
                              void* d_out, int out_size, void* d_ws, size_t ws_size,
                              hipStream_t stream) {
    const float* query = (const float*)d_in[0];
    const float* value = (const float*)d_in[1];
    const float* mem_key = (const float*)d_in[2];
    const float* mem_value = (const float*)d_in[3];
    const float* q_w = (const float*)d_in[4];
    const float* q_b = (const float*)d_in[5];
    const float* v_w = (const float*)d_in[6];
    const float* v_b = (const float*)d_in[7];
    const float* out_w = (const float*)d_in[8];
    const float* out_b = (const float*)d_in[9];
    const float* ln1_g = (const float*)d_in[10];
    const float* ln1_b = (const float*)d_in[11];
    const float* ln3_g = (const float*)d_in[12];
    const float* ln3_b = (const float*)d_in[13];
    float* out = (float*)d_out;

    char* ws = (char*)d_ws;
    size_t off = 0;
    auto alloc = [&](size_t bytes) {
        void* p = ws + off;
        off += (bytes + 255) & ~(size_t)255;
        return p;
    };
    bf16_t* qb = (bf16_t*)alloc(16777216ull * 2);      // query bf16 (live to end)
    bf16_t* vb = (bf16_t*)alloc(16777216ull * 2);      // value bf16 (live to end)
    bf16_t* qpb = (bf16_t*)alloc(16777216ull * 2);     // qp; stageP aliases after addr_predict
    bf16_t* vpb = (bf16_t*)alloc(16777216ull * 2);     // vp; stageR aliases after sim_softmax
    bf16_t* addr = (bf16_t*)alloc(32768ull * 896 * 2); // addr; addr2 aliases
    bf16_t* qwb = (bf16_t*)alloc(262144ull * 2);
    bf16_t* vwb = (bf16_t*)alloc(262144ull * 2);
    bf16_t* owb = (bf16_t*)alloc(2097152ull * 2);
    bf16_t* wct = (bf16_t*)alloc(896ull * 512 * 2);    // WcT[512][896]
    bf16_t* keyn = (bf16_t*)alloc(896ull * 64 * 2);
    bf16_t* mvb = (bf16_t*)alloc(128ull * 512 * 2);
    bf16_t* mvT = (bf16_t*)alloc(512ull * 128 * 2);
    float* invmv = (float*)alloc(112 * 4);
    float* rrpart = (float*)alloc(4096 * 4);
    bf16_t* addr2 = addr;
    bf16_t* stageP = qpb;
    bf16_t* stageR = vpb;

    float* f_predict = out;
    float* f_recon = out + 16777216;
    float* loss_slots = out + 33554432;  // [recon_loss, contrastive_loss]

    // prep
    cast_all<<<2048, 256, 0, stream>>>(query, value, q_w, v_w, out_w,
                                       qb, vb, qwb, vwb, owb);
    keyn_k<<<224, 256, 0, stream>>>(mem_key, keyn);
    mv_prep_k<<<128, 256, 0, stream>>>(mem_value, mvb, mvT, invmv, loss_slots);
    contrastive_k<<<112, 256, 0, stream>>>(mem_value, invmv, loss_slots + 1);
    // WcT[d][h*112+s] = sum_j out_w[d][h*512+j] * mem_value[s][j]
    gemm_bt<<<dim3(8, 2, 8), 256, 0, stream>>>(owb, 4096, 512, mvb, 512, 0,
                                               wct, 896, 112, 512, 112, 512);
    // projections (pure-bf16 gload_lds path)
    gemm128_bb<<<dim3(256, 4), 256, 0, stream>>>(qb, 512, qwb, 512, q_b,
                                                 qpb, 512, 512);
    gemm128_bb<<<dim3(256, 4), 256, 0, stream>>>(vb, 512, vwb, 512, v_b,
                                                 vpb, 512, 512);
    // predict branch
    addr_predict<<<dim3(512, 8), 256, 0, stream>>>(qpb, keyn, addr);
    gemm128_bb<<<dim3(256, 4), 256, 0, stream>>>(addr, 896, wct, 896, out_b,
                                                 stageP, 512, 896);
    // recon branch
    gemm_sim_softmax<<<256, 256, 0, stream>>>(vpb, mvb, invmv, addr2);
    gemm128_bb<<<dim3(256, 4), 256, 0, stream>>>(addr2, 128, mvT, 128,
                                                 (const float*)nullptr,
                                                 stageR, 512, 128);
    // both epilogues fused
    fused_ep<<<4096, 256, 0, stream>>>(stageP, stageR, qb, vb,
                                       ln1_g, ln1_b, ln3_g, ln3_b,
                                       f_predict, f_recon, rrpart);
    reduce_part_k<<<1, 256, 0, stream>>>(rrpart, 4096, loss_slots);
}

// Round 11
// 307.772 us; speedup vs baseline: 1.1794x; 1.0560x over previous
//
#include <hip/hip_runtime.h>
#include <hip/hip_bf16.h>
#include <math.h>

typedef __bf16 bf16_t;
typedef __attribute__((ext_vector_type(8))) __bf16 bf16x8;
typedef __attribute__((ext_vector_type(4))) __bf16 bf16x4;
typedef __attribute__((ext_vector_type(4))) float f32x4;

#define LN_EPS 1e-5f
#define RADIUS_F 16.0f

__device__ inline bf16x8 zero8() {
    bf16x8 v;
#pragma unroll
    for (int i = 0; i < 8; ++i) v[i] = (__bf16)0.f;
    return v;
}

__device__ inline float wave_sum(float v) {
#pragma unroll
    for (int o = 1; o < 64; o <<= 1) v += __shfl_xor(v, o);
    return v;
}

__device__ inline void gload_lds16(const bf16_t* g, bf16_t* l) {
    __builtin_amdgcn_global_load_lds(
        (const __attribute__((address_space(1))) void*)g,
        (__attribute__((address_space(3))) void*)l, 16, 0, 0);
}

__device__ inline void drain_barrier() {
    asm volatile("s_waitcnt vmcnt(0)" ::: "memory");
    __builtin_amdgcn_s_barrier();
}

// ---------------- one grid-stride cast for q, v, and all three weights ----------------
__global__ __launch_bounds__(256) void cast_all(
    const float* __restrict__ q, const float* __restrict__ v,
    const float* __restrict__ qw, const float* __restrict__ vw,
    const float* __restrict__ ow,
    bf16_t* __restrict__ qb, bf16_t* __restrict__ vb,
    bf16_t* __restrict__ qwb, bf16_t* __restrict__ vwb,
    bf16_t* __restrict__ owb) {
    const int total = 9043968;  // float4 count
    for (int i = blockIdx.x * 256 + threadIdx.x; i < total; i += gridDim.x * 256) {
        const float* src;
        bf16_t* dst;
        int j;
        if (i < 4194304) { src = q; dst = qb; j = i; }
        else if (i < 8388608) { src = v; dst = vb; j = i - 4194304; }
        else if (i < 8454144) { src = qw; dst = qwb; j = i - 8388608; }
        else if (i < 8519680) { src = vw; dst = vwb; j = i - 8454144; }
        else { src = ow; dst = owb; j = i - 8519680; }
        float4 x = reinterpret_cast<const float4*>(src)[j];
        bf16x4 o;
        o[0] = (__bf16)x.x; o[1] = (__bf16)x.y; o[2] = (__bf16)x.z; o[3] = (__bf16)x.w;
        reinterpret_cast<bf16x4*>(dst)[j] = o;
    }
}

// normalize mem_key rows (896 x 64) -> bf16
__global__ __launch_bounds__(256) void keyn_k(const float* __restrict__ mk,
                                              bf16_t* __restrict__ kn) {
    int row = blockIdx.x * 4 + (threadIdx.x >> 6);
    int lane = threadIdx.x & 63;
    float x = mk[(size_t)row * 64 + lane];
    float ss = wave_sum(x * x);
    kn[(size_t)row * 64 + lane] = (__bf16)(x / fmaxf(sqrtf(ss), 1e-12f));
}

// mem_value: row inv-norms + bf16 copy (padded to 128) + transposed copy; zero loss
__global__ __launch_bounds__(256) void mv_prep_k(const float* __restrict__ mv,
                                                 bf16_t* __restrict__ mvb,
                                                 bf16_t* __restrict__ mvT,
                                                 float* __restrict__ invmv,
                                                 float* __restrict__ loss_slots) {
    const int s = blockIdx.x, tid = threadIdx.x;
    if (s >= 112) {
        mvb[(size_t)s * 512 + tid * 2] = (__bf16)0.f;
        mvb[(size_t)s * 512 + tid * 2 + 1] = (__bf16)0.f;
        mvT[(size_t)tid * 128 + s] = (__bf16)0.f;
        mvT[(size_t)(tid + 256) * 128 + s] = (__bf16)0.f;
        return;
    }
    float2 x = *reinterpret_cast<const float2*>(mv + (size_t)s * 512 + tid * 2);
    float ss = wave_sum(x.x * x.x + x.y * x.y);
    __shared__ float red[4];
    int wid = tid >> 6, lane = tid & 63;
    if (lane == 0) red[wid] = ss;
    __syncthreads();
    ss = red[0] + red[1] + red[2] + red[3];
    if (tid == 0) invmv[s] = 1.f / fmaxf(sqrtf(ss), 1e-12f);
    mvb[(size_t)s * 512 + tid * 2] = (__bf16)x.x;
    mvb[(size_t)s * 512 + tid * 2 + 1] = (__bf16)x.y;
    mvT[(size_t)tid * 128 + s] = (__bf16)mv[(size_t)s * 512 + tid];
    mvT[(size_t)(tid + 256) * 128 + s] = (__bf16)mv[(size_t)s * 512 + tid + 256];
    if (s == 0 && tid < 2) loss_slots[tid] = 0.f;
}

// contrastive loss: sum |I - Gn Gn^T| * 0.01  (fp32)
__global__ __launch_bounds__(256) void contrastive_k(const float* __restrict__ mv,
                                                     const float* __restrict__ invmv,
                                                     float* __restrict__ out_slot) {
    const int a = blockIdx.x;
    const int tid = threadIdx.x, wid = tid >> 6, lane = tid & 63;
    __shared__ float rowa[512];
    __shared__ float wsum[4];
    for (int i = tid; i < 512; i += 256) rowa[i] = mv[(size_t)a * 512 + i];
    __syncthreads();
    float acc = 0.f;
    const float ia = invmv[a];
    for (int b = wid; b < 112; b += 4) {
        float d = 0.f;
#pragma unroll
        for (int i = 0; i < 8; ++i) d += rowa[lane + i * 64] * mv[(size_t)b * 512 + lane + i * 64];
        d = wave_sum(d);
        float gv = d * ia * invmv[b];
        acc += fabsf((a == b ? 1.f : 0.f) - gv);
    }
    if (lane == 0) wsum[wid] = acc;
    __syncthreads();
    if (tid == 0) atomicAdd(out_slot, (wsum[0] + wsum[1] + wsum[2] + wsum[3]) * 0.01f);
}

// ---------------- dual 128x128 GEMM (two independent problems via blockIdx.z) ----------------
// z=0: C0[M,512](bf16) = A0 @ W0^T + bias0 (K0) ; z=1: same with *1 args.
__global__ __launch_bounds__(256) void gemm_dual(
    const bf16_t* __restrict__ A0, int lda0, const bf16_t* __restrict__ W0, int ldw0,
    const float* __restrict__ bias0, bf16_t* __restrict__ C0, int K0,
    const bf16_t* __restrict__ A1, int lda1, const bf16_t* __restrict__ W1, int ldw1,
    const float* __restrict__ bias1, bf16_t* __restrict__ C1, int K1) {
    const bf16_t* A = blockIdx.z ? A1 : A0;
    const bf16_t* W = blockIdx.z ? W1 : W0;
    const float* bias = blockIdx.z ? bias1 : bias0;
    bf16_t* Cb = blockIdx.z ? C1 : C0;
    const int lda = blockIdx.z ? lda1 : lda0;
    const int ldw = blockIdx.z ? ldw1 : ldw0;
    const int K = blockIdx.z ? K1 : K0;
    __shared__ __align__(16) bf16_t As[2][128 * 32];
    __shared__ __align__(16) bf16_t Bs[2][128 * 32];
    const int tid = threadIdx.x;
    const int wid = tid >> 6, lane = tid & 63;
    const int wr = wid >> 1, wc = wid & 1;
    const int lr = lane & 15;
    const int ko = (lane >> 4) * 8;
    const size_t rowBase = (size_t)blockIdx.x * 128;
    const size_t colBase = (size_t)blockIdx.y * 128;
    const int r0 = tid >> 2;
    const int c0 = (tid & 3) * 8;
    const bf16_t* a_src = A + (rowBase + r0) * lda + c0;
    const bf16_t* w_src = W + (colBase + r0) * ldw + c0;
    f32x4 acc[4][4];
#pragma unroll
    for (int m = 0; m < 4; ++m)
#pragma unroll
        for (int n = 0; n < 4; ++n) {
            acc[m][n][0] = 0.f; acc[m][n][1] = 0.f;
            acc[m][n][2] = 0.f; acc[m][n][3] = 0.f;
        }
    auto stage = [&](int buf, int ks) {
        const int k0 = ks * 32;
        gload_lds16(a_src + k0, &As[buf][tid * 8]);
        gload_lds16(a_src + (size_t)64 * lda + k0, &As[buf][2048 + tid * 8]);
        gload_lds16(w_src + k0, &Bs[buf][tid * 8]);
        gload_lds16(w_src + (size_t)64 * ldw + k0, &Bs[buf][2048 + tid * 8]);
    };
    stage(0, 0);
    __syncthreads();
    const int nt = K >> 5;
    int cur = 0;
    for (int ks = 0; ks < nt; ++ks) {
        const int nb = cur ^ 1;
        if (ks + 1 < nt) stage(nb, ks + 1);
        bf16x8 af[4], bfr[4];
#pragma unroll
        for (int m = 0; m < 4; ++m)
            af[m] = *reinterpret_cast<const bf16x8*>(&As[cur][(wr * 64 + m * 16 + lr) * 32 + ko]);
#pragma unroll
        for (int n = 0; n < 4; ++n)
            bfr[n] = *reinterpret_cast<const bf16x8*>(&Bs[cur][(wc * 64 + n * 16 + lr) * 32 + ko]);
#pragma unroll
        for (int m = 0; m < 4; ++m)
#pragma unroll
            for (int n = 0; n < 4; ++n)
                acc[m][n] = __builtin_amdgcn_mfma_f32_16x16x32_bf16(af[m], bfr[n], acc[m][n], 0, 0, 0);
        __syncthreads();
        cur = nb;
    }
    const int rj = (lane >> 4) * 4;
#pragma unroll
    for (int n = 0; n < 4; ++n) {
        const int col = (int)colBase + wc * 64 + n * 16 + lr;
        const float bv = bias ? bias[col] : 0.f;
#pragma unroll
        for (int m = 0; m < 4; ++m) {
            const size_t r = rowBase + wr * 64 + m * 16 + rj;
#pragma unroll
            for (int j = 0; j < 4; ++j)
                Cb[(r + j) * 512 + col] = (__bf16)(acc[m][n][j] + bv);
        }
    }
}

// ---------------- small direct GEMM (WcT fold only) ----------------
__global__ __launch_bounds__(256) void gemm_bt(
    const bf16_t* __restrict__ A, int lda, int aZ,
    const bf16_t* __restrict__ W, int ldw, int wZ,
    bf16_t* __restrict__ Cb, int ldc, int cZ,
    int M, int N, int K) {
    const int wid = threadIdx.x >> 6;
    const int lane = threadIdx.x & 63;
    const int lr = lane & 15;
    const int kk = (lane >> 4) * 8;
    const int row0 = blockIdx.x * 64 + wid * 16;
    const int col0 = blockIdx.y * 64;
    A += (size_t)blockIdx.z * aZ;
    W += (size_t)blockIdx.z * wZ;
    const bf16_t* a_ptr = A + (size_t)(row0 + lr) * lda + kk;
    const bf16_t* w_ptr = W + (size_t)(col0 + lr) * ldw + kk;
    f32x4 acc[4];
#pragma unroll
    for (int t = 0; t < 4; ++t) { acc[t][0] = 0.f; acc[t][1] = 0.f; acc[t][2] = 0.f; acc[t][3] = 0.f; }
    bool colv[4];
#pragma unroll
    for (int t = 0; t < 4; ++t) colv[t] = (col0 + t * 16 + lr) < N;
    for (int k0 = 0; k0 < K; k0 += 32) {
        bf16x8 a = *reinterpret_cast<const bf16x8*>(a_ptr + k0);
#pragma unroll
        for (int t = 0; t < 4; ++t) {
            bf16x8 b;
            if (colv[t]) b = *reinterpret_cast<const bf16x8*>(w_ptr + (size_t)t * 16 * ldw + k0);
            else b = zero8();
            acc[t] = __builtin_amdgcn_mfma_f32_16x16x32_bf16(a, b, acc[t], 0, 0, 0);
        }
    }
    const int rb = (lane >> 4) * 4;
    Cb += (size_t)blockIdx.z * cZ;
#pragma unroll
    for (int t = 0; t < 4; ++t) {
        int col = col0 + t * 16 + lr;
        if (col >= N) continue;
#pragma unroll
        for (int j = 0; j < 4; ++j) {
            int r = row0 + rb + j;
            Cb[(size_t)r * ldc + col] = (__bf16)acc[t][j];
        }
    }
}

// ---------------- predict addressing: sim -> softmax -> addr bf16 [N,896] ----------------
__global__ __launch_bounds__(256) void addr_predict(const bf16_t* __restrict__ qp,
                                                    const bf16_t* __restrict__ keyn,
                                                    bf16_t* __restrict__ addr) {
    const int wid = threadIdx.x >> 6, lane = threadIdx.x & 63;
    const int lr = lane & 15, kk = (lane >> 4) * 8;
    const int h = blockIdx.y;
    const int row0 = blockIdx.x * 64 + wid * 16;
    const bf16_t* a_ptr = qp + (size_t)(row0 + lr) * 512 + h * 64 + kk;
    bf16x8 a0 = *reinterpret_cast<const bf16x8*>(a_ptr);
    bf16x8 a1 = *reinterpret_cast<const bf16x8*>(a_ptr + 32);
    float ssq = 0.f;
#pragma unroll
    for (int j = 0; j < 8; ++j) {
        float x = (float)a0[j], y = (float)a1[j];
        ssq += x * x + y * y;
    }
    ssq += __shfl_xor(ssq, 16);
    ssq += __shfl_xor(ssq, 32);
    const float invq = 1.f / fmaxf(sqrtf(ssq), 1e-12f);
    f32x4 acc[7];
#pragma unroll
    for (int t = 0; t < 7; ++t) {
        const bf16_t* b_ptr = keyn + (size_t)(h * 112 + t * 16 + lr) * 64 + kk;
        bf16x8 b0 = *reinterpret_cast<const bf16x8*>(b_ptr);
        bf16x8 b1 = *reinterpret_cast<const bf16x8*>(b_ptr + 32);
        f32x4 c; c[0] = 0.f; c[1] = 0.f; c[2] = 0.f; c[3] = 0.f;
        c = __builtin_amdgcn_mfma_f32_16x16x32_bf16(a0, b0, c, 0, 0, 0);
        c = __builtin_amdgcn_mfma_f32_16x16x32_bf16(a1, b1, c, 0, 0, 0);
        acc[t] = c;
    }
    const int rb = (lane >> 4) * 4;
    float iq[4];
#pragma unroll
    for (int j = 0; j < 4; ++j) iq[j] = __shfl(invq, rb + j);
#pragma unroll
    for (int j = 0; j < 4; ++j) {
        float m = -1e30f;
#pragma unroll
        for (int t = 0; t < 7; ++t) { acc[t][j] *= iq[j] * RADIUS_F; m = fmaxf(m, acc[t][j]); }
#pragma unroll
        for (int o = 1; o < 16; o <<= 1) m = fmaxf(m, __shfl_xor(m, o));
        float s = 0.f;
#pragma unroll
        for (int t = 0; t < 7; ++t) { float e = __expf(acc[t][j] - m); acc[t][j] = e; s += e; }
#pragma unroll
        for (int o = 1; o < 16; o <<= 1) s += __shfl_xor(s, o);
        const float rs = 1.f / s;
#pragma unroll
        for (int t = 0; t < 7; ++t) acc[t][j] *= rs;
    }
#pragma unroll
    for (int t = 0; t < 7; ++t)
#pragma unroll
        for (int j = 0; j < 4; ++j)
            addr[(size_t)(row0 + rb + j) * 896 + h * 112 + t * 16 + lr] = (__bf16)acc[t][j];
}

// ---------------- fused recon sim GEMM + softmax -> addr2 [M][128] ----------------
// 64 rows/block (grid 512 -> 2 blocks/CU), 4 waves x 16 rows, dbuf.
__global__ __launch_bounds__(256) void gemm_sim_softmax(
    const bf16_t* __restrict__ vp,   // [M][512]
    const bf16_t* __restrict__ mvb,  // [128][512] (rows 112..127 zero)
    const float* __restrict__ invmv, // [112]
    bf16_t* __restrict__ addr2) {    // [M][128]
    __shared__ __align__(16) bf16_t As[2][64 * 32];
    __shared__ __align__(16) bf16_t Bs[2][128 * 32];
    const int tid = threadIdx.x;
    const int wid = tid >> 6, lane = tid & 63;
    const int lr = lane & 15, hi = lane >> 4;
    const int ko = hi * 8;
    const size_t rowBase = (size_t)blockIdx.x * 64;
    const int r0 = tid >> 2, c0 = (tid & 3) * 8;
    const bf16_t* a_src = vp + (rowBase + r0) * 512 + c0;
    const bf16_t* b_src = mvb + (size_t)r0 * 512 + c0;
    f32x4 acc[8];
#pragma unroll
    for (int n = 0; n < 8; ++n) {
        acc[n][0] = 0.f; acc[n][1] = 0.f; acc[n][2] = 0.f; acc[n][3] = 0.f;
    }
    float ssq = 0.f;
    auto stage = [&](int buf, int ks) {
        const int k0 = ks * 32;
        gload_lds16(a_src + k0, &As[buf][tid * 8]);
        gload_lds16(b_src + k0, &Bs[buf][tid * 8]);
        gload_lds16(b_src + (size_t)64 * 512 + k0, &Bs[buf][2048 + tid * 8]);
    };
    stage(0, 0);
    drain_barrier();
    int cur = 0;
    for (int ks = 0; ks < 16; ++ks) {
        if (ks < 15) stage(cur ^ 1, ks + 1);
        bf16x8 af, bfr[8];
        af = *reinterpret_cast<const bf16x8*>(&As[cur][(wid * 16 + lr) * 32 + ko]);
#pragma unroll
        for (int n = 0; n < 8; ++n)
            bfr[n] = *reinterpret_cast<const bf16x8*>(&Bs[cur][(n * 16 + lr) * 32 + ko]);
#pragma unroll
        for (int j = 0; j < 8; ++j) { float x = (float)af[j]; ssq += x * x; }
#pragma unroll
        for (int n = 0; n < 8; ++n)
            acc[n] = __builtin_amdgcn_mfma_f32_16x16x32_bf16(af, bfr[n], acc[n], 0, 0, 0);
        drain_barrier();
        cur ^= 1;
    }
    ssq += __shfl_xor(ssq, 16);
    ssq += __shfl_xor(ssq, 32);
    ssq = 1.f / fmaxf(sqrtf(ssq), 1e-12f);
    const int rb = hi * 4;
    float imv[7];
#pragma unroll
    for (int n = 0; n < 7; ++n) imv[n] = invmv[n * 16 + lr];
#pragma unroll
    for (int j = 0; j < 4; ++j) {
        const float iq = __shfl(ssq, (lane & 48) | (rb + j));
        float x[7];
        float mx = -1e30f;
#pragma unroll
        for (int n = 0; n < 7; ++n) {
            x[n] = acc[n][j] * iq * imv[n] * RADIUS_F;
            mx = fmaxf(mx, x[n]);
        }
#pragma unroll
        for (int o = 1; o < 16; o <<= 1) mx = fmaxf(mx, __shfl_xor(mx, o));
        float s = 0.f;
#pragma unroll
        for (int n = 0; n < 7; ++n) { x[n] = __expf(x[n] - mx); s += x[n]; }
#pragma unroll
        for (int o = 1; o < 16; o <<= 1) s += __shfl_xor(s, o);
        const float rs = 1.f / s;
        const size_t row = rowBase + wid * 16 + rb + j;
#pragma unroll
        for (int n = 0; n < 7; ++n)
            addr2[row * 128 + n * 16 + lr] = (__bf16)(x[n] * rs);
        addr2[row * 128 + 112 + lr] = (__bf16)0.f;
    }
}

// ---------------- fused epilogue: BOTH branches, 2 rows/wave, all-bf16 inputs ----------------
__global__ __launch_bounds__(256) void fused_ep(
    const bf16_t* __restrict__ sP, const bf16_t* __restrict__ sR,
    const bf16_t* __restrict__ qb, const bf16_t* __restrict__ vb,
    const float* __restrict__ g1, const float* __restrict__ b1,
    const float* __restrict__ g3, const float* __restrict__ b3,
    float* __restrict__ fP, float* __restrict__ fR,
    float* __restrict__ rrpart) {
    const int wid = threadIdx.x >> 6, lane = threadIdx.x & 63;
    const size_t row0 = (size_t)blockIdx.x * 8 + wid * 2;
    const int c1 = lane * 8, c2 = lane * 8 + 4;
    float xP[2][8], aR[2][8], qv[2][8];
    float s1[2], s2[2], sa[2], sa2[2], sav[2], sv2[2];
#pragma unroll
    for (int r = 0; r < 2; ++r) {
        const size_t base = (row0 + r) * 512;
        bf16x8 p = *reinterpret_cast<const bf16x8*>(sP + base + c1);
        bf16x8 rr = *reinterpret_cast<const bf16x8*>(sR + base + c1);
        bf16x8 qq = *reinterpret_cast<const bf16x8*>(qb + base + c1);
        bf16x8 vv = *reinterpret_cast<const bf16x8*>(vb + base + c1);
        s1[r] = 0.f; s2[r] = 0.f;
        sa[r] = 0.f; sa2[r] = 0.f; sav[r] = 0.f; sv2[r] = 0.f;
#pragma unroll
        for (int j = 0; j < 8; ++j) {
            const float qf = (float)qq[j];
            const float pf = (float)p[j];
            const float af = (float)rr[j];
            const float vf = (float)vv[j];
            qv[r][j] = qf;
            const float x = qf + pf;
            xP[r][j] = x;
            s1[r] += x; s2[r] += x * x;
            aR[r][j] = af;
            sa[r] += af; sa2[r] += af * af;
            sav[r] += af * vf; sv2[r] += vf * vf;
        }
    }
#pragma unroll
    for (int o = 1; o < 64; o <<= 1)
#pragma unroll
        for (int r = 0; r < 2; ++r) {
            s1[r] += __shfl_xor(s1[r], o);
            s2[r] += __shfl_xor(s2[r], o);
            sa[r] += __shfl_xor(sa[r], o);
            sa2[r] += __shfl_xor(sa2[r], o);
            sav[r] += __shfl_xor(sav[r], o);
            sv2[r] += __shfl_xor(sv2[r], o);
        }
    const float4 g1a = *reinterpret_cast<const float4*>(g1 + c1);
    const float4 g1b = *reinterpret_cast<const float4*>(g1 + c2);
    const float4 b1a = *reinterpret_cast<const float4*>(b1 + c1);
    const float4 b1b = *reinterpret_cast<const float4*>(b1 + c2);
#pragma unroll
    for (int r = 0; r < 2; ++r) {
        const size_t base = (row0 + r) * 512;
        const float mu = s1[r] * (1.f / 512.f);
        const float rs = rsqrtf(s2[r] * (1.f / 512.f) - mu * mu + LN_EPS);
        float4 o1 = make_float4((xP[r][0] - mu) * rs * g1a.x + b1a.x,
                                (xP[r][1] - mu) * rs * g1a.y + b1a.y,
                                (xP[r][2] - mu) * rs * g1a.z + b1a.z,
                                (xP[r][3] - mu) * rs * g1a.w + b1a.w);
        float4 o2 = make_float4((xP[r][4] - mu) * rs * g1b.x + b1b.x,
                                (xP[r][5] - mu) * rs * g1b.y + b1b.y,
                                (xP[r][6] - mu) * rs * g1b.z + b1b.z,
                                (xP[r][7] - mu) * rs * g1b.w + b1b.w);
        *reinterpret_cast<float4*>(fP + base + c1) = o1;
        *reinterpret_cast<float4*>(fP + base + c2) = o2;
    }
    float rrw = 0.f;
    if (lane == 0) {
#pragma unroll
        for (int r = 0; r < 2; ++r) {
            const float na = fmaxf(sqrtf(sa2[r]), 1e-12f);
            const float nv = fmaxf(sqrtf(sv2[r]), 1e-12f);
            rrw += fabsf(1.f - sav[r] / (na * nv));
        }
    }
    const float4 g3a = *reinterpret_cast<const float4*>(g3 + c1);
    const float4 g3b = *reinterpret_cast<const float4*>(g3 + c2);
    const float4 b3a = *reinterpret_cast<const float4*>(b3 + c1);
    const float4 b3b = *reinterpret_cast<const float4*>(b3 + c2);
#pragma unroll
    for (int r = 0; r < 2; ++r) {
        const float mu3 = sa[r] * (1.f / 512.f);
        const float r3 = rsqrtf(sa2[r] * (1.f / 512.f) - mu3 * mu3 + LN_EPS);
        float s1n = 0.f, s2n = 0.f;
        const float gg[8] = {g3a.x, g3a.y, g3a.z, g3a.w, g3b.x, g3b.y, g3b.z, g3b.w};
        const float bb[8] = {b3a.x, b3a.y, b3a.z, b3a.w, b3b.x, b3b.y, b3b.z, b3b.w};
#pragma unroll
        for (int j = 0; j < 8; ++j) {
            const float x = qv[r][j] + (aR[r][j] - mu3) * r3 * gg[j] + bb[j];
            aR[r][j] = x;
            s1n += x; s2n += x * x;
        }
        s1[r] = s1n; s2[r] = s2n;
    }
#pragma unroll
    for (int o = 1; o < 64; o <<= 1)
#pragma unroll
        for (int r = 0; r < 2; ++r) {
            s1[r] += __shfl_xor(s1[r], o);
            s2[r] += __shfl_xor(s2[r], o);
        }
#pragma unroll
    for (int r = 0; r < 2; ++r) {
        const size_t base = (row0 + r) * 512;
        const float mu = s1[r] * (1.f / 512.f);
        const float rs = rsqrtf(s2[r] * (1.f / 512.f) - mu * mu + LN_EPS);
        float4 o1 = make_float4((aR[r][0] - mu) * rs * g1a.x + b1a.x,
                                (aR[r][1] - mu) * rs * g1a.y + b1a.y,
                                (aR[r][2] - mu) * rs * g1a.z + b1a.z,
                                (aR[r][3] - mu) * rs * g1a.w + b1a.w);
        float4 o2 = make_float4((aR[r][4] - mu) * rs * g1b.x + b1b.x,
                                (aR[r][5] - mu) * rs * g1b.y + b1b.y,
                                (aR[r][6] - mu) * rs * g1b.z + b1b.z,
                                (aR[r][7] - mu) * rs * g1b.w + b1b.w);
        *reinterpret_cast<float4*>(fR + base + c1) = o1;
        *reinterpret_cast<float4*>(fR + base + c2) = o2;
    }
    __shared__ float rred[4];
    if (lane == 0) rred[wid] = rrw;
    __syncthreads();
    if (threadIdx.x == 0)
        rrpart[blockIdx.x] = rred[0] + rred[1] + rred[2] + rred[3];
}

// sum block partials -> loss_slots[0]
__global__ __launch_bounds__(256) void reduce_part_k(const float* __restrict__ part,
                                                     int n, float* __restrict__ out) {
    float s = 0.f;
    for (int i = threadIdx.x; i < n; i += 256) s += part[i];
    s = wave_sum(s);
    __shared__ float red[4];
    const int wid = threadIdx.x >> 6, lane = threadIdx.x & 63;
    if (lane == 0) red[wid] = s;
    __syncthreads();
    if (threadIdx.x == 0)
        out[0] = (red[0] + red[1] + red[2] + red[3]) * (1.f / 32768.f);
}

extern "C" void kernel_launch(void* const* d_in, const int* in_sizes, int n_in,
                              void* d_out, int out_size, void* d_ws, size_t ws_size,
                              hipStream_t stream) {
    const float* query = (const float*)d_in[0];
    const float* value = (const float*)d_in[1];
    const float* mem_key = (const float*)d_in[2];
    const float* mem_value = (const float*)d_in[3];
    const float* q_w = (const float*)d_in[4];
    const float* q_b = (const float*)d_in[5];
    const float* v_w = (const float*)d_in[6];
    const float* v_b = (const float*)d_in[7];
    const float* out_w = (const float*)d_in[8];
    const float* out_b = (const float*)d_in[9];
    const float* ln1_g = (const float*)d_in[10];
    const float* ln1_b = (const float*)d_in[11];
    const float* ln3_g = (const float*)d_in[12];
    const float* ln3_b = (const float*)d_in[13];
    float* out = (float*)d_out;

    char* ws = (char*)d_ws;
    size_t off = 0;
    auto alloc = [&](size_t bytes) {
        void* p = ws + off;
        off += (bytes + 255) & ~(size_t)255;
        return p;
    };
    bf16_t* qb = (bf16_t*)alloc(16777216ull * 2);      // query bf16 (live to end)
    bf16_t* vb = (bf16_t*)alloc(16777216ull * 2);      // value bf16 (live to end)
    bf16_t* qpb = (bf16_t*)alloc(16777216ull * 2);     // qp; stageP aliases after addr_predict
    bf16_t* vpb = (bf16_t*)alloc(16777216ull * 2);     // vp; stageR aliases after sim_softmax
    bf16_t* addr = (bf16_t*)alloc(32768ull * 896 * 2); // addr [N][896]
    bf16_t* addr2 = (bf16_t*)alloc(32768ull * 128 * 2);// addr2 [N][128] (separate!)
    bf16_t* qwb = (bf16_t*)alloc(262144ull * 2);
    bf16_t* vwb = (bf16_t*)alloc(262144ull * 2);
    bf16_t* owb = (bf16_t*)alloc(2097152ull * 2);
    bf16_t* wct = (bf16_t*)alloc(896ull * 512 * 2);    // WcT[512][896]
    bf16_t* keyn = (bf16_t*)alloc(896ull * 64 * 2);
    bf16_t* mvb = (bf16_t*)alloc(128ull * 512 * 2);
    bf16_t* mvT = (bf16_t*)alloc(512ull * 128 * 2);
    float* invmv = (float*)alloc(112 * 4);
    float* rrpart = (float*)alloc(4096 * 4);
    bf16_t* stageP = qpb;
    bf16_t* stageR = vpb;

    float* f_predict = out;
    float* f_recon = out + 16777216;
    float* loss_slots = out + 33554432;  // [recon_loss, contrastive_loss]

    // prep
    cast_all<<<2048, 256, 0, stream>>>(query, value, q_w, v_w, out_w,
                                       qb, vb, qwb, vwb, owb);
    keyn_k<<<224, 256, 0, stream>>>(mem_key, keyn);
    mv_prep_k<<<128, 256, 0, stream>>>(mem_value, mvb, mvT, invmv, loss_slots);
    contrastive_k<<<112, 256, 0, stream>>>(mem_value, invmv, loss_slots + 1);
    // WcT[d][h*112+s] = sum_j out_w[d][h*512+j] * mem_value[s][j]
    gemm_bt<<<dim3(8, 2, 8), 256, 0, stream>>>(owb, 4096, 512, mvb, 512, 0,
                                               wct, 896, 112, 512, 112, 512);
    // both projections in ONE dispatch
    gemm_dual<<<dim3(256, 4, 2), 256, 0, stream>>>(
        qb, 512, qwb, 512, q_b, qpb, 512,
        vb, 512, vwb, 512, v_b, vpb, 512);
    // addressing (both branches; independent)
    addr_predict<<<dim3(512, 8), 256, 0, stream>>>(qpb, keyn, addr);
    gemm_sim_softmax<<<512, 256, 0, stream>>>(vpb, mvb, invmv, addr2);
    // both stage GEMMs in ONE dispatch
    gemm_dual<<<dim3(256, 4, 2), 256, 0, stream>>>(
        addr, 896, wct, 896, out_b, stageP, 896,
        addr2, 128, mvT, 128, (const float*)nullptr, stageR, 128);
    // both epilogues fused
    fused_ep<<<4096, 256, 0, stream>>>(stageP, stageR, qb, vb,
                                       ln1_g, ln1_b, ln3_g, ln3_b,
                                       f_predict, f_recon, rrpart);
    reduce_part_k<<<1, 256, 0, stream>>>(rrpart, 4096, loss_slots);
}

// Round 12
// 306.612 us; speedup vs baseline: 1.1839x; 1.0038x over previous
//
#include <hip/hip_runtime.h>
#include <hip/hip_bf16.h>
#include <math.h>

typedef __bf16 bf16_t;
typedef __attribute__((ext_vector_type(8))) __bf16 bf16x8;
typedef __attribute__((ext_vector_type(4))) __bf16 bf16x4;
typedef __attribute__((ext_vector_type(4))) float f32x4;

#define LN_EPS 1e-5f
#define RADIUS_F 16.0f

__device__ inline bf16x8 zero8() {
    bf16x8 v;
#pragma unroll
    for (int i = 0; i < 8; ++i) v[i] = (__bf16)0.f;
    return v;
}

__device__ inline float wave_sum(float v) {
#pragma unroll
    for (int o = 1; o < 64; o <<= 1) v += __shfl_xor(v, o);
    return v;
}

__device__ inline void gload_lds16(const bf16_t* g, bf16_t* l) {
    __builtin_amdgcn_global_load_lds(
        (const __attribute__((address_space(1))) void*)g,
        (__attribute__((address_space(3))) void*)l, 16, 0, 0);
}

__device__ inline void drain_barrier() {
    asm volatile("s_waitcnt vmcnt(0)" ::: "memory");
    __builtin_amdgcn_s_barrier();
}

// ---------------- one grid-stride cast for q, v, and all three weights ----------------
__global__ __launch_bounds__(256) void cast_all(
    const float* __restrict__ q, const float* __restrict__ v,
    const float* __restrict__ qw, const float* __restrict__ vw,
    const float* __restrict__ ow,
    bf16_t* __restrict__ qb, bf16_t* __restrict__ vb,
    bf16_t* __restrict__ qwb, bf16_t* __restrict__ vwb,
    bf16_t* __restrict__ owb) {
    const int total = 9043968;  // float4 count
    for (int i = blockIdx.x * 256 + threadIdx.x; i < total; i += gridDim.x * 256) {
        const float* src;
        bf16_t* dst;
        int j;
        if (i < 4194304) { src = q; dst = qb; j = i; }
        else if (i < 8388608) { src = v; dst = vb; j = i - 4194304; }
        else if (i < 8454144) { src = qw; dst = qwb; j = i - 8388608; }
        else if (i < 8519680) { src = vw; dst = vwb; j = i - 8454144; }
        else { src = ow; dst = owb; j = i - 8519680; }
        float4 x = reinterpret_cast<const float4*>(src)[j];
        bf16x4 o;
        o[0] = (__bf16)x.x; o[1] = (__bf16)x.y; o[2] = (__bf16)x.z; o[3] = (__bf16)x.w;
        reinterpret_cast<bf16x4*>(dst)[j] = o;
    }
}

// normalize mem_key rows (896 x 64) -> bf16
__global__ __launch_bounds__(256) void keyn_k(const float* __restrict__ mk,
                                              bf16_t* __restrict__ kn) {
    int row = blockIdx.x * 4 + (threadIdx.x >> 6);
    int lane = threadIdx.x & 63;
    float x = mk[(size_t)row * 64 + lane];
    float ss = wave_sum(x * x);
    kn[(size_t)row * 64 + lane] = (__bf16)(x / fmaxf(sqrtf(ss), 1e-12f));
}

// mem_value: row inv-norms + bf16 copy (padded to 128) + transposed copy; zero loss
__global__ __launch_bounds__(256) void mv_prep_k(const float* __restrict__ mv,
                                                 bf16_t* __restrict__ mvb,
                                                 bf16_t* __restrict__ mvT,
                                                 float* __restrict__ invmv,
                                                 float* __restrict__ loss_slots) {
    const int s = blockIdx.x, tid = threadIdx.x;
    if (s >= 112) {
        mvb[(size_t)s * 512 + tid * 2] = (__bf16)0.f;
        mvb[(size_t)s * 512 + tid * 2 + 1] = (__bf16)0.f;
        mvT[(size_t)tid * 128 + s] = (__bf16)0.f;
        mvT[(size_t)(tid + 256) * 128 + s] = (__bf16)0.f;
        return;
    }
    float2 x = *reinterpret_cast<const float2*>(mv + (size_t)s * 512 + tid * 2);
    float ss = wave_sum(x.x * x.x + x.y * x.y);
    __shared__ float red[4];
    int wid = tid >> 6, lane = tid & 63;
    if (lane == 0) red[wid] = ss;
    __syncthreads();
    ss = red[0] + red[1] + red[2] + red[3];
    if (tid == 0) invmv[s] = 1.f / fmaxf(sqrtf(ss), 1e-12f);
    mvb[(size_t)s * 512 + tid * 2] = (__bf16)x.x;
    mvb[(size_t)s * 512 + tid * 2 + 1] = (__bf16)x.y;
    mvT[(size_t)tid * 128 + s] = (__bf16)mv[(size_t)s * 512 + tid];
    mvT[(size_t)(tid + 256) * 128 + s] = (__bf16)mv[(size_t)s * 512 + tid + 256];
    if (s == 0 && tid < 2) loss_slots[tid] = 0.f;
}

// contrastive loss: sum |I - Gn Gn^T| * 0.01  (fp32)
__global__ __launch_bounds__(256) void contrastive_k(const float* __restrict__ mv,
                                                     const float* __restrict__ invmv,
                                                     float* __restrict__ out_slot) {
    const int a = blockIdx.x;
    const int tid = threadIdx.x, wid = tid >> 6, lane = tid & 63;
    __shared__ float rowa[512];
    __shared__ float wsum[4];
    for (int i = tid; i < 512; i += 256) rowa[i] = mv[(size_t)a * 512 + i];
    __syncthreads();
    float acc = 0.f;
    const float ia = invmv[a];
    for (int b = wid; b < 112; b += 4) {
        float d = 0.f;
#pragma unroll
        for (int i = 0; i < 8; ++i) d += rowa[lane + i * 64] * mv[(size_t)b * 512 + lane + i * 64];
        d = wave_sum(d);
        float gv = d * ia * invmv[b];
        acc += fabsf((a == b ? 1.f : 0.f) - gv);
    }
    if (lane == 0) wsum[wid] = acc;
    __syncthreads();
    if (tid == 0) atomicAdd(out_slot, (wsum[0] + wsum[1] + wsum[2] + wsum[3]) * 0.01f);
}

// ---------------- dual 128x128 GEMM: 3-buffer depth-2 counted-vmcnt pipeline ----------------
// z=0: C0 = A0 @ W0^T + bias0 (K0) ; z=1: same with *1 args. ldc fixed 512.
// Pipeline: tiles k+1,k+2 in flight across the barrier; wait vmcnt(4) (= older
// tile's 4 loads done), NEVER vmcnt(0) in steady state.
__global__ __launch_bounds__(256) void gemm_dual(
    const bf16_t* __restrict__ A0, int lda0, const bf16_t* __restrict__ W0, int ldw0,
    const float* __restrict__ bias0, bf16_t* __restrict__ C0, int K0,
    const bf16_t* __restrict__ A1, int lda1, const bf16_t* __restrict__ W1, int ldw1,
    const float* __restrict__ bias1, bf16_t* __restrict__ C1, int K1) {
    const bf16_t* A = blockIdx.z ? A1 : A0;
    const bf16_t* W = blockIdx.z ? W1 : W0;
    const float* bias = blockIdx.z ? bias1 : bias0;
    bf16_t* Cb = blockIdx.z ? C1 : C0;
    const int lda = blockIdx.z ? lda1 : lda0;
    const int ldw = blockIdx.z ? ldw1 : ldw0;
    const int K = blockIdx.z ? K1 : K0;
    __shared__ __align__(16) bf16_t As[3][128 * 32];
    __shared__ __align__(16) bf16_t Bs[3][128 * 32];
    const int tid = threadIdx.x;
    const int wid = tid >> 6, lane = tid & 63;
    const int wr = wid >> 1, wc = wid & 1;
    const int lr = lane & 15;
    const int ko = (lane >> 4) * 8;
    const size_t rowBase = (size_t)blockIdx.x * 128;
    const size_t colBase = (size_t)blockIdx.y * 128;
    const int r0 = tid >> 2;
    const int c0 = (tid & 3) * 8;
    const bf16_t* a_src = A + (rowBase + r0) * lda + c0;
    const bf16_t* w_src = W + (colBase + r0) * ldw + c0;
    f32x4 acc[4][4];
#pragma unroll
    for (int m = 0; m < 4; ++m)
#pragma unroll
        for (int n = 0; n < 4; ++n) {
            acc[m][n][0] = 0.f; acc[m][n][1] = 0.f;
            acc[m][n][2] = 0.f; acc[m][n][3] = 0.f;
        }
    auto stage = [&](int buf, int ks) {
        const int k0 = ks * 32;
        gload_lds16(a_src + k0, &As[buf][tid * 8]);
        gload_lds16(a_src + (size_t)64 * lda + k0, &As[buf][2048 + tid * 8]);
        gload_lds16(w_src + k0, &Bs[buf][tid * 8]);
        gload_lds16(w_src + (size_t)64 * ldw + k0, &Bs[buf][2048 + tid * 8]);
    };
    const int nt = K >> 5;  // all call sites have nt >= 4
    stage(0, 0);
    stage(1, 1);
    asm volatile("s_waitcnt vmcnt(4)" ::: "memory");  // tile 0 landed; tile 1 in flight
    __builtin_amdgcn_s_barrier();
    int cur = 0;
    for (int ks = 0; ks < nt; ++ks) {
        const int pre = (cur == 0) ? 2 : (cur - 1);  // (cur+2)%3
        if (ks + 2 < nt) stage(pre, ks + 2);
        bf16x8 af[4], bfr[4];
#pragma unroll
        for (int m = 0; m < 4; ++m)
            af[m] = *reinterpret_cast<const bf16x8*>(&As[cur][(wr * 64 + m * 16 + lr) * 32 + ko]);
#pragma unroll
        for (int n = 0; n < 4; ++n)
            bfr[n] = *reinterpret_cast<const bf16x8*>(&Bs[cur][(wc * 64 + n * 16 + lr) * 32 + ko]);
#pragma unroll
        for (int m = 0; m < 4; ++m)
#pragma unroll
            for (int n = 0; n < 4; ++n)
                acc[m][n] = __builtin_amdgcn_mfma_f32_16x16x32_bf16(af[m], bfr[n], acc[m][n], 0, 0, 0);
        if (ks + 1 < nt) {
            // next tile (ks+1) must have landed; newer tile (ks+2) may stay in flight
            if (ks + 2 < nt) asm volatile("s_waitcnt vmcnt(4)" ::: "memory");
            else             asm volatile("s_waitcnt vmcnt(0)" ::: "memory");
            __builtin_amdgcn_s_barrier();
        }
        cur = (cur == 2) ? 0 : (cur + 1);
    }
    const int rj = (lane >> 4) * 4;
#pragma unroll
    for (int n = 0; n < 4; ++n) {
        const int col = (int)colBase + wc * 64 + n * 16 + lr;
        const float bv = bias ? bias[col] : 0.f;
#pragma unroll
        for (int m = 0; m < 4; ++m) {
            const size_t r = rowBase + wr * 64 + m * 16 + rj;
#pragma unroll
            for (int j = 0; j < 4; ++j)
                Cb[(r + j) * 512 + col] = (__bf16)(acc[m][n][j] + bv);
        }
    }
}

// ---------------- small direct GEMM (WcT fold only) ----------------
__global__ __launch_bounds__(256) void gemm_bt(
    const bf16_t* __restrict__ A, int lda, int aZ,
    const bf16_t* __restrict__ W, int ldw, int wZ,
    bf16_t* __restrict__ Cb, int ldc, int cZ,
    int M, int N, int K) {
    const int wid = threadIdx.x >> 6;
    const int lane = threadIdx.x & 63;
    const int lr = lane & 15;
    const int kk = (lane >> 4) * 8;
    const int row0 = blockIdx.x * 64 + wid * 16;
    const int col0 = blockIdx.y * 64;
    A += (size_t)blockIdx.z * aZ;
    W += (size_t)blockIdx.z * wZ;
    const bf16_t* a_ptr = A + (size_t)(row0 + lr) * lda + kk;
    const bf16_t* w_ptr = W + (size_t)(col0 + lr) * ldw + kk;
    f32x4 acc[4];
#pragma unroll
    for (int t = 0; t < 4; ++t) { acc[t][0] = 0.f; acc[t][1] = 0.f; acc[t][2] = 0.f; acc[t][3] = 0.f; }
    bool colv[4];
#pragma unroll
    for (int t = 0; t < 4; ++t) colv[t] = (col0 + t * 16 + lr) < N;
    for (int k0 = 0; k0 < K; k0 += 32) {
        bf16x8 a = *reinterpret_cast<const bf16x8*>(a_ptr + k0);
#pragma unroll
        for (int t = 0; t < 4; ++t) {
            bf16x8 b;
            if (colv[t]) b = *reinterpret_cast<const bf16x8*>(w_ptr + (size_t)t * 16 * ldw + k0);
            else b = zero8();
            acc[t] = __builtin_amdgcn_mfma_f32_16x16x32_bf16(a, b, acc[t], 0, 0, 0);
        }
    }
    const int rb = (lane >> 4) * 4;
    Cb += (size_t)blockIdx.z * cZ;
#pragma unroll
    for (int t = 0; t < 4; ++t) {
        int col = col0 + t * 16 + lr;
        if (col >= N) continue;
#pragma unroll
        for (int j = 0; j < 4; ++j) {
            int r = row0 + rb + j;
            Cb[(size_t)r * ldc + col] = (__bf16)acc[t][j];
        }
    }
}

// ---------------- predict addressing: sim -> softmax -> addr bf16 [N,896] ----------------
__global__ __launch_bounds__(256) void addr_predict(const bf16_t* __restrict__ qp,
                                                    const bf16_t* __restrict__ keyn,
                                                    bf16_t* __restrict__ addr) {
    const int wid = threadIdx.x >> 6, lane = threadIdx.x & 63;
    const int lr = lane & 15, kk = (lane >> 4) * 8;
    const int h = blockIdx.y;
    const int row0 = blockIdx.x * 64 + wid * 16;
    const bf16_t* a_ptr = qp + (size_t)(row0 + lr) * 512 + h * 64 + kk;
    bf16x8 a0 = *reinterpret_cast<const bf16x8*>(a_ptr);
    bf16x8 a1 = *reinterpret_cast<const bf16x8*>(a_ptr + 32);
    float ssq = 0.f;
#pragma unroll
    for (int j = 0; j < 8; ++j) {
        float x = (float)a0[j], y = (float)a1[j];
        ssq += x * x + y * y;
    }
    ssq += __shfl_xor(ssq, 16);
    ssq += __shfl_xor(ssq, 32);
    const float invq = 1.f / fmaxf(sqrtf(ssq), 1e-12f);
    f32x4 acc[7];
#pragma unroll
    for (int t = 0; t < 7; ++t) {
        const bf16_t* b_ptr = keyn + (size_t)(h * 112 + t * 16 + lr) * 64 + kk;
        bf16x8 b0 = *reinterpret_cast<const bf16x8*>(b_ptr);
        bf16x8 b1 = *reinterpret_cast<const bf16x8*>(b_ptr + 32);
        f32x4 c; c[0] = 0.f; c[1] = 0.f; c[2] = 0.f; c[3] = 0.f;
        c = __builtin_amdgcn_mfma_f32_16x16x32_bf16(a0, b0, c, 0, 0, 0);
        c = __builtin_amdgcn_mfma_f32_16x16x32_bf16(a1, b1, c, 0, 0, 0);
        acc[t] = c;
    }
    const int rb = (lane >> 4) * 4;
    float iq[4];
#pragma unroll
    for (int j = 0; j < 4; ++j) iq[j] = __shfl(invq, rb + j);
#pragma unroll
    for (int j = 0; j < 4; ++j) {
        float m = -1e30f;
#pragma unroll
        for (int t = 0; t < 7; ++t) { acc[t][j] *= iq[j] * RADIUS_F; m = fmaxf(m, acc[t][j]); }
#pragma unroll
        for (int o = 1; o < 16; o <<= 1) m = fmaxf(m, __shfl_xor(m, o));
        float s = 0.f;
#pragma unroll
        for (int t = 0; t < 7; ++t) { float e = __expf(acc[t][j] - m); acc[t][j] = e; s += e; }
#pragma unroll
        for (int o = 1; o < 16; o <<= 1) s += __shfl_xor(s, o);
        const float rs = 1.f / s;
#pragma unroll
        for (int t = 0; t < 7; ++t) acc[t][j] *= rs;
    }
#pragma unroll
    for (int t = 0; t < 7; ++t)
#pragma unroll
        for (int j = 0; j < 4; ++j)
            addr[(size_t)(row0 + rb + j) * 896 + h * 112 + t * 16 + lr] = (__bf16)acc[t][j];
}

// ---------------- fused recon sim GEMM + softmax -> addr2 [M][128] ----------------
// 64 rows/block (grid 512 -> 2 blocks/CU), 4 waves x 16 rows, dbuf.
__global__ __launch_bounds__(256) void gemm_sim_softmax(
    const bf16_t* __restrict__ vp,   // [M][512]
    const bf16_t* __restrict__ mvb,  // [128][512] (rows 112..127 zero)
    const float* __restrict__ invmv, // [112]
    bf16_t* __restrict__ addr2) {    // [M][128]
    __shared__ __align__(16) bf16_t As[2][64 * 32];
    __shared__ __align__(16) bf16_t Bs[2][128 * 32];
    const int tid = threadIdx.x;
    const int wid = tid >> 6, lane = tid & 63;
    const int lr = lane & 15, hi = lane >> 4;
    const int ko = hi * 8;
    const size_t rowBase = (size_t)blockIdx.x * 64;
    const int r0 = tid >> 2, c0 = (tid & 3) * 8;
    const bf16_t* a_src = vp + (rowBase + r0) * 512 + c0;
    const bf16_t* b_src = mvb + (size_t)r0 * 512 + c0;
    f32x4 acc[8];
#pragma unroll
    for (int n = 0; n < 8; ++n) {
        acc[n][0] = 0.f; acc[n][1] = 0.f; acc[n][2] = 0.f; acc[n][3] = 0.f;
    }
    float ssq = 0.f;
    auto stage = [&](int buf, int ks) {
        const int k0 = ks * 32;
        gload_lds16(a_src + k0, &As[buf][tid * 8]);
        gload_lds16(b_src + k0, &Bs[buf][tid * 8]);
        gload_lds16(b_src + (size_t)64 * 512 + k0, &Bs[buf][2048 + tid * 8]);
    };
    stage(0, 0);
    drain_barrier();
    int cur = 0;
    for (int ks = 0; ks < 16; ++ks) {
        if (ks < 15) stage(cur ^ 1, ks + 1);
        bf16x8 af, bfr[8];
        af = *reinterpret_cast<const bf16x8*>(&As[cur][(wid * 16 + lr) * 32 + ko]);
#pragma unroll
        for (int n = 0; n < 8; ++n)
            bfr[n] = *reinterpret_cast<const bf16x8*>(&Bs[cur][(n * 16 + lr) * 32 + ko]);
#pragma unroll
        for (int j = 0; j < 8; ++j) { float x = (float)af[j]; ssq += x * x; }
#pragma unroll
        for (int n = 0; n < 8; ++n)
            acc[n] = __builtin_amdgcn_mfma_f32_16x16x32_bf16(af, bfr[n], acc[n], 0, 0, 0);
        drain_barrier();
        cur ^= 1;
    }
    ssq += __shfl_xor(ssq, 16);
    ssq += __shfl_xor(ssq, 32);
    ssq = 1.f / fmaxf(sqrtf(ssq), 1e-12f);
    const int rb = hi * 4;
    float imv[7];
#pragma unroll
    for (int n = 0; n < 7; ++n) imv[n] = invmv[n * 16 + lr];
#pragma unroll
    for (int j = 0; j < 4; ++j) {
        const float iq = __shfl(ssq, (lane & 48) | (rb + j));
        float x[7];
        float mx = -1e30f;
#pragma unroll
        for (int n = 0; n < 7; ++n) {
            x[n] = acc[n][j] * iq * imv[n] * RADIUS_F;
            mx = fmaxf(mx, x[n]);
        }
#pragma unroll
        for (int o = 1; o < 16; o <<= 1) mx = fmaxf(mx, __shfl_xor(mx, o));
        float s = 0.f;
#pragma unroll
        for (int n = 0; n < 7; ++n) { x[n] = __expf(x[n] - mx); s += x[n]; }
#pragma unroll
        for (int o = 1; o < 16; o <<= 1) s += __shfl_xor(s, o);
        const float rs = 1.f / s;
        const size_t row = rowBase + wid * 16 + rb + j;
#pragma unroll
        for (int n = 0; n < 7; ++n)
            addr2[row * 128 + n * 16 + lr] = (__bf16)(x[n] * rs);
        addr2[row * 128 + 112 + lr] = (__bf16)0.f;
    }
}

// ---------------- fused epilogue: BOTH branches, 2 rows/wave, all-bf16 inputs ----------------
__global__ __launch_bounds__(256) void fused_ep(
    const bf16_t* __restrict__ sP, const bf16_t* __restrict__ sR,
    const bf16_t* __restrict__ qb, const bf16_t* __restrict__ vb,
    const float* __restrict__ g1, const float* __restrict__ b1,
    const float* __restrict__ g3, const float* __restrict__ b3,
    float* __restrict__ fP, float* __restrict__ fR,
    float* __restrict__ rrpart) {
    const int wid = threadIdx.x >> 6, lane = threadIdx.x & 63;
    const size_t row0 = (size_t)blockIdx.x * 8 + wid * 2;
    const int c1 = lane * 8, c2 = lane * 8 + 4;
    float xP[2][8], aR[2][8], qv[2][8];
    float s1[2], s2[2], sa[2], sa2[2], sav[2], sv2[2];
#pragma unroll
    for (int r = 0; r < 2; ++r) {
        const size_t base = (row0 + r) * 512;
        bf16x8 p = *reinterpret_cast<const bf16x8*>(sP + base + c1);
        bf16x8 rr = *reinterpret_cast<const bf16x8*>(sR + base + c1);
        bf16x8 qq = *reinterpret_cast<const bf16x8*>(qb + base + c1);
        bf16x8 vv = *reinterpret_cast<const bf16x8*>(vb + base + c1);
        s1[r] = 0.f; s2[r] = 0.f;
        sa[r] = 0.f; sa2[r] = 0.f; sav[r] = 0.f; sv2[r] = 0.f;
#pragma unroll
        for (int j = 0; j < 8; ++j) {
            const float qf = (float)qq[j];
            const float pf = (float)p[j];
            const float af = (float)rr[j];
            const float vf = (float)vv[j];
            qv[r][j] = qf;
            const float x = qf + pf;
            xP[r][j] = x;
            s1[r] += x; s2[r] += x * x;
            aR[r][j] = af;
            sa[r] += af; sa2[r] += af * af;
            sav[r] += af * vf; sv2[r] += vf * vf;
        }
    }
#pragma unroll
    for (int o = 1; o < 64; o <<= 1)
#pragma unroll
        for (int r = 0; r < 2; ++r) {
            s1[r] += __shfl_xor(s1[r], o);
            s2[r] += __shfl_xor(s2[r], o);
            sa[r] += __shfl_xor(sa[r], o);
            sa2[r] += __shfl_xor(sa2[r], o);
            sav[r] += __shfl_xor(sav[r], o);
            sv2[r] += __shfl_xor(sv2[r], o);
        }
    const float4 g1a = *reinterpret_cast<const float4*>(g1 + c1);
    const float4 g1b = *reinterpret_cast<const float4*>(g1 + c2);
    const float4 b1a = *reinterpret_cast<const float4*>(b1 + c1);
    const float4 b1b = *reinterpret_cast<const float4*>(b1 + c2);
#pragma unroll
    for (int r = 0; r < 2; ++r) {
        const size_t base = (row0 + r) * 512;
        const float mu = s1[r] * (1.f / 512.f);
        const float rs = rsqrtf(s2[r] * (1.f / 512.f) - mu * mu + LN_EPS);
        float4 o1 = make_float4((xP[r][0] - mu) * rs * g1a.x + b1a.x,
                                (xP[r][1] - mu) * rs * g1a.y + b1a.y,
                                (xP[r][2] - mu) * rs * g1a.z + b1a.z,
                                (xP[r][3] - mu) * rs * g1a.w + b1a.w);
        float4 o2 = make_float4((xP[r][4] - mu) * rs * g1b.x + b1b.x,
                                (xP[r][5] - mu) * rs * g1b.y + b1b.y,
                                (xP[r][6] - mu) * rs * g1b.z + b1b.z,
                                (xP[r][7] - mu) * rs * g1b.w + b1b.w);
        *reinterpret_cast<float4*>(fP + base + c1) = o1;
        *reinterpret_cast<float4*>(fP + base + c2) = o2;
    }
    float rrw = 0.f;
    if (lane == 0) {
#pragma unroll
        for (int r = 0; r < 2; ++r) {
            const float na = fmaxf(sqrtf(sa2[r]), 1e-12f);
            const float nv = fmaxf(sqrtf(sv2[r]), 1e-12f);
            rrw += fabsf(1.f - sav[r] / (na * nv));
        }
    }
    const float4 g3a = *reinterpret_cast<const float4*>(g3 + c1);
    const float4 g3b = *reinterpret_cast<const float4*>(g3 + c2);
    const float4 b3a = *reinterpret_cast<const float4*>(b3 + c1);
    const float4 b3b = *reinterpret_cast<const float4*>(b3 + c2);
#pragma unroll
    for (int r = 0; r < 2; ++r) {
        const float mu3 = sa[r] * (1.f / 512.f);
        const float r3 = rsqrtf(sa2[r] * (1.f / 512.f) - mu3 * mu3 + LN_EPS);
        float s1n = 0.f, s2n = 0.f;
        const float gg[8] = {g3a.x, g3a.y, g3a.z, g3a.w, g3b.x, g3b.y, g3b.z, g3b.w};
        const float bb[8] = {b3a.x, b3a.y, b3a.z, b3a.w, b3b.x, b3b.y, b3b.z, b3b.w};
#pragma unroll
        for (int j = 0; j < 8; ++j) {
            const float x = qv[r][j] + (aR[r][j] - mu3) * r3 * gg[j] + bb[j];
            aR[r][j] = x;
            s1n += x; s2n += x * x;
        }
        s1[r] = s1n; s2[r] = s2n;
    }
#pragma unroll
    for (int o = 1; o < 64; o <<= 1)
#pragma unroll
        for (int r = 0; r < 2; ++r) {
            s1[r] += __shfl_xor(s1[r], o);
            s2[r] += __shfl_xor(s2[r], o);
        }
#pragma unroll
    for (int r = 0; r < 2; ++r) {
        const size_t base = (row0 + r) * 512;
        const float mu = s1[r] * (1.f / 512.f);
        const float rs = rsqrtf(s2[r] * (1.f / 512.f) - mu * mu + LN_EPS);
        float4 o1 = make_float4((aR[r][0] - mu) * rs * g1a.x + b1a.x,
                                (aR[r][1] - mu) * rs * g1a.y + b1a.y,
                                (aR[r][2] - mu) * rs * g1a.z + b1a.z,
                                (aR[r][3] - mu) * rs * g1a.w + b1a.w);
        float4 o2 = make_float4((aR[r][4] - mu) * rs * g1b.x + b1b.x,
                                (aR[r][5] - mu) * rs * g1b.y + b1b.y,
                                (aR[r][6] - mu) * rs * g1b.z + b1b.z,
                                (aR[r][7] - mu) * rs * g1b.w + b1b.w);
        *reinterpret_cast<float4*>(fR + base + c1) = o1;
        *reinterpret_cast<float4*>(fR + base + c2) = o2;
    }
    __shared__ float rred[4];
    if (lane == 0) rred[wid] = rrw;
    __syncthreads();
    if (threadIdx.x == 0)
        rrpart[blockIdx.x] = rred[0] + rred[1] + rred[2] + rred[3];
}

// sum block partials -> loss_slots[0]
__global__ __launch_bounds__(256) void reduce_part_k(const float* __restrict__ part,
                                                     int n, float* __restrict__ out) {
    float s = 0.f;
    for (int i = threadIdx.x; i < n; i += 256) s += part[i];
    s = wave_sum(s);
    __shared__ float red[4];
    const int wid = threadIdx.x >> 6, lane = threadIdx.x & 63;
    if (lane == 0) red[wid] = s;
    __syncthreads();
    if (threadIdx.x == 0)
        out[0] = (red[0] + red[1] + red[2] + red[3]) * (1.f / 32768.f);
}

extern "C" void kernel_launch(void* const* d_in, const int* in_sizes, int n_in,
                              void* d_out, int out_size, void* d_ws, size_t ws_size,
                              hipStream_t stream) {
    const float* query = (const float*)d_in[0];
    const float* value = (const float*)d_in[1];
    const float* mem_key = (const float*)d_in[2];
    const float* mem_value = (const float*)d_in[3];
    const float* q_w = (const float*)d_in[4];
    const float* q_b = (const float*)d_in[5];
    const float* v_w = (const float*)d_in[6];
    const float* v_b = (const float*)d_in[7];
    const float* out_w = (const float*)d_in[8];
    const float* out_b = (const float*)d_in[9];
    const float* ln1_g = (const float*)d_in[10];
    const float* ln1_b = (const float*)d_in[11];
    const float* ln3_g = (const float*)d_in[12];
    const float* ln3_b = (const float*)d_in[13];
    float* out = (float*)d_out;

    char* ws = (char*)d_ws;
    size_t off = 0;
    auto alloc = [&](size_t bytes) {
        void* p = ws + off;
        off += (bytes + 255) & ~(size_t)255;
        return p;
    };
    bf16_t* qb = (bf16_t*)alloc(16777216ull * 2);      // query bf16 (live to end)
    bf16_t* vb = (bf16_t*)alloc(16777216ull * 2);      // value bf16 (live to end)
    bf16_t* qpb = (bf16_t*)alloc(16777216ull * 2);     // qp; stageP aliases after addr_predict
    bf16_t* vpb = (bf16_t*)alloc(16777216ull * 2);     // vp; stageR aliases after sim_softmax
    bf16_t* addr = (bf16_t*)alloc(32768ull * 896 * 2); // addr [N][896]
    bf16_t* addr2 = (bf16_t*)alloc(32768ull * 128 * 2);// addr2 [N][128]
    bf16_t* qwb = (bf16_t*)alloc(262144ull * 2);
    bf16_t* vwb = (bf16_t*)alloc(262144ull * 2);
    bf16_t* owb = (bf16_t*)alloc(2097152ull * 2);
    bf16_t* wct = (bf16_t*)alloc(896ull * 512 * 2);    // WcT[512][896]
    bf16_t* keyn = (bf16_t*)alloc(896ull * 64 * 2);
    bf16_t* mvb = (bf16_t*)alloc(128ull * 512 * 2);
    bf16_t* mvT = (bf16_t*)alloc(512ull * 128 * 2);
    float* invmv = (float*)alloc(112 * 4);
    float* rrpart = (float*)alloc(4096 * 4);
    bf16_t* stageP = qpb;
    bf16_t* stageR = vpb;

    float* f_predict = out;
    float* f_recon = out + 16777216;
    float* loss_slots = out + 33554432;  // [recon_loss, contrastive_loss]

    // prep
    cast_all<<<2048, 256, 0, stream>>>(query, value, q_w, v_w, out_w,
                                       qb, vb, qwb, vwb, owb);
    keyn_k<<<224, 256, 0, stream>>>(mem_key, keyn);
    mv_prep_k<<<128, 256, 0, stream>>>(mem_value, mvb, mvT, invmv, loss_slots);
    contrastive_k<<<112, 256, 0, stream>>>(mem_value, invmv, loss_slots + 1);
    // WcT[d][h*112+s] = sum_j out_w[d][h*512+j] * mem_value[s][j]
    gemm_bt<<<dim3(8, 2, 8), 256, 0, stream>>>(owb, 4096, 512, mvb, 512, 0,
                                               wct, 896, 112, 512, 112, 512);
    // both projections in ONE dispatch (depth-2 pipelined)
    gemm_dual<<<dim3(256, 4, 2), 256, 0, stream>>>(
        qb, 512, qwb, 512, q_b, qpb, 512,
        vb, 512, vwb, 512, v_b, vpb, 512);
    // addressing (both branches; independent)
    addr_predict<<<dim3(512, 8), 256, 0, stream>>>(qpb, keyn, addr);
    gemm_sim_softmax<<<512, 256, 0, stream>>>(vpb, mvb, invmv, addr2);
    // both stage GEMMs in ONE dispatch (depth-2 pipelined)
    gemm_dual<<<dim3(256, 4, 2), 256, 0, stream>>>(
        addr, 896, wct, 896, out_b, stageP, 896,
        addr2, 128, mvT, 128, (const float*)nullptr, stageR, 128);
    // both epilogues fused
    fused_ep<<<4096, 256, 0, stream>>>(stageP, stageR, qb, vb,
                                       ln1_g, ln1_b, ln3_g, ln3_b,
                                       f_predict, f_recon, rrpart);
    reduce_part_k<<<1, 256, 0, stream>>>(rrpart, 4096, loss_slots);
}

// Round 13
// 281.822 us; speedup vs baseline: 1.2880x; 1.0880x over previous
//
#include <hip/hip_runtime.h>
#include <hip/hip_bf16.h>
#include <math.h>

typedef __bf16 bf16_t;
typedef __attribute__((ext_vector_type(8))) __bf16 bf16x8;
typedef __attribute__((ext_vector_type(4))) __bf16 bf16x4;
typedef __attribute__((ext_vector_type(4))) float f32x4;

#define LN_EPS 1e-5f
#define RADIUS_F 16.0f

__device__ inline bf16x8 zero8() {
    bf16x8 v;
#pragma unroll
    for (int i = 0; i < 8; ++i) v[i] = (__bf16)0.f;
    return v;
}

__device__ inline float wave_sum(float v) {
#pragma unroll
    for (int o = 1; o < 64; o <<= 1) v += __shfl_xor(v, o);
    return v;
}

__device__ inline void gload_lds16(const bf16_t* g, bf16_t* l) {
    __builtin_amdgcn_global_load_lds(
        (const __attribute__((address_space(1))) void*)g,
        (__attribute__((address_space(3))) void*)l, 16, 0, 0);
}

__device__ inline void drain_barrier() {
    asm volatile("s_waitcnt vmcnt(0)" ::: "memory");
    __builtin_amdgcn_s_barrier();
}

// ---------------- one grid-stride cast for q, v, and all three weights ----------------
__global__ __launch_bounds__(256) void cast_all(
    const float* __restrict__ q, const float* __restrict__ v,
    const float* __restrict__ qw, const float* __restrict__ vw,
    const float* __restrict__ ow,
    bf16_t* __restrict__ qb, bf16_t* __restrict__ vb,
    bf16_t* __restrict__ qwb, bf16_t* __restrict__ vwb,
    bf16_t* __restrict__ owb) {
    const int total = 9043968;  // float4 count
    for (int i = blockIdx.x * 256 + threadIdx.x; i < total; i += gridDim.x * 256) {
        const float* src;
        bf16_t* dst;
        int j;
        if (i < 4194304) { src = q; dst = qb; j = i; }
        else if (i < 8388608) { src = v; dst = vb; j = i - 4194304; }
        else if (i < 8454144) { src = qw; dst = qwb; j = i - 8388608; }
        else if (i < 8519680) { src = vw; dst = vwb; j = i - 8454144; }
        else { src = ow; dst = owb; j = i - 8519680; }
        float4 x = reinterpret_cast<const float4*>(src)[j];
        bf16x4 o;
        o[0] = (__bf16)x.x; o[1] = (__bf16)x.y; o[2] = (__bf16)x.z; o[3] = (__bf16)x.w;
        reinterpret_cast<bf16x4*>(dst)[j] = o;
    }
}

// ---------------- merged prep: keyn (blocks 0..223) + mv_prep (224..351) ----------------
__global__ __launch_bounds__(256) void prep_merge(
    const float* __restrict__ mk, bf16_t* __restrict__ kn,
    const float* __restrict__ mv, bf16_t* __restrict__ mvb,
    bf16_t* __restrict__ mvT, float* __restrict__ invmv,
    float* __restrict__ loss_slots) {
    __shared__ float red[4];
    const int tid = threadIdx.x;
    const int wid = tid >> 6, lane = tid & 63;
    if (blockIdx.x < 224) {
        // normalize mem_key rows (896 x 64) -> bf16
        int row = blockIdx.x * 4 + wid;
        float x = mk[(size_t)row * 64 + lane];
        float ss = wave_sum(x * x);
        kn[(size_t)row * 64 + lane] = (__bf16)(x / fmaxf(sqrtf(ss), 1e-12f));
        return;
    }
    const int s = blockIdx.x - 224;
    if (s >= 112) {
        mvb[(size_t)s * 512 + tid * 2] = (__bf16)0.f;
        mvb[(size_t)s * 512 + tid * 2 + 1] = (__bf16)0.f;
        mvT[(size_t)tid * 128 + s] = (__bf16)0.f;
        mvT[(size_t)(tid + 256) * 128 + s] = (__bf16)0.f;
        return;
    }
    float2 x = *reinterpret_cast<const float2*>(mv + (size_t)s * 512 + tid * 2);
    float ss = wave_sum(x.x * x.x + x.y * x.y);
    if (lane == 0) red[wid] = ss;
    __syncthreads();
    ss = red[0] + red[1] + red[2] + red[3];
    if (tid == 0) invmv[s] = 1.f / fmaxf(sqrtf(ss), 1e-12f);
    mvb[(size_t)s * 512 + tid * 2] = (__bf16)x.x;
    mvb[(size_t)s * 512 + tid * 2 + 1] = (__bf16)x.y;
    mvT[(size_t)tid * 128 + s] = (__bf16)mv[(size_t)s * 512 + tid];
    mvT[(size_t)(tid + 256) * 128 + s] = (__bf16)mv[(size_t)s * 512 + tid + 256];
    if (s == 0 && tid < 2) loss_slots[tid] = 0.f;
}

// ---------------- merged small: contrastive (0..111) + WcT-fold gemm_bt (112..239) ----------------
__global__ __launch_bounds__(256) void small_merge(
    const float* __restrict__ mv, const float* __restrict__ invmv,
    float* __restrict__ out_slot,
    const bf16_t* __restrict__ owb, const bf16_t* __restrict__ mvb,
    bf16_t* __restrict__ wct) {
    __shared__ float rowa[512];
    __shared__ float wsum[4];
    const int tid = threadIdx.x;
    const int wid = tid >> 6, lane = tid & 63;
    if (blockIdx.x < 112) {
        const int a = blockIdx.x;
        for (int i = tid; i < 512; i += 256) rowa[i] = mv[(size_t)a * 512 + i];
        __syncthreads();
        float acc = 0.f;
        const float ia = invmv[a];
        for (int b = wid; b < 112; b += 4) {
            float d = 0.f;
#pragma unroll
            for (int i = 0; i < 8; ++i)
                d += rowa[lane + i * 64] * mv[(size_t)b * 512 + lane + i * 64];
            d = wave_sum(d);
            float gv = d * ia * invmv[b];
            acc += fabsf((a == b ? 1.f : 0.f) - gv);
        }
        if (lane == 0) wsum[wid] = acc;
        __syncthreads();
        if (tid == 0) atomicAdd(out_slot, (wsum[0] + wsum[1] + wsum[2] + wsum[3]) * 0.01f);
        return;
    }
    // WcT fold: wct[d][h*112+s] = sum_j owb[d][h*512+j] * mvb[s][j]
    const int idx = blockIdx.x - 112;          // 0..127
    const int bx = idx & 7, by = (idx >> 3) & 1, bz = idx >> 4;
    const int lr = lane & 15;
    const int kk = (lane >> 4) * 8;
    const int row0 = bx * 64 + wid * 16;
    const int col0 = by * 64;
    const bf16_t* A = owb + (size_t)bz * 512;  // head column offset
    const bf16_t* W = mvb;
    const bf16_t* a_ptr = A + (size_t)(row0 + lr) * 4096 + kk;
    const bf16_t* w_ptr = W + (size_t)(col0 + lr) * 512 + kk;
    f32x4 acc[4];
#pragma unroll
    for (int t = 0; t < 4; ++t) { acc[t][0] = 0.f; acc[t][1] = 0.f; acc[t][2] = 0.f; acc[t][3] = 0.f; }
    bool colv[4];
#pragma unroll
    for (int t = 0; t < 4; ++t) colv[t] = (col0 + t * 16 + lr) < 112;
    for (int k0 = 0; k0 < 512; k0 += 32) {
        bf16x8 a = *reinterpret_cast<const bf16x8*>(a_ptr + k0);
#pragma unroll
        for (int t = 0; t < 4; ++t) {
            bf16x8 b;
            if (colv[t]) b = *reinterpret_cast<const bf16x8*>(w_ptr + (size_t)t * 16 * 512 + k0);
            else b = zero8();
            acc[t] = __builtin_amdgcn_mfma_f32_16x16x32_bf16(a, b, acc[t], 0, 0, 0);
        }
    }
    const int rb = (lane >> 4) * 4;
    bf16_t* Cb = wct + (size_t)bz * 112;
#pragma unroll
    for (int t = 0; t < 4; ++t) {
        int col = col0 + t * 16 + lr;
        if (col >= 112) continue;
#pragma unroll
        for (int j = 0; j < 4; ++j) {
            int r = row0 + rb + j;
            Cb[(size_t)r * 896 + col] = (__bf16)acc[t][j];
        }
    }
}

// ---------------- dual 128x128 GEMM: 3-buffer depth-2 counted-vmcnt pipeline ----------------
__global__ __launch_bounds__(256) void gemm_dual(
    const bf16_t* __restrict__ A0, int lda0, const bf16_t* __restrict__ W0, int ldw0,
    const float* __restrict__ bias0, bf16_t* __restrict__ C0, int K0,
    const bf16_t* __restrict__ A1, int lda1, const bf16_t* __restrict__ W1, int ldw1,
    const float* __restrict__ bias1, bf16_t* __restrict__ C1, int K1) {
    const bf16_t* A = blockIdx.z ? A1 : A0;
    const bf16_t* W = blockIdx.z ? W1 : W0;
    const float* bias = blockIdx.z ? bias1 : bias0;
    bf16_t* Cb = blockIdx.z ? C1 : C0;
    const int lda = blockIdx.z ? lda1 : lda0;
    const int ldw = blockIdx.z ? ldw1 : ldw0;
    const int K = blockIdx.z ? K1 : K0;
    __shared__ __align__(16) bf16_t As[3][128 * 32];
    __shared__ __align__(16) bf16_t Bs[3][128 * 32];
    const int tid = threadIdx.x;
    const int wid = tid >> 6, lane = tid & 63;
    const int wr = wid >> 1, wc = wid & 1;
    const int lr = lane & 15;
    const int ko = (lane >> 4) * 8;
    const size_t rowBase = (size_t)blockIdx.x * 128;
    const size_t colBase = (size_t)blockIdx.y * 128;
    const int r0 = tid >> 2;
    const int c0 = (tid & 3) * 8;
    const bf16_t* a_src = A + (rowBase + r0) * lda + c0;
    const bf16_t* w_src = W + (colBase + r0) * ldw + c0;
    f32x4 acc[4][4];
#pragma unroll
    for (int m = 0; m < 4; ++m)
#pragma unroll
        for (int n = 0; n < 4; ++n) {
            acc[m][n][0] = 0.f; acc[m][n][1] = 0.f;
            acc[m][n][2] = 0.f; acc[m][n][3] = 0.f;
        }
    auto stage = [&](int buf, int ks) {
        const int k0 = ks * 32;
        gload_lds16(a_src + k0, &As[buf][tid * 8]);
        gload_lds16(a_src + (size_t)64 * lda + k0, &As[buf][2048 + tid * 8]);
        gload_lds16(w_src + k0, &Bs[buf][tid * 8]);
        gload_lds16(w_src + (size_t)64 * ldw + k0, &Bs[buf][2048 + tid * 8]);
    };
    const int nt = K >> 5;  // all call sites have nt >= 4
    stage(0, 0);
    stage(1, 1);
    asm volatile("s_waitcnt vmcnt(4)" ::: "memory");
    __builtin_amdgcn_s_barrier();
    int cur = 0;
    for (int ks = 0; ks < nt; ++ks) {
        const int pre = (cur == 0) ? 2 : (cur - 1);
        if (ks + 2 < nt) stage(pre, ks + 2);
        bf16x8 af[4], bfr[4];
#pragma unroll
        for (int m = 0; m < 4; ++m)
            af[m] = *reinterpret_cast<const bf16x8*>(&As[cur][(wr * 64 + m * 16 + lr) * 32 + ko]);
#pragma unroll
        for (int n = 0; n < 4; ++n)
            bfr[n] = *reinterpret_cast<const bf16x8*>(&Bs[cur][(wc * 64 + n * 16 + lr) * 32 + ko]);
#pragma unroll
        for (int m = 0; m < 4; ++m)
#pragma unroll
            for (int n = 0; n < 4; ++n)
                acc[m][n] = __builtin_amdgcn_mfma_f32_16x16x32_bf16(af[m], bfr[n], acc[m][n], 0, 0, 0);
        if (ks + 1 < nt) {
            if (ks + 2 < nt) asm volatile("s_waitcnt vmcnt(4)" ::: "memory");
            else             asm volatile("s_waitcnt vmcnt(0)" ::: "memory");
            __builtin_amdgcn_s_barrier();
        }
        cur = (cur == 2) ? 0 : (cur + 1);
    }
    const int rj = (lane >> 4) * 4;
#pragma unroll
    for (int n = 0; n < 4; ++n) {
        const int col = (int)colBase + wc * 64 + n * 16 + lr;
        const float bv = bias ? bias[col] : 0.f;
#pragma unroll
        for (int m = 0; m < 4; ++m) {
            const size_t r = rowBase + wr * 64 + m * 16 + rj;
#pragma unroll
            for (int j = 0; j < 4; ++j)
                Cb[(r + j) * 512 + col] = (__bf16)(acc[m][n][j] + bv);
        }
    }
}

// ---------------- merged addressing: predict (blocks 0..4095) + recon sim (4096..4607) ----------------
__global__ __launch_bounds__(256) void addr_sim(
    const bf16_t* __restrict__ qp, const bf16_t* __restrict__ keyn,
    bf16_t* __restrict__ addr,
    const bf16_t* __restrict__ vp, const bf16_t* __restrict__ mvb,
    const float* __restrict__ invmv, bf16_t* __restrict__ addr2) {
    __shared__ __align__(16) bf16_t As[2][64 * 32];
    __shared__ __align__(16) bf16_t Bs[2][128 * 32];
    const int tid = threadIdx.x;
    const int wid = tid >> 6, lane = tid & 63;
    const int lr = lane & 15, hi = lane >> 4;
    if (blockIdx.x < 4096) {
        // ---- predict addressing: sim -> softmax -> addr bf16 [N,896] ----
        const int kk = hi * 8;
        const int h = blockIdx.x >> 9;
        const int row0 = (blockIdx.x & 511) * 64 + wid * 16;
        const bf16_t* a_ptr = qp + (size_t)(row0 + lr) * 512 + h * 64 + kk;
        bf16x8 a0 = *reinterpret_cast<const bf16x8*>(a_ptr);
        bf16x8 a1 = *reinterpret_cast<const bf16x8*>(a_ptr + 32);
        float ssq = 0.f;
#pragma unroll
        for (int j = 0; j < 8; ++j) {
            float x = (float)a0[j], y = (float)a1[j];
            ssq += x * x + y * y;
        }
        ssq += __shfl_xor(ssq, 16);
        ssq += __shfl_xor(ssq, 32);
        const float invq = 1.f / fmaxf(sqrtf(ssq), 1e-12f);
        f32x4 acc[7];
#pragma unroll
        for (int t = 0; t < 7; ++t) {
            const bf16_t* b_ptr = keyn + (size_t)(h * 112 + t * 16 + lr) * 64 + kk;
            bf16x8 b0 = *reinterpret_cast<const bf16x8*>(b_ptr);
            bf16x8 b1 = *reinterpret_cast<const bf16x8*>(b_ptr + 32);
            f32x4 c; c[0] = 0.f; c[1] = 0.f; c[2] = 0.f; c[3] = 0.f;
            c = __builtin_amdgcn_mfma_f32_16x16x32_bf16(a0, b0, c, 0, 0, 0);
            c = __builtin_amdgcn_mfma_f32_16x16x32_bf16(a1, b1, c, 0, 0, 0);
            acc[t] = c;
        }
        const int rb = hi * 4;
        float iq[4];
#pragma unroll
        for (int j = 0; j < 4; ++j) iq[j] = __shfl(invq, rb + j);
#pragma unroll
        for (int j = 0; j < 4; ++j) {
            float m = -1e30f;
#pragma unroll
            for (int t = 0; t < 7; ++t) { acc[t][j] *= iq[j] * RADIUS_F; m = fmaxf(m, acc[t][j]); }
#pragma unroll
            for (int o = 1; o < 16; o <<= 1) m = fmaxf(m, __shfl_xor(m, o));
            float s = 0.f;
#pragma unroll
            for (int t = 0; t < 7; ++t) { float e = __expf(acc[t][j] - m); acc[t][j] = e; s += e; }
#pragma unroll
            for (int o = 1; o < 16; o <<= 1) s += __shfl_xor(s, o);
            const float rs = 1.f / s;
#pragma unroll
            for (int t = 0; t < 7; ++t) acc[t][j] *= rs;
        }
#pragma unroll
        for (int t = 0; t < 7; ++t)
#pragma unroll
            for (int j = 0; j < 4; ++j)
                addr[(size_t)(row0 + rb + j) * 896 + h * 112 + t * 16 + lr] = (__bf16)acc[t][j];
        return;
    }
    // ---- recon sim GEMM + softmax -> addr2 [M][128], 64 rows/block ----
    const int ko = hi * 8;
    const size_t rowBase = (size_t)(blockIdx.x - 4096) * 64;
    const int r0 = tid >> 2, c0 = (tid & 3) * 8;
    const bf16_t* a_src = vp + (rowBase + r0) * 512 + c0;
    const bf16_t* b_src = mvb + (size_t)r0 * 512 + c0;
    f32x4 acc[8];
#pragma unroll
    for (int n = 0; n < 8; ++n) {
        acc[n][0] = 0.f; acc[n][1] = 0.f; acc[n][2] = 0.f; acc[n][3] = 0.f;
    }
    float ssq = 0.f;
    auto stage = [&](int buf, int ks) {
        const int k0 = ks * 32;
        gload_lds16(a_src + k0, &As[buf][tid * 8]);
        gload_lds16(b_src + k0, &Bs[buf][tid * 8]);
        gload_lds16(b_src + (size_t)64 * 512 + k0, &Bs[buf][2048 + tid * 8]);
    };
    stage(0, 0);
    drain_barrier();
    int cur = 0;
    for (int ks = 0; ks < 16; ++ks) {
        if (ks < 15) stage(cur ^ 1, ks + 1);
        bf16x8 af, bfr[8];
        af = *reinterpret_cast<const bf16x8*>(&As[cur][(wid * 16 + lr) * 32 + ko]);
#pragma unroll
        for (int n = 0; n < 8; ++n)
            bfr[n] = *reinterpret_cast<const bf16x8*>(&Bs[cur][(n * 16 + lr) * 32 + ko]);
#pragma unroll
        for (int j = 0; j < 8; ++j) { float x = (float)af[j]; ssq += x * x; }
#pragma unroll
        for (int n = 0; n < 8; ++n)
            acc[n] = __builtin_amdgcn_mfma_f32_16x16x32_bf16(af, bfr[n], acc[n], 0, 0, 0);
        drain_barrier();
        cur ^= 1;
    }
    ssq += __shfl_xor(ssq, 16);
    ssq += __shfl_xor(ssq, 32);
    ssq = 1.f / fmaxf(sqrtf(ssq), 1e-12f);
    const int rb = hi * 4;
    float imv[7];
#pragma unroll
    for (int n = 0; n < 7; ++n) imv[n] = invmv[n * 16 + lr];
#pragma unroll
    for (int j = 0; j < 4; ++j) {
        const float iq = __shfl(ssq, (lane & 48) | (rb + j));
        float x[7];
        float mx = -1e30f;
#pragma unroll
        for (int n = 0; n < 7; ++n) {
            x[n] = acc[n][j] * iq * imv[n] * RADIUS_F;
            mx = fmaxf(mx, x[n]);
        }
#pragma unroll
        for (int o = 1; o < 16; o <<= 1) mx = fmaxf(mx, __shfl_xor(mx, o));
        float s = 0.f;
#pragma unroll
        for (int n = 0; n < 7; ++n) { x[n] = __expf(x[n] - mx); s += x[n]; }
#pragma unroll
        for (int o = 1; o < 16; o <<= 1) s += __shfl_xor(s, o);
        const float rs = 1.f / s;
        const size_t row = rowBase + wid * 16 + rb + j;
#pragma unroll
        for (int n = 0; n < 7; ++n)
            addr2[row * 128 + n * 16 + lr] = (__bf16)(x[n] * rs);
        addr2[row * 128 + 112 + lr] = (__bf16)0.f;
    }
}

// ---------------- fused epilogue: BOTH branches, 2 rows/wave, all-bf16 inputs ----------------
__global__ __launch_bounds__(256) void fused_ep(
    const bf16_t* __restrict__ sP, const bf16_t* __restrict__ sR,
    const bf16_t* __restrict__ qb, const bf16_t* __restrict__ vb,
    const float* __restrict__ g1, const float* __restrict__ b1,
    const float* __restrict__ g3, const float* __restrict__ b3,
    float* __restrict__ fP, float* __restrict__ fR,
    float* __restrict__ rrpart) {
    const int wid = threadIdx.x >> 6, lane = threadIdx.x & 63;
    const size_t row0 = (size_t)blockIdx.x * 8 + wid * 2;
    const int c1 = lane * 8, c2 = lane * 8 + 4;
    float xP[2][8], aR[2][8], qv[2][8];
    float s1[2], s2[2], sa[2], sa2[2], sav[2], sv2[2];
#pragma unroll
    for (int r = 0; r < 2; ++r) {
        const size_t base = (row0 + r) * 512;
        bf16x8 p = *reinterpret_cast<const bf16x8*>(sP + base + c1);
        bf16x8 rr = *reinterpret_cast<const bf16x8*>(sR + base + c1);
        bf16x8 qq = *reinterpret_cast<const bf16x8*>(qb + base + c1);
        bf16x8 vv = *reinterpret_cast<const bf16x8*>(vb + base + c1);
        s1[r] = 0.f; s2[r] = 0.f;
        sa[r] = 0.f; sa2[r] = 0.f; sav[r] = 0.f; sv2[r] = 0.f;
#pragma unroll
        for (int j = 0; j < 8; ++j) {
            const float qf = (float)qq[j];
            const float pf = (float)p[j];
            const float af = (float)rr[j];
            const float vf = (float)vv[j];
            qv[r][j] = qf;
            const float x = qf + pf;
            xP[r][j] = x;
            s1[r] += x; s2[r] += x * x;
            aR[r][j] = af;
            sa[r] += af; sa2[r] += af * af;
            sav[r] += af * vf; sv2[r] += vf * vf;
        }
    }
#pragma unroll
    for (int o = 1; o < 64; o <<= 1)
#pragma unroll
        for (int r = 0; r < 2; ++r) {
            s1[r] += __shfl_xor(s1[r], o);
            s2[r] += __shfl_xor(s2[r], o);
            sa[r] += __shfl_xor(sa[r], o);
            sa2[r] += __shfl_xor(sa2[r], o);
            sav[r] += __shfl_xor(sav[r], o);
            sv2[r] += __shfl_xor(sv2[r], o);
        }
    const float4 g1a = *reinterpret_cast<const float4*>(g1 + c1);
    const float4 g1b = *reinterpret_cast<const float4*>(g1 + c2);
    const float4 b1a = *reinterpret_cast<const float4*>(b1 + c1);
    const float4 b1b = *reinterpret_cast<const float4*>(b1 + c2);
#pragma unroll
    for (int r = 0; r < 2; ++r) {
        const size_t base = (row0 + r) * 512;
        const float mu = s1[r] * (1.f / 512.f);
        const float rs = rsqrtf(s2[r] * (1.f / 512.f) - mu * mu + LN_EPS);
        float4 o1 = make_float4((xP[r][0] - mu) * rs * g1a.x + b1a.x,
                                (xP[r][1] - mu) * rs * g1a.y + b1a.y,
                                (xP[r][2] - mu) * rs * g1a.z + b1a.z,
                                (xP[r][3] - mu) * rs * g1a.w + b1a.w);
        float4 o2 = make_float4((xP[r][4] - mu) * rs * g1b.x + b1b.x,
                                (xP[r][5] - mu) * rs * g1b.y + b1b.y,
                                (xP[r][6] - mu) * rs * g1b.z + b1b.z,
                                (xP[r][7] - mu) * rs * g1b.w + b1b.w);
        *reinterpret_cast<float4*>(fP + base + c1) = o1;
        *reinterpret_cast<float4*>(fP + base + c2) = o2;
    }
    float rrw = 0.f;
    if (lane == 0) {
#pragma unroll
        for (int r = 0; r < 2; ++r) {
            const float na = fmaxf(sqrtf(sa2[r]), 1e-12f);
            const float nv = fmaxf(sqrtf(sv2[r]), 1e-12f);
            rrw += fabsf(1.f - sav[r] / (na * nv));
        }
    }
    const float4 g3a = *reinterpret_cast<const float4*>(g3 + c1);
    const float4 g3b = *reinterpret_cast<const float4*>(g3 + c2);
    const float4 b3a = *reinterpret_cast<const float4*>(b3 + c1);
    const float4 b3b = *reinterpret_cast<const float4*>(b3 + c2);
#pragma unroll
    for (int r = 0; r < 2; ++r) {
        const float mu3 = sa[r] * (1.f / 512.f);
        const float r3 = rsqrtf(sa2[r] * (1.f / 512.f) - mu3 * mu3 + LN_EPS);
        float s1n = 0.f, s2n = 0.f;
        const float gg[8] = {g3a.x, g3a.y, g3a.z, g3a.w, g3b.x, g3b.y, g3b.z, g3b.w};
        const float bb[8] = {b3a.x, b3a.y, b3a.z, b3a.w, b3b.x, b3b.y, b3b.z, b3b.w};
#pragma unroll
        for (int j = 0; j < 8; ++j) {
            const float x = qv[r][j] + (aR[r][j] - mu3) * r3 * gg[j] + bb[j];
            aR[r][j] = x;
            s1n += x; s2n += x * x;
        }
        s1[r] = s1n; s2[r] = s2n;
    }
#pragma unroll
    for (int o = 1; o < 64; o <<= 1)
#pragma unroll
        for (int r = 0; r < 2; ++r) {
            s1[r] += __shfl_xor(s1[r], o);
            s2[r] += __shfl_xor(s2[r], o);
        }
#pragma unroll
    for (int r = 0; r < 2; ++r) {
        const size_t base = (row0 + r) * 512;
        const float mu = s1[r] * (1.f / 512.f);
        const float rs = rsqrtf(s2[r] * (1.f / 512.f) - mu * mu + LN_EPS);
        float4 o1 = make_float4((aR[r][0] - mu) * rs * g1a.x + b1a.x,
                                (aR[r][1] - mu) * rs * g1a.y + b1a.y,
                                (aR[r][2] - mu) * rs * g1a.z + b1a.z,
                                (aR[r][3] - mu) * rs * g1a.w + b1a.w);
        float4 o2 = make_float4((aR[r][4] - mu) * rs * g1b.x + b1b.x,
                                (aR[r][5] - mu) * rs * g1b.y + b1b.y,
                                (aR[r][6] - mu) * rs * g1b.z + b1b.z,
                                (aR[r][7] - mu) * rs * g1b.w + b1b.w);
        *reinterpret_cast<float4*>(fR + base + c1) = o1;
        *reinterpret_cast<float4*>(fR + base + c2) = o2;
    }
    __shared__ float rred[4];
    if (lane == 0) rred[wid] = rrw;
    __syncthreads();
    if (threadIdx.x == 0)
        rrpart[blockIdx.x] = rred[0] + rred[1] + rred[2] + rred[3];
}

// sum block partials -> loss_slots[0]
__global__ __launch_bounds__(256) void reduce_part_k(const float* __restrict__ part,
                                                     int n, float* __restrict__ out) {
    float s = 0.f;
    for (int i = threadIdx.x; i < n; i += 256) s += part[i];
    s = wave_sum(s);
    __shared__ float red[4];
    const int wid = threadIdx.x >> 6, lane = threadIdx.x & 63;
    if (lane == 0) red[wid] = s;
    __syncthreads();
    if (threadIdx.x == 0)
        out[0] = (red[0] + red[1] + red[2] + red[3]) * (1.f / 32768.f);
}

extern "C" void kernel_launch(void* const* d_in, const int* in_sizes, int n_in,
                              void* d_out, int out_size, void* d_ws, size_t ws_size,
                              hipStream_t stream) {
    const float* query = (const float*)d_in[0];
    const float* value = (const float*)d_in[1];
    const float* mem_key = (const float*)d_in[2];
    const float* mem_value = (const float*)d_in[3];
    const float* q_w = (const float*)d_in[4];
    const float* q_b = (const float*)d_in[5];
    const float* v_w = (const float*)d_in[6];
    const float* v_b = (const float*)d_in[7];
    const float* out_w = (const float*)d_in[8];
    const float* out_b = (const float*)d_in[9];
    const float* ln1_g = (const float*)d_in[10];
    const float* ln1_b = (const float*)d_in[11];
    const float* ln3_g = (const float*)d_in[12];
    const float* ln3_b = (const float*)d_in[13];
    float* out = (float*)d_out;

    char* ws = (char*)d_ws;
    size_t off = 0;
    auto alloc = [&](size_t bytes) {
        void* p = ws + off;
        off += (bytes + 255) & ~(size_t)255;
        return p;
    };
    bf16_t* qb = (bf16_t*)alloc(16777216ull * 2);      // query bf16 (live to end)
    bf16_t* vb = (bf16_t*)alloc(16777216ull * 2);      // value bf16 (live to end)
    bf16_t* qpb = (bf16_t*)alloc(16777216ull * 2);     // qp; stageP aliases after addr_sim
    bf16_t* vpb = (bf16_t*)alloc(16777216ull * 2);     // vp; stageR aliases after addr_sim
    bf16_t* addr = (bf16_t*)alloc(32768ull * 896 * 2); // addr [N][896]
    bf16_t* addr2 = (bf16_t*)alloc(32768ull * 128 * 2);// addr2 [N][128]
    bf16_t* qwb = (bf16_t*)alloc(262144ull * 2);
    bf16_t* vwb = (bf16_t*)alloc(262144ull * 2);
    bf16_t* owb = (bf16_t*)alloc(2097152ull * 2);
    bf16_t* wct = (bf16_t*)alloc(896ull * 512 * 2);    // WcT[512][896]
    bf16_t* keyn = (bf16_t*)alloc(896ull * 64 * 2);
    bf16_t* mvb = (bf16_t*)alloc(128ull * 512 * 2);
    bf16_t* mvT = (bf16_t*)alloc(512ull * 128 * 2);
    float* invmv = (float*)alloc(112 * 4);
    float* rrpart = (float*)alloc(4096 * 4);
    bf16_t* stageP = qpb;
    bf16_t* stageR = vpb;

    float* f_predict = out;
    float* f_recon = out + 16777216;
    float* loss_slots = out + 33554432;  // [recon_loss, contrastive_loss]

    // prep
    cast_all<<<2048, 256, 0, stream>>>(query, value, q_w, v_w, out_w,
                                       qb, vb, qwb, vwb, owb);
    prep_merge<<<352, 256, 0, stream>>>(mem_key, keyn, mem_value, mvb, mvT,
                                        invmv, loss_slots);
    small_merge<<<240, 256, 0, stream>>>(mem_value, invmv, loss_slots + 1,
                                         owb, mvb, wct);
    // both projections in ONE dispatch
    gemm_dual<<<dim3(256, 4, 2), 256, 0, stream>>>(
        qb, 512, qwb, 512, q_b, qpb, 512,
        vb, 512, vwb, 512, v_b, vpb, 512);
    // both addressing paths in ONE dispatch (sim blocks fill addr's tail)
    addr_sim<<<4608, 256, 0, stream>>>(qpb, keyn, addr, vpb, mvb, invmv, addr2);
    // both stage GEMMs in ONE dispatch
    gemm_dual<<<dim3(256, 4, 2), 256, 0, stream>>>(
        addr, 896, wct, 896, out_b, stageP, 896,
        addr2, 128, mvT, 128, (const float*)nullptr, stageR, 128);
    // both epilogues fused
    fused_ep<<<4096, 256, 0, stream>>>(stageP, stageR, qb, vb,
                                       ln1_g, ln1_b, ln3_g, ln3_b,
                                       f_predict, f_recon, rrpart);
    reduce_part_k<<<1, 256, 0, stream>>>(rrpart, 4096, loss_slots);
}

// Round 14
// 275.020 us; speedup vs baseline: 1.3199x; 1.0247x over previous
//
#include <hip/hip_runtime.h>
#include <hip/hip_bf16.h>
#include <math.h>

typedef __bf16 bf16_t;
typedef __attribute__((ext_vector_type(8))) __bf16 bf16x8;
typedef __attribute__((ext_vector_type(4))) __bf16 bf16x4;
typedef __attribute__((ext_vector_type(4))) float f32x4;

#define LN_EPS 1e-5f
#define RADIUS_F 16.0f

__device__ inline bf16x8 zero8() {
    bf16x8 v;
#pragma unroll
    for (int i = 0; i < 8; ++i) v[i] = (__bf16)0.f;
    return v;
}

__device__ inline float wave_sum(float v) {
#pragma unroll
    for (int o = 1; o < 64; o <<= 1) v += __shfl_xor(v, o);
    return v;
}

__device__ inline void gload_lds16(const bf16_t* g, bf16_t* l) {
    __builtin_amdgcn_global_load_lds(
        (const __attribute__((address_space(1))) void*)g,
        (__attribute__((address_space(3))) void*)l, 16, 0, 0);
}

__device__ inline void drain_barrier() {
    asm volatile("s_waitcnt vmcnt(0)" ::: "memory");
    __builtin_amdgcn_s_barrier();
}

// ---------------- merged prep: keyn (0..223) + mv_prep (224..351) + casts (352..) ----------------
__global__ __launch_bounds__(256) void prep_all(
    const float* __restrict__ mk, bf16_t* __restrict__ kn,
    const float* __restrict__ mv, bf16_t* __restrict__ mvb,
    bf16_t* __restrict__ mvT, float* __restrict__ invmv,
    float* __restrict__ loss_slots,
    const float* __restrict__ q, const float* __restrict__ v,
    const float* __restrict__ qw, const float* __restrict__ vw,
    const float* __restrict__ ow,
    bf16_t* __restrict__ qb, bf16_t* __restrict__ vb,
    bf16_t* __restrict__ qwb, bf16_t* __restrict__ vwb,
    bf16_t* __restrict__ owb) {
    __shared__ float red[4];
    const int tid = threadIdx.x;
    const int wid = tid >> 6, lane = tid & 63;
    if (blockIdx.x < 224) {
        // normalize mem_key rows (896 x 64) -> bf16
        int row = blockIdx.x * 4 + wid;
        float x = mk[(size_t)row * 64 + lane];
        float ss = wave_sum(x * x);
        kn[(size_t)row * 64 + lane] = (__bf16)(x / fmaxf(sqrtf(ss), 1e-12f));
        return;
    }
    if (blockIdx.x < 352) {
        const int s = blockIdx.x - 224;
        if (s >= 112) {
            mvb[(size_t)s * 512 + tid * 2] = (__bf16)0.f;
            mvb[(size_t)s * 512 + tid * 2 + 1] = (__bf16)0.f;
            mvT[(size_t)tid * 128 + s] = (__bf16)0.f;
            mvT[(size_t)(tid + 256) * 128 + s] = (__bf16)0.f;
            return;
        }
        float2 x = *reinterpret_cast<const float2*>(mv + (size_t)s * 512 + tid * 2);
        float ss = wave_sum(x.x * x.x + x.y * x.y);
        if (lane == 0) red[wid] = ss;
        __syncthreads();
        ss = red[0] + red[1] + red[2] + red[3];
        if (tid == 0) invmv[s] = 1.f / fmaxf(sqrtf(ss), 1e-12f);
        mvb[(size_t)s * 512 + tid * 2] = (__bf16)x.x;
        mvb[(size_t)s * 512 + tid * 2 + 1] = (__bf16)x.y;
        mvT[(size_t)tid * 128 + s] = (__bf16)mv[(size_t)s * 512 + tid];
        mvT[(size_t)(tid + 256) * 128 + s] = (__bf16)mv[(size_t)s * 512 + tid + 256];
        if (s == 0 && tid < 2) loss_slots[tid] = 0.f;
        return;
    }
    // grid-stride cast over q, v, and the three weights
    const int total = 9043968;  // float4 count
    const int nblocks = gridDim.x - 352;
    for (int i = (blockIdx.x - 352) * 256 + tid; i < total; i += nblocks * 256) {
        const float* src;
        bf16_t* dst;
        int j;
        if (i < 4194304) { src = q; dst = qb; j = i; }
        else if (i < 8388608) { src = v; dst = vb; j = i - 4194304; }
        else if (i < 8454144) { src = qw; dst = qwb; j = i - 8388608; }
        else if (i < 8519680) { src = vw; dst = vwb; j = i - 8454144; }
        else { src = ow; dst = owb; j = i - 8519680; }
        float4 x = reinterpret_cast<const float4*>(src)[j];
        bf16x4 o;
        o[0] = (__bf16)x.x; o[1] = (__bf16)x.y; o[2] = (__bf16)x.z; o[3] = (__bf16)x.w;
        reinterpret_cast<bf16x4*>(dst)[j] = o;
    }
}

// ---------------- dual 128x128 GEMM (z=0,1) + contrastive/WcT-fold plane (z=2) ----------------
// z<2: C = A @ W^T + bias (3-buffer depth-2 pipeline).
// z=2: flat = blockIdx.x*4+blockIdx.y; flat<112 -> contrastive; 112..239 -> WcT fold.
__global__ __launch_bounds__(256) void gemm_dual(
    const bf16_t* __restrict__ A0, int lda0, const bf16_t* __restrict__ W0, int ldw0,
    const float* __restrict__ bias0, bf16_t* __restrict__ C0, int K0,
    const bf16_t* __restrict__ A1, int lda1, const bf16_t* __restrict__ W1, int ldw1,
    const float* __restrict__ bias1, bf16_t* __restrict__ C1, int K1,
    const float* __restrict__ mv, const float* __restrict__ invmv,
    float* __restrict__ loss1,
    const bf16_t* __restrict__ owb, const bf16_t* __restrict__ mvb,
    bf16_t* __restrict__ wct) {
    __shared__ __align__(16) bf16_t As[3][128 * 32];
    __shared__ __align__(16) bf16_t Bs[3][128 * 32];
    const int tid = threadIdx.x;
    const int wid = tid >> 6, lane = tid & 63;
    const int lr = lane & 15;
    if (blockIdx.z == 2) {
        if (mv == nullptr) return;  // plane unused in this call
        const int flat = blockIdx.x * 4 + blockIdx.y;
        if (flat < 112) {
            // contrastive loss row
            float* rowa = reinterpret_cast<float*>(&As[0][0]);   // 2KB scratch
            float* wsum = reinterpret_cast<float*>(&Bs[0][0]);
            const int a = flat;
            for (int i = tid; i < 512; i += 256) rowa[i] = mv[(size_t)a * 512 + i];
            __syncthreads();
            float acc = 0.f;
            const float ia = invmv[a];
            for (int b = wid; b < 112; b += 4) {
                float d = 0.f;
#pragma unroll
                for (int i = 0; i < 8; ++i)
                    d += rowa[lane + i * 64] * mv[(size_t)b * 512 + lane + i * 64];
                d = wave_sum(d);
                float gv = d * ia * invmv[b];
                acc += fabsf((a == b ? 1.f : 0.f) - gv);
            }
            if (lane == 0) wsum[wid] = acc;
            __syncthreads();
            if (tid == 0) atomicAdd(loss1, (wsum[0] + wsum[1] + wsum[2] + wsum[3]) * 0.01f);
            return;
        }
        if (flat >= 240) return;
        // WcT fold: wct[d][h*112+s] = sum_j owb[d][h*512+j] * mvb[s][j]
        const int idx = flat - 112;                // 0..127
        const int bx = idx & 7, by = (idx >> 3) & 1, bz = idx >> 4;
        const int kk = (lane >> 4) * 8;
        const int row0 = bx * 64 + wid * 16;
        const int col0 = by * 64;
        const bf16_t* a_ptr = owb + (size_t)bz * 512 + (size_t)(row0 + lr) * 4096 + kk;
        const bf16_t* w_ptr = mvb + (size_t)(col0 + lr) * 512 + kk;
        f32x4 acc[4];
#pragma unroll
        for (int t = 0; t < 4; ++t) { acc[t][0] = 0.f; acc[t][1] = 0.f; acc[t][2] = 0.f; acc[t][3] = 0.f; }
        bool colv[4];
#pragma unroll
        for (int t = 0; t < 4; ++t) colv[t] = (col0 + t * 16 + lr) < 112;
        for (int k0 = 0; k0 < 512; k0 += 32) {
            bf16x8 a = *reinterpret_cast<const bf16x8*>(a_ptr + k0);
#pragma unroll
            for (int t = 0; t < 4; ++t) {
                bf16x8 b;
                if (colv[t]) b = *reinterpret_cast<const bf16x8*>(w_ptr + (size_t)t * 16 * 512 + k0);
                else b = zero8();
                acc[t] = __builtin_amdgcn_mfma_f32_16x16x32_bf16(a, b, acc[t], 0, 0, 0);
            }
        }
        const int rb = (lane >> 4) * 4;
        bf16_t* Cb = wct + (size_t)bz * 112;
#pragma unroll
        for (int t = 0; t < 4; ++t) {
            int col = col0 + t * 16 + lr;
            if (col >= 112) continue;
#pragma unroll
            for (int j = 0; j < 4; ++j) {
                int r = row0 + rb + j;
                Cb[(size_t)r * 896 + col] = (__bf16)acc[t][j];
            }
        }
        return;
    }
    // ---- GEMM planes ----
    const bf16_t* A = blockIdx.z ? A1 : A0;
    const bf16_t* W = blockIdx.z ? W1 : W0;
    const float* bias = blockIdx.z ? bias1 : bias0;
    bf16_t* Cb = blockIdx.z ? C1 : C0;
    const int lda = blockIdx.z ? lda1 : lda0;
    const int ldw = blockIdx.z ? ldw1 : ldw0;
    const int K = blockIdx.z ? K1 : K0;
    const int wr = wid >> 1, wc = wid & 1;
    const int ko = (lane >> 4) * 8;
    const size_t rowBase = (size_t)blockIdx.x * 128;
    const size_t colBase = (size_t)blockIdx.y * 128;
    const int r0 = tid >> 2;
    const int c0 = (tid & 3) * 8;
    const bf16_t* a_src = A + (rowBase + r0) * lda + c0;
    const bf16_t* w_src = W + (colBase + r0) * ldw + c0;
    f32x4 acc[4][4];
#pragma unroll
    for (int m = 0; m < 4; ++m)
#pragma unroll
        for (int n = 0; n < 4; ++n) {
            acc[m][n][0] = 0.f; acc[m][n][1] = 0.f;
            acc[m][n][2] = 0.f; acc[m][n][3] = 0.f;
        }
    auto stage = [&](int buf, int ks) {
        const int k0 = ks * 32;
        gload_lds16(a_src + k0, &As[buf][tid * 8]);
        gload_lds16(a_src + (size_t)64 * lda + k0, &As[buf][2048 + tid * 8]);
        gload_lds16(w_src + k0, &Bs[buf][tid * 8]);
        gload_lds16(w_src + (size_t)64 * ldw + k0, &Bs[buf][2048 + tid * 8]);
    };
    const int nt = K >> 5;
    stage(0, 0);
    stage(1, 1);
    asm volatile("s_waitcnt vmcnt(4)" ::: "memory");
    __builtin_amdgcn_s_barrier();
    int cur = 0;
    for (int ks = 0; ks < nt; ++ks) {
        const int pre = (cur == 0) ? 2 : (cur - 1);
        if (ks + 2 < nt) stage(pre, ks + 2);
        bf16x8 af[4], bfr[4];
#pragma unroll
        for (int m = 0; m < 4; ++m)
            af[m] = *reinterpret_cast<const bf16x8*>(&As[cur][(wr * 64 + m * 16 + lr) * 32 + ko]);
#pragma unroll
        for (int n = 0; n < 4; ++n)
            bfr[n] = *reinterpret_cast<const bf16x8*>(&Bs[cur][(wc * 64 + n * 16 + lr) * 32 + ko]);
#pragma unroll
        for (int m = 0; m < 4; ++m)
#pragma unroll
            for (int n = 0; n < 4; ++n)
                acc[m][n] = __builtin_amdgcn_mfma_f32_16x16x32_bf16(af[m], bfr[n], acc[m][n], 0, 0, 0);
        if (ks + 1 < nt) {
            if (ks + 2 < nt) asm volatile("s_waitcnt vmcnt(4)" ::: "memory");
            else             asm volatile("s_waitcnt vmcnt(0)" ::: "memory");
            __builtin_amdgcn_s_barrier();
        }
        cur = (cur == 2) ? 0 : (cur + 1);
    }
    const int rj = (lane >> 4) * 4;
#pragma unroll
    for (int n = 0; n < 4; ++n) {
        const int col = (int)colBase + wc * 64 + n * 16 + lr;
        const float bv = bias ? bias[col] : 0.f;
#pragma unroll
        for (int m = 0; m < 4; ++m) {
            const size_t r = rowBase + wr * 64 + m * 16 + rj;
#pragma unroll
            for (int j = 0; j < 4; ++j)
                Cb[(r + j) * 512 + col] = (__bf16)(acc[m][n][j] + bv);
        }
    }
}

// ---------------- merged addressing: predict (blocks 0..4095) + recon sim (4096..4607) ----------------
__global__ __launch_bounds__(256) void addr_sim(
    const bf16_t* __restrict__ qp, const bf16_t* __restrict__ keyn,
    bf16_t* __restrict__ addr,
    const bf16_t* __restrict__ vp, const bf16_t* __restrict__ mvb,
    const float* __restrict__ invmv, bf16_t* __restrict__ addr2) {
    __shared__ __align__(16) bf16_t As[2][64 * 32];
    __shared__ __align__(16) bf16_t Bs[2][128 * 32];
    const int tid = threadIdx.x;
    const int wid = tid >> 6, lane = tid & 63;
    const int lr = lane & 15, hi = lane >> 4;
    if (blockIdx.x < 4096) {
        const int kk = hi * 8;
        const int h = blockIdx.x >> 9;
        const int row0 = (blockIdx.x & 511) * 64 + wid * 16;
        const bf16_t* a_ptr = qp + (size_t)(row0 + lr) * 512 + h * 64 + kk;
        bf16x8 a0 = *reinterpret_cast<const bf16x8*>(a_ptr);
        bf16x8 a1 = *reinterpret_cast<const bf16x8*>(a_ptr + 32);
        float ssq = 0.f;
#pragma unroll
        for (int j = 0; j < 8; ++j) {
            float x = (float)a0[j], y = (float)a1[j];
            ssq += x * x + y * y;
        }
        ssq += __shfl_xor(ssq, 16);
        ssq += __shfl_xor(ssq, 32);
        const float invq = 1.f / fmaxf(sqrtf(ssq), 1e-12f);
        f32x4 acc[7];
#pragma unroll
        for (int t = 0; t < 7; ++t) {
            const bf16_t* b_ptr = keyn + (size_t)(h * 112 + t * 16 + lr) * 64 + kk;
            bf16x8 b0 = *reinterpret_cast<const bf16x8*>(b_ptr);
            bf16x8 b1 = *reinterpret_cast<const bf16x8*>(b_ptr + 32);
            f32x4 c; c[0] = 0.f; c[1] = 0.f; c[2] = 0.f; c[3] = 0.f;
            c = __builtin_amdgcn_mfma_f32_16x16x32_bf16(a0, b0, c, 0, 0, 0);
            c = __builtin_amdgcn_mfma_f32_16x16x32_bf16(a1, b1, c, 0, 0, 0);
            acc[t] = c;
        }
        const int rb = hi * 4;
        float iq[4];
#pragma unroll
        for (int j = 0; j < 4; ++j) iq[j] = __shfl(invq, rb + j);
#pragma unroll
        for (int j = 0; j < 4; ++j) {
            float m = -1e30f;
#pragma unroll
            for (int t = 0; t < 7; ++t) { acc[t][j] *= iq[j] * RADIUS_F; m = fmaxf(m, acc[t][j]); }
#pragma unroll
            for (int o = 1; o < 16; o <<= 1) m = fmaxf(m, __shfl_xor(m, o));
            float s = 0.f;
#pragma unroll
            for (int t = 0; t < 7; ++t) { float e = __expf(acc[t][j] - m); acc[t][j] = e; s += e; }
#pragma unroll
            for (int o = 1; o < 16; o <<= 1) s += __shfl_xor(s, o);
            const float rs = 1.f / s;
#pragma unroll
            for (int t = 0; t < 7; ++t) acc[t][j] *= rs;
        }
#pragma unroll
        for (int t = 0; t < 7; ++t)
#pragma unroll
            for (int j = 0; j < 4; ++j)
                addr[(size_t)(row0 + rb + j) * 896 + h * 112 + t * 16 + lr] = (__bf16)acc[t][j];
        return;
    }
    const int ko = hi * 8;
    const size_t rowBase = (size_t)(blockIdx.x - 4096) * 64;
    const int r0 = tid >> 2, c0 = (tid & 3) * 8;
    const bf16_t* a_src = vp + (rowBase + r0) * 512 + c0;
    const bf16_t* b_src = mvb + (size_t)r0 * 512 + c0;
    f32x4 acc[8];
#pragma unroll
    for (int n = 0; n < 8; ++n) {
        acc[n][0] = 0.f; acc[n][1] = 0.f; acc[n][2] = 0.f; acc[n][3] = 0.f;
    }
    float ssq = 0.f;
    auto stage = [&](int buf, int ks) {
        const int k0 = ks * 32;
        gload_lds16(a_src + k0, &As[buf][tid * 8]);
        gload_lds16(b_src + k0, &Bs[buf][tid * 8]);
        gload_lds16(b_src + (size_t)64 * 512 + k0, &Bs[buf][2048 + tid * 8]);
    };
    stage(0, 0);
    drain_barrier();
    int cur = 0;
    for (int ks = 0; ks < 16; ++ks) {
        if (ks < 15) stage(cur ^ 1, ks + 1);
        bf16x8 af, bfr[8];
        af = *reinterpret_cast<const bf16x8*>(&As[cur][(wid * 16 + lr) * 32 + ko]);
#pragma unroll
        for (int n = 0; n < 8; ++n)
            bfr[n] = *reinterpret_cast<const bf16x8*>(&Bs[cur][(n * 16 + lr) * 32 + ko]);
#pragma unroll
        for (int j = 0; j < 8; ++j) { float x = (float)af[j]; ssq += x * x; }
#pragma unroll
        for (int n = 0; n < 8; ++n)
            acc[n] = __builtin_amdgcn_mfma_f32_16x16x32_bf16(af, bfr[n], acc[n], 0, 0, 0);
        drain_barrier();
        cur ^= 1;
    }
    ssq += __shfl_xor(ssq, 16);
    ssq += __shfl_xor(ssq, 32);
    ssq = 1.f / fmaxf(sqrtf(ssq), 1e-12f);
    const int rb = hi * 4;
    float imv[7];
#pragma unroll
    for (int n = 0; n < 7; ++n) imv[n] = invmv[n * 16 + lr];
#pragma unroll
    for (int j = 0; j < 4; ++j) {
        const float iq = __shfl(ssq, (lane & 48) | (rb + j));
        float x[7];
        float mx = -1e30f;
#pragma unroll
        for (int n = 0; n < 7; ++n) {
            x[n] = acc[n][j] * iq * imv[n] * RADIUS_F;
            mx = fmaxf(mx, x[n]);
        }
#pragma unroll
        for (int o = 1; o < 16; o <<= 1) mx = fmaxf(mx, __shfl_xor(mx, o));
        float s = 0.f;
#pragma unroll
        for (int n = 0; n < 7; ++n) { x[n] = __expf(x[n] - mx); s += x[n]; }
#pragma unroll
        for (int o = 1; o < 16; o <<= 1) s += __shfl_xor(s, o);
        const float rs = 1.f / s;
        const size_t row = rowBase + wid * 16 + rb + j;
#pragma unroll
        for (int n = 0; n < 7; ++n)
            addr2[row * 128 + n * 16 + lr] = (__bf16)(x[n] * rs);
        addr2[row * 128 + 112 + lr] = (__bf16)0.f;
    }
}

// ---------------- fused epilogue: BOTH branches, 2 rows/wave, all-bf16 inputs ----------------
__global__ __launch_bounds__(256) void fused_ep(
    const bf16_t* __restrict__ sP, const bf16_t* __restrict__ sR,
    const bf16_t* __restrict__ qb, const bf16_t* __restrict__ vb,
    const float* __restrict__ g1, const float* __restrict__ b1,
    const float* __restrict__ g3, const float* __restrict__ b3,
    float* __restrict__ fP, float* __restrict__ fR,
    float* __restrict__ rrpart) {
    const int wid = threadIdx.x >> 6, lane = threadIdx.x & 63;
    const size_t row0 = (size_t)blockIdx.x * 8 + wid * 2;
    const int c1 = lane * 8, c2 = lane * 8 + 4;
    float xP[2][8], aR[2][8], qv[2][8];
    float s1[2], s2[2], sa[2], sa2[2], sav[2], sv2[2];
#pragma unroll
    for (int r = 0; r < 2; ++r) {
        const size_t base = (row0 + r) * 512;
        bf16x8 p = *reinterpret_cast<const bf16x8*>(sP + base + c1);
        bf16x8 rr = *reinterpret_cast<const bf16x8*>(sR + base + c1);
        bf16x8 qq = *reinterpret_cast<const bf16x8*>(qb + base + c1);
        bf16x8 vv = *reinterpret_cast<const bf16x8*>(vb + base + c1);
        s1[r] = 0.f; s2[r] = 0.f;
        sa[r] = 0.f; sa2[r] = 0.f; sav[r] = 0.f; sv2[r] = 0.f;
#pragma unroll
        for (int j = 0; j < 8; ++j) {
            const float qf = (float)qq[j];
            const float pf = (float)p[j];
            const float af = (float)rr[j];
            const float vf = (float)vv[j];
            qv[r][j] = qf;
            const float x = qf + pf;
            xP[r][j] = x;
            s1[r] += x; s2[r] += x * x;
            aR[r][j] = af;
            sa[r] += af; sa2[r] += af * af;
            sav[r] += af * vf; sv2[r] += vf * vf;
        }
    }
#pragma unroll
    for (int o = 1; o < 64; o <<= 1)
#pragma unroll
        for (int r = 0; r < 2; ++r) {
            s1[r] += __shfl_xor(s1[r], o);
            s2[r] += __shfl_xor(s2[r], o);
            sa[r] += __shfl_xor(sa[r], o);
            sa2[r] += __shfl_xor(sa2[r], o);
            sav[r] += __shfl_xor(sav[r], o);
            sv2[r] += __shfl_xor(sv2[r], o);
        }
    const float4 g1a = *reinterpret_cast<const float4*>(g1 + c1);
    const float4 g1b = *reinterpret_cast<const float4*>(g1 + c2);
    const float4 b1a = *reinterpret_cast<const float4*>(b1 + c1);
    const float4 b1b = *reinterpret_cast<const float4*>(b1 + c2);
#pragma unroll
    for (int r = 0; r < 2; ++r) {
        const size_t base = (row0 + r) * 512;
        const float mu = s1[r] * (1.f / 512.f);
        const float rs = rsqrtf(s2[r] * (1.f / 512.f) - mu * mu + LN_EPS);
        float4 o1 = make_float4((xP[r][0] - mu) * rs * g1a.x + b1a.x,
                                (xP[r][1] - mu) * rs * g1a.y + b1a.y,
                                (xP[r][2] - mu) * rs * g1a.z + b1a.z,
                                (xP[r][3] - mu) * rs * g1a.w + b1a.w);
        float4 o2 = make_float4((xP[r][4] - mu) * rs * g1b.x + b1b.x,
                                (xP[r][5] - mu) * rs * g1b.y + b1b.y,
                                (xP[r][6] - mu) * rs * g1b.z + b1b.z,
                                (xP[r][7] - mu) * rs * g1b.w + b1b.w);
        *reinterpret_cast<float4*>(fP + base + c1) = o1;
        *reinterpret_cast<float4*>(fP + base + c2) = o2;
    }
    float rrw = 0.f;
    if (lane == 0) {
#pragma unroll
        for (int r = 0; r < 2; ++r) {
            const float na = fmaxf(sqrtf(sa2[r]), 1e-12f);
            const float nv = fmaxf(sqrtf(sv2[r]), 1e-12f);
            rrw += fabsf(1.f - sav[r] / (na * nv));
        }
    }
    const float4 g3a = *reinterpret_cast<const float4*>(g3 + c1);
    const float4 g3b = *reinterpret_cast<const float4*>(g3 + c2);
    const float4 b3a = *reinterpret_cast<const float4*>(b3 + c1);
    const float4 b3b = *reinterpret_cast<const float4*>(b3 + c2);
#pragma unroll
    for (int r = 0; r < 2; ++r) {
        const float mu3 = sa[r] * (1.f / 512.f);
        const float r3 = rsqrtf(sa2[r] * (1.f / 512.f) - mu3 * mu3 + LN_EPS);
        float s1n = 0.f, s2n = 0.f;
        const float gg[8] = {g3a.x, g3a.y, g3a.z, g3a.w, g3b.x, g3b.y, g3b.z, g3b.w};
        const float bb[8] = {b3a.x, b3a.y, b3a.z, b3a.w, b3b.x, b3b.y, b3b.z, b3b.w};
#pragma unroll
        for (int j = 0; j < 8; ++j) {
            const float x = qv[r][j] + (aR[r][j] - mu3) * r3 * gg[j] + bb[j];
            aR[r][j] = x;
            s1n += x; s2n += x * x;
        }
        s1[r] = s1n; s2[r] = s2n;
    }
#pragma unroll
    for (int o = 1; o < 64; o <<= 1)
#pragma unroll
        for (int r = 0; r < 2; ++r) {
            s1[r] += __shfl_xor(s1[r], o);
            s2[r] += __shfl_xor(s2[r], o);
        }
#pragma unroll
    for (int r = 0; r < 2; ++r) {
        const size_t base = (row0 + r) * 512;
        const float mu = s1[r] * (1.f / 512.f);
        const float rs = rsqrtf(s2[r] * (1.f / 512.f) - mu * mu + LN_EPS);
        float4 o1 = make_float4((aR[r][0] - mu) * rs * g1a.x + b1a.x,
                                (aR[r][1] - mu) * rs * g1a.y + b1a.y,
                                (aR[r][2] - mu) * rs * g1a.z + b1a.z,
                                (aR[r][3] - mu) * rs * g1a.w + b1a.w);
        float4 o2 = make_float4((aR[r][4] - mu) * rs * g1b.x + b1b.x,
                                (aR[r][5] - mu) * rs * g1b.y + b1b.y,
                                (aR[r][6] - mu) * rs * g1b.z + b1b.z,
                                (aR[r][7] - mu) * rs * g1b.w + b1b.w);
        *reinterpret_cast<float4*>(fR + base + c1) = o1;
        *reinterpret_cast<float4*>(fR + base + c2) = o2;
    }
    __shared__ float rred[4];
    if (lane == 0) rred[wid] = rrw;
    __syncthreads();
    if (threadIdx.x == 0)
        rrpart[blockIdx.x] = rred[0] + rred[1] + rred[2] + rred[3];
}

// sum block partials -> loss_slots[0]
__global__ __launch_bounds__(256) void reduce_part_k(const float* __restrict__ part,
                                                     int n, float* __restrict__ out) {
    float s = 0.f;
    for (int i = threadIdx.x; i < n; i += 256) s += part[i];
    s = wave_sum(s);
    __shared__ float red[4];
    const int wid = threadIdx.x >> 6, lane = threadIdx.x & 63;
    if (lane == 0) red[wid] = s;
    __syncthreads();
    if (threadIdx.x == 0)
        out[0] = (red[0] + red[1] + red[2] + red[3]) * (1.f / 32768.f);
}

extern "C" void kernel_launch(void* const* d_in, const int* in_sizes, int n_in,
                              void* d_out, int out_size, void* d_ws, size_t ws_size,
                              hipStream_t stream) {
    const float* query = (const float*)d_in[0];
    const float* value = (const float*)d_in[1];
    const float* mem_key = (const float*)d_in[2];
    const float* mem_value = (const float*)d_in[3];
    const float* q_w = (const float*)d_in[4];
    const float* q_b = (const float*)d_in[5];
    const float* v_w = (const float*)d_in[6];
    const float* v_b = (const float*)d_in[7];
    const float* out_w = (const float*)d_in[8];
    const float* out_b = (const float*)d_in[9];
    const float* ln1_g = (const float*)d_in[10];
    const float* ln1_b = (const float*)d_in[11];
    const float* ln3_g = (const float*)d_in[12];
    const float* ln3_b = (const float*)d_in[13];
    float* out = (float*)d_out;

    char* ws = (char*)d_ws;
    size_t off = 0;
    auto alloc = [&](size_t bytes) {
        void* p = ws + off;
        off += (bytes + 255) & ~(size_t)255;
        return p;
    };
    bf16_t* qb = (bf16_t*)alloc(16777216ull * 2);      // query bf16 (live to end)
    bf16_t* vb = (bf16_t*)alloc(16777216ull * 2);      // value bf16 (live to end)
    bf16_t* qpb = (bf16_t*)alloc(16777216ull * 2);     // qp; stageP aliases after addr_sim
    bf16_t* vpb = (bf16_t*)alloc(16777216ull * 2);     // vp; stageR aliases after addr_sim
    bf16_t* addr = (bf16_t*)alloc(32768ull * 896 * 2); // addr [N][896]
    bf16_t* addr2 = (bf16_t*)alloc(32768ull * 128 * 2);// addr2 [N][128]
    bf16_t* qwb = (bf16_t*)alloc(262144ull * 2);
    bf16_t* vwb = (bf16_t*)alloc(262144ull * 2);
    bf16_t* owb = (bf16_t*)alloc(2097152ull * 2);
    bf16_t* wct = (bf16_t*)alloc(896ull * 512 * 2);    // WcT[512][896]
    bf16_t* keyn = (bf16_t*)alloc(896ull * 64 * 2);
    bf16_t* mvb = (bf16_t*)alloc(128ull * 512 * 2);
    bf16_t* mvT = (bf16_t*)alloc(512ull * 128 * 2);
    float* invmv = (float*)alloc(112 * 4);
    float* rrpart = (float*)alloc(4096 * 4);
    bf16_t* stageP = qpb;
    bf16_t* stageR = vpb;

    float* f_predict = out;
    float* f_recon = out + 16777216;
    float* loss_slots = out + 33554432;  // [recon_loss, contrastive_loss]

    // round 1: all prep (norms, bf16 copies, casts) in ONE dispatch
    prep_all<<<2400, 256, 0, stream>>>(mem_key, keyn, mem_value, mvb, mvT,
                                       invmv, loss_slots,
                                       query, value, q_w, v_w, out_w,
                                       qb, vb, qwb, vwb, owb);
    // round 2: projections (z=0,1) + contrastive & WcT fold (z=2) in ONE dispatch
    gemm_dual<<<dim3(256, 4, 3), 256, 0, stream>>>(
        qb, 512, qwb, 512, q_b, qpb, 512,
        vb, 512, vwb, 512, v_b, vpb, 512,
        mem_value, invmv, loss_slots + 1, owb, mvb, wct);
    // round 3: both addressing paths in ONE dispatch
    addr_sim<<<4608, 256, 0, stream>>>(qpb, keyn, addr, vpb, mvb, invmv, addr2);
    // round 4: both stage GEMMs in ONE dispatch (z=2 plane unused)
    gemm_dual<<<dim3(256, 4, 2), 256, 0, stream>>>(
        addr, 896, wct, 896, out_b, stageP, 896,
        addr2, 128, mvT, 128, (const float*)nullptr, stageR, 128,
        (const float*)nullptr, (const float*)nullptr, (float*)nullptr,
        (const bf16_t*)nullptr, (const bf16_t*)nullptr, (bf16_t*)nullptr);
    // round 5: both epilogues fused
    fused_ep<<<4096, 256, 0, stream>>>(stageP, stageR, qb, vb,
                                       ln1_g, ln1_b, ln3_g, ln3_b,
                                       f_predict, f_recon, rrpart);
    reduce_part_k<<<1, 256, 0, stream>>>(rrpart, 4096, loss_slots);
}